// Round 8
// baseline (2828.982 us; speedup 1.0000x reference)
//
#include <hip/hip_runtime.h>
#include <hip/hip_bf16.h>

// ---------------------------------------------------------------------------
// SurpriseKimiDeltaAttention  (B=2, T=4096, H=2048, NH=16, DK=DV=128, CONV=4)
// Pipeline: cast -> qkv GEMM -> conv/stats -> gate GEMMs -> prepass ->
//           scan (reg-pipelined, D=5 deferral, 5-stage prefetch, 32-lane cols)
//           -> normgate -> out GEMM
// Record (per h,t; 664 shorts = 1328 B), index r = t+4 (recs 0..3 zero pads):
//   bytes: kw@0 qw@256 k@512 E@768 v@1024 sc@1280 (f32[12]: beta,qk,a1..4,qb1..4)
// Scan recurrence (deferral D=5):
//   pk_t = kw_t . S_{t-5} + sum_m a_m(t) d_{t-m};  d_t = beta (v_t - pk_t)
//   o_t  = qw_t . S_{t-5} + sum_m qb_m d_{t-m} + qk d_t
//   S_t  = E_t * S_{t-1} + k_t d_t
// Scan thread map: 32 lanes per column, 4 dims/thread; block = 8 cols;
// all stage loads forced into vmcnt domain (opaque per-lane zero) so
// ds_bpermute lgkm waits don't drain the prefetch pipeline.
// Plan A (ws >= ~267.6MB): both batches' P resident -> ONE scan launch (512 blk).
// Plan B (ws >= ~180.5MB): per-batch sequential (256 blk).
// ---------------------------------------------------------------------------

typedef __attribute__((ext_vector_type(8))) short bf16x8;
typedef __attribute__((ext_vector_type(4))) float floatx4;

#define TB 4096
#define RSH 664                      // shorts per record
#define RB 1328                      // bytes per record
#define NREC 4100                    // 4 zero pads + TB
#define BHSH ((size_t)NREC * RSH)    // shorts per (b,h) stream
#define TAILPAD (16 * RB)            // benign-overread pad after last stream

__device__ __forceinline__ float b2f(ushort u) {
    union { unsigned int u; float f; } c; c.u = ((unsigned int)u) << 16; return c.f;
}
__device__ __forceinline__ ushort f2b(float f) {
    union { float f; unsigned int u; } c; c.f = f;
    unsigned int r = (c.u + 0x7fffu + ((c.u >> 16) & 1u)) >> 16;
    return (ushort)r;
}
__device__ __forceinline__ float silu(float x) { return x / (1.0f + expf(-x)); }

// ---------------------------------------------------------------------------
__global__ __launch_bounds__(256) void cast_f32_bf16(const float* __restrict__ in,
                                                     ushort* __restrict__ out, int n) {
    int i = (blockIdx.x * 256 + threadIdx.x) * 4;
    int stride = gridDim.x * 256 * 4;
    for (; i + 3 < n; i += stride) {
        float4 v = *(const float4*)(in + i);
        ushort4 u;
        u.x = f2b(v.x); u.y = f2b(v.y); u.z = f2b(v.z); u.w = f2b(v.w);
        *(ushort4*)(out + i) = u;
    }
}

// ---------------------------------------------------------------------------
// bf16 MFMA GEMM: C[M][N] = A[M][K] @ B[N][K]^T  (row-major, K contiguous)
// ---------------------------------------------------------------------------
template <typename CT>
__global__ __launch_bounds__(256) void gemm_bf16(const ushort* __restrict__ A,
                                                 const ushort* __restrict__ B,
                                                 CT* __restrict__ C, int M, int N, int K) {
    __shared__ ushort As[128 * 40];
    __shared__ ushort Bs[128 * 40];
    const int tid = threadIdx.x;
    const int lane = tid & 63, wid = tid >> 6;
    const int wr = wid >> 1, wc = wid & 1;
    const int bm = blockIdx.y, bn = blockIdx.x;

    const int r0 = tid >> 2;
    const int kc0 = (tid & 3) * 8;
    const size_t aoff0 = (size_t)(bm * 128 + r0) * K + kc0;
    const size_t aoff1 = aoff0 + (size_t)64 * K;
    const size_t boff0 = (size_t)(bn * 128 + r0) * K + kc0;
    const size_t boff1 = boff0 + (size_t)64 * K;
    const int lw0 = r0 * 40 + kc0;
    const int lw1 = (r0 + 64) * 40 + kc0;

    const int arow = wr * 64 + (lane & 15);
    const int brow = wc * 64 + (lane & 15);
    const int kg = (lane >> 4) * 8;

    floatx4 acc[4][4];
#pragma unroll
    for (int m = 0; m < 4; ++m)
#pragma unroll
        for (int n = 0; n < 4; ++n) acc[m][n] = (floatx4){0.f, 0.f, 0.f, 0.f};

    uint4 ra0 = *(const uint4*)(A + aoff0);
    uint4 ra1 = *(const uint4*)(A + aoff1);
    uint4 rb0 = *(const uint4*)(B + boff0);
    uint4 rb1 = *(const uint4*)(B + boff1);

    for (int kt = 32; kt <= K; kt += 32) {
        __syncthreads();
        *(uint4*)(As + lw0) = ra0;
        *(uint4*)(As + lw1) = ra1;
        *(uint4*)(Bs + lw0) = rb0;
        *(uint4*)(Bs + lw1) = rb1;
        __syncthreads();
        if (kt < K) {
            ra0 = *(const uint4*)(A + aoff0 + kt);
            ra1 = *(const uint4*)(A + aoff1 + kt);
            rb0 = *(const uint4*)(B + boff0 + kt);
            rb1 = *(const uint4*)(B + boff1 + kt);
        }
        bf16x8 af[4], bfr[4];
#pragma unroll
        for (int m = 0; m < 4; ++m) af[m] = *(const bf16x8*)(As + (arow + m * 16) * 40 + kg);
#pragma unroll
        for (int n = 0; n < 4; ++n) bfr[n] = *(const bf16x8*)(Bs + (brow + n * 16) * 40 + kg);
#pragma unroll
        for (int m = 0; m < 4; ++m)
#pragma unroll
            for (int n = 0; n < 4; ++n)
                acc[m][n] = __builtin_amdgcn_mfma_f32_16x16x32_bf16(af[m], bfr[n], acc[m][n], 0, 0, 0);
    }

    const int crow0 = bm * 128 + wr * 64 + (lane >> 4) * 4;
    const int ccol0 = bn * 128 + wc * 64 + (lane & 15);
#pragma unroll
    for (int m = 0; m < 4; ++m)
#pragma unroll
        for (int n = 0; n < 4; ++n)
#pragma unroll
            for (int j = 0; j < 4; ++j) {
                int row = crow0 + m * 16 + j;
                int col = ccol0 + n * 16;
                if constexpr (sizeof(CT) == 2)
                    C[(size_t)row * N + col] = (CT)f2b(acc[m][n][j]);
                else
                    C[(size_t)row * N + col] = (CT)acc[m][n][j];
            }
}

// ---------------------------------------------------------------------------
// conv + silu + surprise stats + beta/amp MLPs -> record fields (one batch)
// ---------------------------------------------------------------------------
__global__ __launch_bounds__(256) void conv_stats_kernel(
    const ushort* __restrict__ qkv,
    const float* __restrict__ convq, const float* __restrict__ convk,
    const float* __restrict__ convv, const float* __restrict__ Wsv,
    const float* __restrict__ Wb1, const float* __restrict__ bb1,
    const float* __restrict__ Wb2, const float* __restrict__ bb2,
    const float* __restrict__ Wa1, const float* __restrict__ ba1,
    const float* __restrict__ Wa2, const float* __restrict__ ba2,
    const float* __restrict__ A_log, const float* __restrict__ dt_bias,
    ushort* __restrict__ P) {
    __shared__ ushort wsv_s[128 * 136];
    __shared__ float k_sh[4][128];
    // zero-fill pad records 0..3 for each h
    if (blockIdx.x == 0) {
        for (int z = threadIdx.x; z < 16 * 4 * RSH; z += 256) {
            int hh = z / (4 * RSH);
            int off = z % (4 * RSH);
            P[(size_t)hh * BHSH + off] = 0;
        }
    }
    for (int i = threadIdx.x; i < 128 * 128; i += 256) {
        int row = i >> 7, col = i & 127;
        wsv_s[row * 136 + col] = f2b(Wsv[i]);
    }
    __syncthreads();
    const int wid = threadIdx.x >> 6, lane = threadIdx.x & 63;

    for (int it = 0; it < 2; ++it) {
        const int pair = blockIdx.x * 8 + it * 4 + wid;   // [0, TB*16)
        const int t = pair >> 4, h = pair & 15;
        const int c0 = h * 128 + lane, c1 = c0 + 64;

        float wq[4], wq2[4], wk[4], wk2[4], wv[4], wv2[4];
#pragma unroll
        for (int i2 = 0; i2 < 4; ++i2) {
            wq[i2] = convq[c0 * 4 + i2]; wq2[i2] = convq[c1 * 4 + i2];
            wk[i2] = convk[c0 * 4 + i2]; wk2[i2] = convk[c1 * 4 + i2];
            wv[i2] = convv[c0 * 4 + i2]; wv2[i2] = convv[c1 * 4 + i2];
        }
        float aq0 = 0, aq1 = 0, ak0 = 0, ak1 = 0, av0 = 0, av1 = 0;
#pragma unroll
        for (int i2 = 0; i2 < 4; ++i2) {
            int tt = t - 3 + i2;
            if (tt >= 0) {
                const ushort* rowp = qkv + (size_t)tt * 6144 + h * 128;
                aq0 = fmaf(b2f(rowp[lane]), wq[i2], aq0);
                aq1 = fmaf(b2f(rowp[lane + 64]), wq2[i2], aq1);
                ak0 = fmaf(b2f(rowp[2048 + lane]), wk[i2], ak0);
                ak1 = fmaf(b2f(rowp[2048 + lane + 64]), wk2[i2], ak1);
                av0 = fmaf(b2f(rowp[4096 + lane]), wv[i2], av0);
                av1 = fmaf(b2f(rowp[4096 + lane + 64]), wv2[i2], av1);
            }
        }
        float q0 = silu(aq0), q1 = silu(aq1);
        float k0 = silu(ak0), k1 = silu(ak1);
        float v0 = silu(av0), v1 = silu(av1);

        __syncthreads();
        k_sh[wid][lane] = k0;
        k_sh[wid][lane + 64] = k1;
        __syncthreads();

        float vh0 = 0.f, vh1 = 0.f;
        const ushort* wr0 = wsv_s + lane * 136;
        const ushort* wr1 = wsv_s + (lane + 64) * 136;
#pragma unroll 4
        for (int j = 0; j < 128; j += 8) {
            float4 ka = *(const float4*)&k_sh[wid][j];
            float4 kb = *(const float4*)&k_sh[wid][j + 4];
            uint4 wa = *(const uint4*)(wr0 + j);
            uint4 wb = *(const uint4*)(wr1 + j);
            vh0 = fmaf(__uint_as_float(wa.x << 16), ka.x, vh0);
            vh0 = fmaf(__uint_as_float(wa.x & 0xffff0000u), ka.y, vh0);
            vh0 = fmaf(__uint_as_float(wa.y << 16), ka.z, vh0);
            vh0 = fmaf(__uint_as_float(wa.y & 0xffff0000u), ka.w, vh0);
            vh0 = fmaf(__uint_as_float(wa.z << 16), kb.x, vh0);
            vh0 = fmaf(__uint_as_float(wa.z & 0xffff0000u), kb.y, vh0);
            vh0 = fmaf(__uint_as_float(wa.w << 16), kb.z, vh0);
            vh0 = fmaf(__uint_as_float(wa.w & 0xffff0000u), kb.w, vh0);
            vh1 = fmaf(__uint_as_float(wb.x << 16), ka.x, vh1);
            vh1 = fmaf(__uint_as_float(wb.x & 0xffff0000u), ka.y, vh1);
            vh1 = fmaf(__uint_as_float(wb.y << 16), ka.z, vh1);
            vh1 = fmaf(__uint_as_float(wb.y & 0xffff0000u), ka.w, vh1);
            vh1 = fmaf(__uint_as_float(wb.z << 16), kb.x, vh1);
            vh1 = fmaf(__uint_as_float(wb.z & 0xffff0000u), kb.y, vh1);
            vh1 = fmaf(__uint_as_float(wb.w << 16), kb.z, vh1);
            vh1 = fmaf(__uint_as_float(wb.w & 0xffff0000u), kb.w, vh1);
        }

        float e0 = vh0 - v0, e1 = vh1 - v1;
        float se2 = e0 * e0 + e1 * e1;
        float sl1 = fabsf(e0) + fabsf(e1);
        float shv = vh0 * v0 + vh1 * v1;
        float shh = vh0 * vh0 + vh1 * vh1;
        float svv = v0 * v0 + v1 * v1;
        float sk2 = k0 * k0 + k1 * k1;
        float sq2 = q0 * q0 + q1 * q1;
#pragma unroll
        for (int m = 32; m >= 1; m >>= 1) {
            se2 += __shfl_xor(se2, m);
            sl1 += __shfl_xor(sl1, m);
            shv += __shfl_xor(shv, m);
            shh += __shfl_xor(shh, m);
            svv += __shfl_xor(svv, m);
            sk2 += __shfl_xor(sk2, m);
            sq2 += __shfl_xor(sq2, m);
        }
        float s_l2 = sqrtf(se2 + 1e-6f);
        float s_l1 = sl1;
        float s_cos = 1.0f - shv / (sqrtf(shh + 1e-6f) * sqrtf(svv + 1e-6f) + 1e-6f);

        const int j2 = lane & 31;
        const float* W1 = (lane < 32) ? Wb1 : Wa1;
        const float* b1 = (lane < 32) ? bb1 : ba1;
        const float* W2 = (lane < 32) ? Wb2 : Wa2;
        float pre = W1[j2 * 3] * s_l2 + W1[j2 * 3 + 1] * s_l1 + W1[j2 * 3 + 2] * s_cos + b1[j2];
        float val = W2[j2] * silu(pre);
#pragma unroll
        for (int m = 16; m >= 1; m >>= 1) val += __shfl_xor(val, m);
        float pre_b = __shfl(val, 0) + bb2[0];
        float pre_a = __shfl(val, 32) + ba2[0];
        float betav = 1.0f / (1.0f + expf(-pre_b));
        float amp = pre_a;

        float knorm = sqrtf(sk2);
        float rinv = amp / fmaxf(knorm, 1e-12f);
        float ah = expf(A_log[h]);
        float gr0 = fmaf(k0, rinv, dt_bias[c0]);
        float gr1 = fmaf(k1, rinv, dt_bias[c1]);
        float sp0 = (gr0 > 20.f) ? gr0 : log1pf(expf(gr0));
        float sp1 = (gr1 > 20.f) ? gr1 : log1pf(expf(gr1));

        ushort* rec = P + (size_t)h * BHSH + (size_t)(t + 4) * RSH;
        float kinv = rsqrtf(sk2 + 1e-6f);
        float qinv = rsqrtf(sq2 + 1e-6f) * 0.08838834764831845f;  // * DK^-0.5
        rec[128 + lane]      = f2b(q0 * qinv);     // q~ (prepass overwrites with qw)
        rec[128 + lane + 64] = f2b(q1 * qinv);
        rec[256 + lane]      = f2b(k0 * kinv);     // raw normalized k
        rec[256 + lane + 64] = f2b(k1 * kinv);
        rec[384 + lane]      = f2b(expf(-ah * sp0));  // E = exp(g)
        rec[384 + lane + 64] = f2b(expf(-ah * sp1));
        rec[512 + lane]      = f2b(v0);
        rec[512 + lane + 64] = f2b(v1);
        if (lane == 0) *(float*)(rec + 640) = betav;
    }
}

// ---------------------------------------------------------------------------
// prepass: kw = k*W5, qw = q~*W5 (W5 = prod_{i=0..4} E_{t-i}), scalars
// qk, a1..a4, qb1..qb4.  One wave per record; in-place.
// ---------------------------------------------------------------------------
__global__ __launch_bounds__(256) void prepass_kernel(ushort* __restrict__ P) {
    const int g = blockIdx.x * 4 + (threadIdx.x >> 6);
    const int bh = g >> 12, t = g & 4095;
    const int lane = threadIdx.x & 63;
    ushort* rec = P + (size_t)bh * BHSH + (size_t)(t + 4) * RSH;

    float kt0 = b2f(rec[256 + lane]), kt1 = b2f(rec[256 + lane + 64]);
    float qt0 = b2f(rec[128 + lane]), qt1 = b2f(rec[128 + lane + 64]);
    float a[4], qb[4];
    float wa = b2f(rec[384 + lane]), wb = b2f(rec[384 + lane + 64]);  // E_t
    float qk = qt0 * kt0 + qt1 * kt1;
#pragma unroll
    for (int m = 1; m <= 4; ++m) {
        const ushort* rp = rec - (size_t)m * RSH;
        float kp0 = b2f(rp[256 + lane]), kp1 = b2f(rp[256 + lane + 64]);
        a[m - 1]  = kt0 * wa * kp0 + kt1 * wb * kp1;
        qb[m - 1] = qt0 * wa * kp0 + qt1 * wb * kp1;
        float ep0 = b2f(rp[384 + lane]), ep1 = b2f(rp[384 + lane + 64]);
        wa *= ep0; wb *= ep1;   // after loop: wa = W5 per dim
    }
#pragma unroll
    for (int m = 32; m >= 1; m >>= 1) {
        qk += __shfl_xor(qk, m);
        a[0] += __shfl_xor(a[0], m); a[1] += __shfl_xor(a[1], m);
        a[2] += __shfl_xor(a[2], m); a[3] += __shfl_xor(a[3], m);
        qb[0] += __shfl_xor(qb[0], m); qb[1] += __shfl_xor(qb[1], m);
        qb[2] += __shfl_xor(qb[2], m); qb[3] += __shfl_xor(qb[3], m);
    }
    rec[lane]            = f2b(kt0 * wa);
    rec[lane + 64]       = f2b(kt1 * wb);
    rec[128 + lane]      = f2b(qt0 * wa);
    rec[128 + lane + 64] = f2b(qt1 * wb);
    if (lane == 0) {
        float* sc = (float*)(rec + 640);
        sc[1] = qk;
        sc[2] = a[0]; sc[3] = a[1]; sc[4] = a[2]; sc[5] = a[3];
        sc[6] = qb[0]; sc[7] = qb[1]; sc[8] = qb[2]; sc[9] = qb[3];
    }
}

// ---------------------------------------------------------------------------
// scan: 5-stage register prefetch, 32 lanes/col, 4 dims/thread, 8 cols/block.
// All stage loads in vmcnt domain (opaque per-lane zero on uniform addresses)
// so ds_bpermute lgkm waits don't drain SMEM prefetches.
// __launch_bounds__(256,2): 2 waves/SIMD for stall hiding.
// ---------------------------------------------------------------------------
struct Stage {
    uint2 kek, kee, kqw, kqq;
    uint vv;
    float4 s0, s1;
    float2 s2;
};

__device__ __forceinline__ void dec4(uint2 u, float* f) {
    f[0] = __uint_as_float(u.x << 16); f[1] = __uint_as_float(u.x & 0xffff0000u);
    f[2] = __uint_as_float(u.y << 16); f[3] = __uint_as_float(u.y & 0xffff0000u);
}

__global__ __launch_bounds__(256, 2) void scan_kernel(const ushort* __restrict__ P,
                                                      ushort* __restrict__ ob,
                                                      int smask, int sshift) {
    const int tid = threadIdx.x;
    const int l32 = tid & 31, cg = tid >> 5;
    const int s = blockIdx.x & smask;
    const int c = blockIdx.x >> sshift;
    const int b = s >> 4;
    const int h = s & 15;
    const int col = c * 8 + cg;
    // opaque per-lane zero: forces vector (vmcnt) loads for uniform addresses
    unsigned opq;
    asm volatile("v_mov_b32 %0, 0" : "=v"(opq));
    const char* gb = (const char*)(P + (size_t)s * BHSH);
    const char* gbv = gb + opq;
    ushort* op = ob + (size_t)b * TB * 2048 + h * 128 + col;
    const int lo = l32 * 8;         // 4 bf16 dims = 8 bytes per thread
    const int co = col * 2;

    auto ldst = [&](Stage& st, const char* pke, const char* pkq, const char* pvs) {
        st.kek = *(const uint2*)(pke + 512 + lo);
        st.kee = *(const uint2*)(pke + 768 + lo);
        st.kqw = *(const uint2*)(pkq + 0 + lo);
        st.kqq = *(const uint2*)(pkq + 256 + lo);
        st.vv  = *(const ushort*)(pvs + 1024 + co);
        st.s0  = *(const float4*)(pvs + 1280);
        st.s1  = *(const float4*)(pvs + 1296);
        st.s2  = *(const float2*)(pvs + 1312);
    };

    Stage A, B, C, D, E5;
    ldst(A, gbv + (size_t)0 * RB, gbv + (size_t)5 * RB, gbv + (size_t)2 * RB);
    ldst(B, gbv + (size_t)1 * RB, gbv + (size_t)6 * RB, gbv + (size_t)3 * RB);
    ldst(C, gbv + (size_t)2 * RB, gbv + (size_t)7 * RB, gbv + (size_t)4 * RB);
    ldst(D, gbv + (size_t)3 * RB, gbv + (size_t)8 * RB, gbv + (size_t)5 * RB);
    ldst(E5, gbv + (size_t)4 * RB, gbv + (size_t)9 * RB, gbv + (size_t)6 * RB);

    // rolling refill pointers: body J refills ke rec J+7, kq rec J+12, vs rec J+9
    const char* pke = gbv + (size_t)5 * RB;    // first body J=-2
    const char* pkq = gbv + (size_t)10 * RB;
    const char* pvs = gbv + (size_t)7 * RB;

    float S[4];
#pragma unroll
    for (int i = 0; i < 4; ++i) S[i] = 0.f;
    float d1 = 0.f, d2 = 0.f, d3 = 0.f, d4 = 0.f;
    float Ap = 0.f, Aq = 0.f, Bp = 0.f, Bq = 0.f, Cp = 0.f, Cq = 0.f;

    auto body = [&](int J, Stage& st) {
        float k4[4], e4[4], w4[4], q4[4];
        dec4(st.kek, k4); dec4(st.kee, e4);
        dec4(st.kqw, w4); dec4(st.kqq, q4);
        float vj = b2f((ushort)st.vv);
        float beta = st.s0.x, qk = st.s0.y;
        float a1 = st.s0.z, a2 = st.s0.w, a3 = st.s1.x, a4 = st.s1.y;
        float qb1 = st.s1.z, qb2 = st.s1.w, qb3 = st.s2.x, qb4 = st.s2.y;
        // refill (consumed 5 bodies later); rolling pointers
        ldst(st, pke, pkq, pvs);
        pke += RB; pkq += RB; pvs += RB;
        // compiler memory barrier: refill loads cannot sink below
        asm volatile("" ::: "memory");
        // S update: t = J-2
#pragma unroll
        for (int i = 0; i < 4; ++i) S[i] = fmaf(k4[i], d2, e4[i] * S[i]);
        // dots for t = J+3  (kw_{J+3} . S_{J-2})
        float pk = 0.f, pq = 0.f;
#pragma unroll
        for (int i = 0; i < 4; ++i) { pk = fmaf(w4[i], S[i], pk); pq = fmaf(q4[i], S[i], pq); }
        // scalar chain: t = J
        float pks = Cp + a1 * d1 + a2 * d2 + a3 * d3 + a4 * d4;
        float dl = beta * (vj - pks);
        float oo = Cq + qb1 * d1 + qb2 * d2 + qb3 * d3 + qb4 * d4 + qk * dl;
        if (J >= 0 && J < TB && l32 == 0) op[(size_t)J * 2048] = f2b(oo);
        // 5-level reduction spread over 3 bodies: A:(1)  B:(2,4)  C:(8,16)
        float tp = Bp + __shfl_xor(Bp, 8); Cp = tp + __shfl_xor(tp, 16);
        float tq = Bq + __shfl_xor(Bq, 8); Cq = tq + __shfl_xor(tq, 16);
        float up = Ap + __shfl_xor(Ap, 2); Bp = up + __shfl_xor(up, 4);
        float uq = Aq + __shfl_xor(Aq, 2); Bq = uq + __shfl_xor(uq, 4);
        Ap = pk + __shfl_xor(pk, 1); Aq = pq + __shfl_xor(pq, 1);
        d4 = d3; d3 = d2; d2 = d1; d1 = dl;
    };

    int J = -2;
    for (int it = 0; it < 820; ++it) {   // 820*5 = 4100 bodies: J = -2 .. 4097
        body(J, A);
        body(J + 1, B);
        body(J + 2, C);
        body(J + 3, D);
        body(J + 4, E5);
        J += 5;
    }
}

// ---------------------------------------------------------------------------
// gated RMS norm: og = bf16( o*rsqrt(mean o^2+1e-5)*norm_w*sigmoid(gate+bg2) )
// ---------------------------------------------------------------------------
__global__ __launch_bounds__(256) void normgate_kernel(
    const ushort* __restrict__ o, const ushort* __restrict__ gate,
    const float* __restrict__ bg2, const float* __restrict__ norm_w,
    ushort* __restrict__ og) {
    const int lane = threadIdx.x & 63;
    const int wstart = (blockIdx.x * 256 + threadIdx.x) >> 6;
    const int nw = (gridDim.x * 256) >> 6;
    for (int pair = wstart; pair < TB * 16; pair += nw) {
        const int t = pair >> 4, h = pair & 15;
        const size_t basep = (size_t)t * 2048 + h * 128 + lane * 2;
        unsigned int ovu = *(const unsigned int*)(o + basep);
        float o0 = __uint_as_float(ovu << 16);
        float o1 = __uint_as_float(ovu & 0xffff0000u);
        float ss = o0 * o0 + o1 * o1;
#pragma unroll
        for (int m = 32; m >= 1; m >>= 1) ss += __shfl_xor(ss, m);
        float rn = rsqrtf(ss * (1.0f / 128.0f) + 1e-5f);
        const int dg = h * 128 + lane * 2;
        unsigned int gv = *(const unsigned int*)(gate + basep);
        float g0 = __uint_as_float(gv << 16) + bg2[dg];
        float g1 = __uint_as_float(gv & 0xffff0000u) + bg2[dg + 1];
        float w0 = norm_w[lane * 2], w1 = norm_w[lane * 2 + 1];
        float r0 = o0 * rn * w0 / (1.0f + expf(-g0));
        float r1 = o1 * rn * w1 / (1.0f + expf(-g1));
        unsigned int outw = (unsigned int)f2b(r0) | ((unsigned int)f2b(r1) << 16);
        *(unsigned int*)(og + basep) = outw;
    }
}

// ---------------------------------------------------------------------------
extern "C" void kernel_launch(void* const* d_in, const int* in_sizes, int n_in,
                              void* d_out, int out_size, void* d_ws, size_t ws_size,
                              hipStream_t stream) {
    const float* x = (const float*)d_in[0];
    const float* Wq = (const float*)d_in[1];
    const float* Wk = (const float*)d_in[2];
    const float* Wv = (const float*)d_in[3];
    const float* convq = (const float*)d_in[4];
    const float* convk = (const float*)d_in[5];
    const float* convv = (const float*)d_in[6];
    const float* A_log = (const float*)d_in[7];
    const float* dt_bias = (const float*)d_in[8];
    const float* Wsv = (const float*)d_in[9];
    const float* Wb1 = (const float*)d_in[10];
    const float* bb1 = (const float*)d_in[11];
    const float* Wb2 = (const float*)d_in[12];
    const float* bb2 = (const float*)d_in[13];
    const float* Wa1 = (const float*)d_in[14];
    const float* ba1 = (const float*)d_in[15];
    const float* Wa2 = (const float*)d_in[16];
    const float* ba2 = (const float*)d_in[17];
    const float* Wg1 = (const float*)d_in[18];
    const float* Wg2 = (const float*)d_in[19];
    const float* bg2 = (const float*)d_in[20];
    const float* norm_w = (const float*)d_in[21];
    const float* Wo = (const float*)d_in[22];

    // ---- workspace layout (bytes) ----
    const size_t PBATCH   = (size_t)16 * BHSH * 2;      // 87,116,800 per batch
    const size_t OFF_WQKV = 0;                          // 25,165,824
    const size_t OFF_XB   = OFF_WQKV + 25165824;        // 16,777,216
    const size_t OFF_WG1  = OFF_XB + 16777216;          //    524,288
    const size_t OFF_WG2  = OFF_WG1 + 524288;           //    524,288
    const size_t OFF_QKV  = OFF_WG2 + 524288;           // 50,331,648
    const size_t OFF_P    = OFF_QKV + 50331648;         // = 93,323,264
    const size_t NEED_B   = OFF_P + PBATCH + TAILPAD;   // ~180.5 MB
    const size_t NEED_A   = OFF_P + 2 * PBATCH + TAILPAD;  // ~267.6 MB
    if (ws_size < NEED_B) return;  // diagnostic guard
    const bool planA = (ws_size >= NEED_A);

    char* ws = (char*)d_ws;
    ushort* wqkv = (ushort*)(ws + OFF_WQKV);
    ushort* xb   = (ushort*)(ws + OFF_XB);
    ushort* wg1b = (ushort*)(ws + OFF_WG1);
    ushort* wg2b = (ushort*)(ws + OFF_WG2);
    ushort* qkvb = (ushort*)(ws + OFF_QKV);
    ushort* P    = (ushort*)(ws + OFF_P);
    // phase-3 aliases in the dead qkv region:
    ushort* gateb = qkvb;                               // +0        16,777,216
    ushort* xg1b  = (ushort*)(ws + OFF_QKV + 16777216); // +16.78M    1,048,576
    ushort* ogb   = (ushort*)(ws + OFF_QKV + 17825792); // +17.83M   16,777,216
    ushort* wob   = (ushort*)(ws + OFF_QKV + 34603008); // +34.60M    8,388,608
    // scan output: planB -> xb region (per batch, 16.7MB);
    //              planA -> wqkv+xb contiguous span (both batches, 33.5MB; both dead)
    ushort* obp = planA ? (ushort*)(ws + OFF_WQKV) : xb;

    // weight casts
    cast_f32_bf16<<<512, 256, 0, stream>>>(Wq, wqkv, 4194304);
    cast_f32_bf16<<<512, 256, 0, stream>>>(Wk, wqkv + 4194304, 4194304);
    cast_f32_bf16<<<512, 256, 0, stream>>>(Wv, wqkv + 8388608, 4194304);
    cast_f32_bf16<<<64, 256, 0, stream>>>(Wg1, wg1b, 262144);
    cast_f32_bf16<<<64, 256, 0, stream>>>(Wg2, wg2b, 262144);

    if (planA) {
        for (int b = 0; b < 2; ++b) {
            cast_f32_bf16<<<512, 256, 0, stream>>>(x + (size_t)b * TB * 2048, xb, TB * 2048);
            gemm_bf16<ushort><<<dim3(48, TB / 128), 256, 0, stream>>>(xb, wqkv, qkvb, TB, 6144, 2048);
            conv_stats_kernel<<<TB * 16 / 8, 256, 0, stream>>>(qkvb, convq, convk, convv, Wsv,
                Wb1, bb1, Wb2, bb2, Wa1, ba1, Wa2, ba2, A_log, dt_bias,
                P + (size_t)b * 16 * BHSH);
        }
        prepass_kernel<<<32 * 1024, 256, 0, stream>>>(P);
        // ONE scan over both batches (512 blocks) -> obp (wqkv+xb span, now dead)
        scan_kernel<<<512, 256, 0, stream>>>(P, obp, 31, 5);
        // phase 3 (wqkv destroyed; qkv region reused for gate/xg1/og/wob)
        cast_f32_bf16<<<512, 256, 0, stream>>>(Wo, wob, 4194304);
        for (int b = 0; b < 2; ++b) {
            ushort* xstage = ogb;  // 16.7MB staging for x (og written later)
            cast_f32_bf16<<<512, 256, 0, stream>>>(x + (size_t)b * TB * 2048, xstage, TB * 2048);
            gemm_bf16<ushort><<<dim3(1, TB / 128), 256, 0, stream>>>(xstage, wg1b, xg1b, TB, 128, 2048);
            gemm_bf16<ushort><<<dim3(16, TB / 128), 256, 0, stream>>>(xg1b, wg2b, gateb, TB, 2048, 128);
            normgate_kernel<<<2048, 256, 0, stream>>>(obp + (size_t)b * TB * 2048, gateb, bg2, norm_w, ogb);
            gemm_bf16<float><<<dim3(16, TB / 128), 256, 0, stream>>>(ogb, wob,
                (float*)d_out + (size_t)b * TB * 2048, TB, 2048, 2048);
        }
    } else {
        for (int b = 0; b < 2; ++b) {
            const float* xbp = x + (size_t)b * TB * 2048;
            float* outp = (float*)d_out + (size_t)b * TB * 2048;
            cast_f32_bf16<<<512, 256, 0, stream>>>(xbp, xb, TB * 2048);
            gemm_bf16<ushort><<<dim3(48, TB / 128), 256, 0, stream>>>(xb, wqkv, qkvb, TB, 6144, 2048);
            conv_stats_kernel<<<TB * 16 / 8, 256, 0, stream>>>(qkvb, convq, convk, convv, Wsv,
                Wb1, bb1, Wb2, bb2, Wa1, ba1, Wa2, ba2, A_log, dt_bias, P);
            gemm_bf16<ushort><<<dim3(1, TB / 128), 256, 0, stream>>>(xb, wg1b, xg1b, TB, 128, 2048);
            gemm_bf16<ushort><<<dim3(16, TB / 128), 256, 0, stream>>>(xg1b, wg2b, gateb, TB, 2048, 128);
            cast_f32_bf16<<<512, 256, 0, stream>>>(Wo, wob, 4194304);
            prepass_kernel<<<16 * 1024, 256, 0, stream>>>(P);
            scan_kernel<<<256, 256, 0, stream>>>(P, xb, 15, 4);   // xb dead -> ob
            normgate_kernel<<<2048, 256, 0, stream>>>(xb, gateb, bg2, norm_w, ogb);
            gemm_bf16<float><<<dim3(16, TB / 128), 256, 0, stream>>>(ogb, wob, outp, TB, 2048, 2048);
        }
    }
}

// Round 9
// 2377.407 us; speedup vs baseline: 1.1899x; 1.1899x over previous
//
#include <hip/hip_runtime.h>
#include <hip/hip_bf16.h>

// ---------------------------------------------------------------------------
// SurpriseKimiDeltaAttention  (B=2, T=4096, H=2048, NH=16, DK=DV=128, CONV=4)
// Pipeline: cast -> qkv GEMM -> conv/stats -> gate GEMMs -> prepass ->
//           scan (reg-pipelined, D=5 deferral, 5-stage prefetch) ->
//           normgate -> out GEMM
// R9 = R7 structure + ALL scan stage loads forced into the vmcnt domain via
// an opaque per-lane zero added to the base pointer (prevents SMEM s_load,
// whose lgkmcnt waits at each ds_bpermute drained the prefetch pipeline).
// Record (per h,t; 664 shorts = 1328 B), index r = t+4 (recs 0..3 zero pads):
//   bytes: kw@0 qw@256 k@512 E@768 v@1024 sc@1280 (f32[12]: beta,qk,a1..4,qb1..4)
// Scan recurrence (deferral D=5):
//   pk_t = kw_t . S_{t-5} + sum_m a_m(t) d_{t-m};  d_t = beta (v_t - pk_t)
//   o_t  = qw_t . S_{t-5} + sum_m qb_m d_{t-m} + qk d_t
//   S_t  = E_t * S_{t-1} + k_t d_t
// Plan A (ws >= ~267.6MB): both batches' P resident -> ONE scan launch (256 blk).
// Plan B (ws >= ~180.5MB): per-batch sequential (128 blk).
// ---------------------------------------------------------------------------

typedef __attribute__((ext_vector_type(8))) short bf16x8;
typedef __attribute__((ext_vector_type(4))) float floatx4;

#define TB 4096
#define RSH 664                      // shorts per record
#define RB 1328                      // bytes per record
#define NREC 4100                    // 4 zero pads + TB
#define BHSH ((size_t)NREC * RSH)    // shorts per (b,h) stream
#define TAILPAD (16 * RB)            // benign-overread pad after last stream

__device__ __forceinline__ float b2f(ushort u) {
    union { unsigned int u; float f; } c; c.u = ((unsigned int)u) << 16; return c.f;
}
__device__ __forceinline__ ushort f2b(float f) {
    union { float f; unsigned int u; } c; c.f = f;
    unsigned int r = (c.u + 0x7fffu + ((c.u >> 16) & 1u)) >> 16;
    return (ushort)r;
}
__device__ __forceinline__ float silu(float x) { return x / (1.0f + expf(-x)); }

// ---------------------------------------------------------------------------
__global__ __launch_bounds__(256) void cast_f32_bf16(const float* __restrict__ in,
                                                     ushort* __restrict__ out, int n) {
    int i = (blockIdx.x * 256 + threadIdx.x) * 4;
    int stride = gridDim.x * 256 * 4;
    for (; i + 3 < n; i += stride) {
        float4 v = *(const float4*)(in + i);
        ushort4 u;
        u.x = f2b(v.x); u.y = f2b(v.y); u.z = f2b(v.z); u.w = f2b(v.w);
        *(ushort4*)(out + i) = u;
    }
}

// ---------------------------------------------------------------------------
// bf16 MFMA GEMM: C[M][N] = A[M][K] @ B[N][K]^T  (row-major, K contiguous)
// ---------------------------------------------------------------------------
template <typename CT>
__global__ __launch_bounds__(256) void gemm_bf16(const ushort* __restrict__ A,
                                                 const ushort* __restrict__ B,
                                                 CT* __restrict__ C, int M, int N, int K) {
    __shared__ ushort As[128 * 40];
    __shared__ ushort Bs[128 * 40];
    const int tid = threadIdx.x;
    const int lane = tid & 63, wid = tid >> 6;
    const int wr = wid >> 1, wc = wid & 1;
    const int bm = blockIdx.y, bn = blockIdx.x;

    const int r0 = tid >> 2;
    const int kc0 = (tid & 3) * 8;
    const size_t aoff0 = (size_t)(bm * 128 + r0) * K + kc0;
    const size_t aoff1 = aoff0 + (size_t)64 * K;
    const size_t boff0 = (size_t)(bn * 128 + r0) * K + kc0;
    const size_t boff1 = boff0 + (size_t)64 * K;
    const int lw0 = r0 * 40 + kc0;
    const int lw1 = (r0 + 64) * 40 + kc0;

    const int arow = wr * 64 + (lane & 15);
    const int brow = wc * 64 + (lane & 15);
    const int kg = (lane >> 4) * 8;

    floatx4 acc[4][4];
#pragma unroll
    for (int m = 0; m < 4; ++m)
#pragma unroll
        for (int n = 0; n < 4; ++n) acc[m][n] = (floatx4){0.f, 0.f, 0.f, 0.f};

    uint4 ra0 = *(const uint4*)(A + aoff0);
    uint4 ra1 = *(const uint4*)(A + aoff1);
    uint4 rb0 = *(const uint4*)(B + boff0);
    uint4 rb1 = *(const uint4*)(B + boff1);

    for (int kt = 32; kt <= K; kt += 32) {
        __syncthreads();
        *(uint4*)(As + lw0) = ra0;
        *(uint4*)(As + lw1) = ra1;
        *(uint4*)(Bs + lw0) = rb0;
        *(uint4*)(Bs + lw1) = rb1;
        __syncthreads();
        if (kt < K) {
            ra0 = *(const uint4*)(A + aoff0 + kt);
            ra1 = *(const uint4*)(A + aoff1 + kt);
            rb0 = *(const uint4*)(B + boff0 + kt);
            rb1 = *(const uint4*)(B + boff1 + kt);
        }
        bf16x8 af[4], bfr[4];
#pragma unroll
        for (int m = 0; m < 4; ++m) af[m] = *(const bf16x8*)(As + (arow + m * 16) * 40 + kg);
#pragma unroll
        for (int n = 0; n < 4; ++n) bfr[n] = *(const bf16x8*)(Bs + (brow + n * 16) * 40 + kg);
#pragma unroll
        for (int m = 0; m < 4; ++m)
#pragma unroll
            for (int n = 0; n < 4; ++n)
                acc[m][n] = __builtin_amdgcn_mfma_f32_16x16x32_bf16(af[m], bfr[n], acc[m][n], 0, 0, 0);
    }

    const int crow0 = bm * 128 + wr * 64 + (lane >> 4) * 4;
    const int ccol0 = bn * 128 + wc * 64 + (lane & 15);
#pragma unroll
    for (int m = 0; m < 4; ++m)
#pragma unroll
        for (int n = 0; n < 4; ++n)
#pragma unroll
            for (int j = 0; j < 4; ++j) {
                int row = crow0 + m * 16 + j;
                int col = ccol0 + n * 16;
                if constexpr (sizeof(CT) == 2)
                    C[(size_t)row * N + col] = (CT)f2b(acc[m][n][j]);
                else
                    C[(size_t)row * N + col] = (CT)acc[m][n][j];
            }
}

// ---------------------------------------------------------------------------
// conv + silu + surprise stats + beta/amp MLPs -> record fields (one batch)
// ---------------------------------------------------------------------------
__global__ __launch_bounds__(256) void conv_stats_kernel(
    const ushort* __restrict__ qkv,
    const float* __restrict__ convq, const float* __restrict__ convk,
    const float* __restrict__ convv, const float* __restrict__ Wsv,
    const float* __restrict__ Wb1, const float* __restrict__ bb1,
    const float* __restrict__ Wb2, const float* __restrict__ bb2,
    const float* __restrict__ Wa1, const float* __restrict__ ba1,
    const float* __restrict__ Wa2, const float* __restrict__ ba2,
    const float* __restrict__ A_log, const float* __restrict__ dt_bias,
    ushort* __restrict__ P) {
    __shared__ ushort wsv_s[128 * 136];
    __shared__ float k_sh[4][128];
    // zero-fill pad records 0..3 for each h
    if (blockIdx.x == 0) {
        for (int z = threadIdx.x; z < 16 * 4 * RSH; z += 256) {
            int hh = z / (4 * RSH);
            int off = z % (4 * RSH);
            P[(size_t)hh * BHSH + off] = 0;
        }
    }
    for (int i = threadIdx.x; i < 128 * 128; i += 256) {
        int row = i >> 7, col = i & 127;
        wsv_s[row * 136 + col] = f2b(Wsv[i]);
    }
    __syncthreads();
    const int wid = threadIdx.x >> 6, lane = threadIdx.x & 63;

    for (int it = 0; it < 2; ++it) {
        const int pair = blockIdx.x * 8 + it * 4 + wid;   // [0, TB*16)
        const int t = pair >> 4, h = pair & 15;
        const int c0 = h * 128 + lane, c1 = c0 + 64;

        float wq[4], wq2[4], wk[4], wk2[4], wv[4], wv2[4];
#pragma unroll
        for (int i2 = 0; i2 < 4; ++i2) {
            wq[i2] = convq[c0 * 4 + i2]; wq2[i2] = convq[c1 * 4 + i2];
            wk[i2] = convk[c0 * 4 + i2]; wk2[i2] = convk[c1 * 4 + i2];
            wv[i2] = convv[c0 * 4 + i2]; wv2[i2] = convv[c1 * 4 + i2];
        }
        float aq0 = 0, aq1 = 0, ak0 = 0, ak1 = 0, av0 = 0, av1 = 0;
#pragma unroll
        for (int i2 = 0; i2 < 4; ++i2) {
            int tt = t - 3 + i2;
            if (tt >= 0) {
                const ushort* rowp = qkv + (size_t)tt * 6144 + h * 128;
                aq0 = fmaf(b2f(rowp[lane]), wq[i2], aq0);
                aq1 = fmaf(b2f(rowp[lane + 64]), wq2[i2], aq1);
                ak0 = fmaf(b2f(rowp[2048 + lane]), wk[i2], ak0);
                ak1 = fmaf(b2f(rowp[2048 + lane + 64]), wk2[i2], ak1);
                av0 = fmaf(b2f(rowp[4096 + lane]), wv[i2], av0);
                av1 = fmaf(b2f(rowp[4096 + lane + 64]), wv2[i2], av1);
            }
        }
        float q0 = silu(aq0), q1 = silu(aq1);
        float k0 = silu(ak0), k1 = silu(ak1);
        float v0 = silu(av0), v1 = silu(av1);

        __syncthreads();
        k_sh[wid][lane] = k0;
        k_sh[wid][lane + 64] = k1;
        __syncthreads();

        float vh0 = 0.f, vh1 = 0.f;
        const ushort* wr0 = wsv_s + lane * 136;
        const ushort* wr1 = wsv_s + (lane + 64) * 136;
#pragma unroll 4
        for (int j = 0; j < 128; j += 8) {
            float4 ka = *(const float4*)&k_sh[wid][j];
            float4 kb = *(const float4*)&k_sh[wid][j + 4];
            uint4 wa = *(const uint4*)(wr0 + j);
            uint4 wb = *(const uint4*)(wr1 + j);
            vh0 = fmaf(__uint_as_float(wa.x << 16), ka.x, vh0);
            vh0 = fmaf(__uint_as_float(wa.x & 0xffff0000u), ka.y, vh0);
            vh0 = fmaf(__uint_as_float(wa.y << 16), ka.z, vh0);
            vh0 = fmaf(__uint_as_float(wa.y & 0xffff0000u), ka.w, vh0);
            vh0 = fmaf(__uint_as_float(wa.z << 16), kb.x, vh0);
            vh0 = fmaf(__uint_as_float(wa.z & 0xffff0000u), kb.y, vh0);
            vh0 = fmaf(__uint_as_float(wa.w << 16), kb.z, vh0);
            vh0 = fmaf(__uint_as_float(wa.w & 0xffff0000u), kb.w, vh0);
            vh1 = fmaf(__uint_as_float(wb.x << 16), ka.x, vh1);
            vh1 = fmaf(__uint_as_float(wb.x & 0xffff0000u), ka.y, vh1);
            vh1 = fmaf(__uint_as_float(wb.y << 16), ka.z, vh1);
            vh1 = fmaf(__uint_as_float(wb.y & 0xffff0000u), ka.w, vh1);
            vh1 = fmaf(__uint_as_float(wb.z << 16), kb.x, vh1);
            vh1 = fmaf(__uint_as_float(wb.z & 0xffff0000u), kb.y, vh1);
            vh1 = fmaf(__uint_as_float(wb.w << 16), kb.z, vh1);
            vh1 = fmaf(__uint_as_float(wb.w & 0xffff0000u), kb.w, vh1);
        }

        float e0 = vh0 - v0, e1 = vh1 - v1;
        float se2 = e0 * e0 + e1 * e1;
        float sl1 = fabsf(e0) + fabsf(e1);
        float shv = vh0 * v0 + vh1 * v1;
        float shh = vh0 * vh0 + vh1 * vh1;
        float svv = v0 * v0 + v1 * v1;
        float sk2 = k0 * k0 + k1 * k1;
        float sq2 = q0 * q0 + q1 * q1;
#pragma unroll
        for (int m = 32; m >= 1; m >>= 1) {
            se2 += __shfl_xor(se2, m);
            sl1 += __shfl_xor(sl1, m);
            shv += __shfl_xor(shv, m);
            shh += __shfl_xor(shh, m);
            svv += __shfl_xor(svv, m);
            sk2 += __shfl_xor(sk2, m);
            sq2 += __shfl_xor(sq2, m);
        }
        float s_l2 = sqrtf(se2 + 1e-6f);
        float s_l1 = sl1;
        float s_cos = 1.0f - shv / (sqrtf(shh + 1e-6f) * sqrtf(svv + 1e-6f) + 1e-6f);

        const int j2 = lane & 31;
        const float* W1 = (lane < 32) ? Wb1 : Wa1;
        const float* b1 = (lane < 32) ? bb1 : ba1;
        const float* W2 = (lane < 32) ? Wb2 : Wa2;
        float pre = W1[j2 * 3] * s_l2 + W1[j2 * 3 + 1] * s_l1 + W1[j2 * 3 + 2] * s_cos + b1[j2];
        float val = W2[j2] * silu(pre);
#pragma unroll
        for (int m = 16; m >= 1; m >>= 1) val += __shfl_xor(val, m);
        float pre_b = __shfl(val, 0) + bb2[0];
        float pre_a = __shfl(val, 32) + ba2[0];
        float betav = 1.0f / (1.0f + expf(-pre_b));
        float amp = pre_a;

        float knorm = sqrtf(sk2);
        float rinv = amp / fmaxf(knorm, 1e-12f);
        float ah = expf(A_log[h]);
        float gr0 = fmaf(k0, rinv, dt_bias[c0]);
        float gr1 = fmaf(k1, rinv, dt_bias[c1]);
        float sp0 = (gr0 > 20.f) ? gr0 : log1pf(expf(gr0));
        float sp1 = (gr1 > 20.f) ? gr1 : log1pf(expf(gr1));

        ushort* rec = P + (size_t)h * BHSH + (size_t)(t + 4) * RSH;
        float kinv = rsqrtf(sk2 + 1e-6f);
        float qinv = rsqrtf(sq2 + 1e-6f) * 0.08838834764831845f;  // * DK^-0.5
        rec[128 + lane]      = f2b(q0 * qinv);     // q~ (prepass overwrites with qw)
        rec[128 + lane + 64] = f2b(q1 * qinv);
        rec[256 + lane]      = f2b(k0 * kinv);     // raw normalized k
        rec[256 + lane + 64] = f2b(k1 * kinv);
        rec[384 + lane]      = f2b(expf(-ah * sp0));  // E = exp(g)
        rec[384 + lane + 64] = f2b(expf(-ah * sp1));
        rec[512 + lane]      = f2b(v0);
        rec[512 + lane + 64] = f2b(v1);
        if (lane == 0) *(float*)(rec + 640) = betav;
    }
}

// ---------------------------------------------------------------------------
// prepass: kw = k*W5, qw = q~*W5 (W5 = prod_{i=0..4} E_{t-i}), scalars
// qk, a1..a4, qb1..qb4.  One wave per record; in-place.
// ---------------------------------------------------------------------------
__global__ __launch_bounds__(256) void prepass_kernel(ushort* __restrict__ P) {
    const int g = blockIdx.x * 4 + (threadIdx.x >> 6);
    const int bh = g >> 12, t = g & 4095;
    const int lane = threadIdx.x & 63;
    ushort* rec = P + (size_t)bh * BHSH + (size_t)(t + 4) * RSH;

    float kt0 = b2f(rec[256 + lane]), kt1 = b2f(rec[256 + lane + 64]);
    float qt0 = b2f(rec[128 + lane]), qt1 = b2f(rec[128 + lane + 64]);
    float a[4], qb[4];
    float wa = b2f(rec[384 + lane]), wb = b2f(rec[384 + lane + 64]);  // E_t
    float qk = qt0 * kt0 + qt1 * kt1;
#pragma unroll
    for (int m = 1; m <= 4; ++m) {
        const ushort* rp = rec - (size_t)m * RSH;
        float kp0 = b2f(rp[256 + lane]), kp1 = b2f(rp[256 + lane + 64]);
        a[m - 1]  = kt0 * wa * kp0 + kt1 * wb * kp1;
        qb[m - 1] = qt0 * wa * kp0 + qt1 * wb * kp1;
        float ep0 = b2f(rp[384 + lane]), ep1 = b2f(rp[384 + lane + 64]);
        wa *= ep0; wb *= ep1;   // after loop: wa = W5 per dim
    }
#pragma unroll
    for (int m = 32; m >= 1; m >>= 1) {
        qk += __shfl_xor(qk, m);
        a[0] += __shfl_xor(a[0], m); a[1] += __shfl_xor(a[1], m);
        a[2] += __shfl_xor(a[2], m); a[3] += __shfl_xor(a[3], m);
        qb[0] += __shfl_xor(qb[0], m); qb[1] += __shfl_xor(qb[1], m);
        qb[2] += __shfl_xor(qb[2], m); qb[3] += __shfl_xor(qb[3], m);
    }
    rec[lane]            = f2b(kt0 * wa);
    rec[lane + 64]       = f2b(kt1 * wb);
    rec[128 + lane]      = f2b(qt0 * wa);
    rec[128 + lane + 64] = f2b(qt1 * wb);
    if (lane == 0) {
        float* sc = (float*)(rec + 640);
        sc[1] = qk;
        sc[2] = a[0]; sc[3] = a[1]; sc[4] = a[2]; sc[5] = a[3];
        sc[6] = qb[0]; sc[7] = qb[1]; sc[8] = qb[2]; sc[9] = qb[3];
    }
}

// ---------------------------------------------------------------------------
// scan: 5-stage register prefetch (distance 5), 16 lanes/col, 8 dims/thread.
// All stage loads forced into vmcnt domain via opaque per-lane zero so the
// ds_bpermute lgkmcnt waits don't drain in-flight SMEM stage prefetches.
// __launch_bounds__(256,1): 1 wave/SIMD -> up to 512 VGPR, no spill.
// Rolling load pointers (+RB per body); tail-padded P, no clamps.
// XCD swizzle: s = bid & smask (stream), c = bid >> sshift (col-block).
// ---------------------------------------------------------------------------
struct Stage {
    uint4 kek, kee, kqw, kqq;
    uint vv;
    float4 s0, s1;
    float2 s2;
};

__device__ __forceinline__ void dec8(uint4 u, float* f) {
    f[0] = __uint_as_float(u.x << 16); f[1] = __uint_as_float(u.x & 0xffff0000u);
    f[2] = __uint_as_float(u.y << 16); f[3] = __uint_as_float(u.y & 0xffff0000u);
    f[4] = __uint_as_float(u.z << 16); f[5] = __uint_as_float(u.z & 0xffff0000u);
    f[6] = __uint_as_float(u.w << 16); f[7] = __uint_as_float(u.w & 0xffff0000u);
}

__global__ __launch_bounds__(256, 1) void scan_kernel(const ushort* __restrict__ P,
                                                      ushort* __restrict__ ob,
                                                      int smask, int sshift) {
    const int tid = threadIdx.x;
    const int l16 = tid & 15, cg = tid >> 4;
    const int s = blockIdx.x & smask;
    const int c = blockIdx.x >> sshift;
    const int b = s >> 4;
    const int h = s & 15;
    const int col = c * 16 + cg;
    // opaque per-lane zero: forces vector (vmcnt-domain) loads even for
    // wave-uniform addresses (otherwise SMEM s_load -> lgkmcnt collision
    // with ds_bpermute drains the prefetch pipeline every body)
    unsigned opq;
    asm volatile("v_mov_b32 %0, 0" : "=v"(opq));
    const char* gb = (const char*)(P + (size_t)s * BHSH) + opq;
    ushort* op = ob + (size_t)b * TB * 2048 + h * 128 + col;
    const int lo = l16 * 16;
    const int co = col * 2;

    auto ldinit = [&](Stage& st, int rke, int rkq, int rvs) {
        const char* pa = gb + (size_t)rke * RB;
        const char* pb = gb + (size_t)rkq * RB;
        const char* pc = gb + (size_t)rvs * RB;
        st.kek = *(const uint4*)(pa + 512 + lo);
        st.kee = *(const uint4*)(pa + 768 + lo);
        st.kqw = *(const uint4*)(pb + 0 + lo);
        st.kqq = *(const uint4*)(pb + 256 + lo);
        st.vv  = *(const ushort*)(pc + 1024 + co);
        st.s0  = *(const float4*)(pc + 1280);
        st.s1  = *(const float4*)(pc + 1296);
        st.s2  = *(const float2*)(pc + 1312);
    };

    Stage A, B, C, D, E5;
    ldinit(A, 0, 5, 2); ldinit(B, 1, 6, 3); ldinit(C, 2, 7, 4);
    ldinit(D, 3, 8, 5); ldinit(E5, 4, 9, 6);

    // rolling refill pointers: body J refills ke rec J+7, kq rec J+12, vs rec J+9
    const char* pke = gb + (size_t)5 * RB;    // first body J=-2
    const char* pkq = gb + (size_t)10 * RB;
    const char* pvs = gb + (size_t)7 * RB;

    float S[8];
#pragma unroll
    for (int i = 0; i < 8; ++i) S[i] = 0.f;
    float d1 = 0.f, d2 = 0.f, d3 = 0.f, d4 = 0.f;
    float Ap = 0.f, Aq = 0.f, Bp = 0.f, Bq = 0.f, Cp = 0.f, Cq = 0.f;

    auto body = [&](int J, Stage& st) {
        float k8[8], e8[8], w8[8], q8[8];
        dec8(st.kek, k8); dec8(st.kee, e8);
        dec8(st.kqw, w8); dec8(st.kqq, q8);
        float vj = b2f((ushort)st.vv);
        float beta = st.s0.x, qk = st.s0.y;
        float a1 = st.s0.z, a2 = st.s0.w, a3 = st.s1.x, a4 = st.s1.y;
        float qb1 = st.s1.z, qb2 = st.s1.w, qb3 = st.s2.x, qb4 = st.s2.y;
        // refill (consumed 5 bodies later); rolling pointers, no muls/clamps
        st.kek = *(const uint4*)(pke + 512 + lo);
        st.kee = *(const uint4*)(pke + 768 + lo);
        st.kqw = *(const uint4*)(pkq + 0 + lo);
        st.kqq = *(const uint4*)(pkq + 256 + lo);
        st.vv  = *(const ushort*)(pvs + 1024 + co);
        st.s0  = *(const float4*)(pvs + 1280);
        st.s1  = *(const float4*)(pvs + 1296);
        st.s2  = *(const float2*)(pvs + 1312);
        pke += RB; pkq += RB; pvs += RB;
        // compiler memory barrier: refill loads cannot sink below
        asm volatile("" ::: "memory");
        // S update: t = J-2
#pragma unroll
        for (int i = 0; i < 8; ++i) S[i] = fmaf(k8[i], d2, e8[i] * S[i]);
        // dots for t = J+3  (kw_{J+3} . S_{J-2})
        float pk = 0.f, pq = 0.f;
#pragma unroll
        for (int i = 0; i < 8; ++i) { pk = fmaf(w8[i], S[i], pk); pq = fmaf(q8[i], S[i], pq); }
        // scalar chain: t = J
        float pks = Cp + a1 * d1 + a2 * d2 + a3 * d3 + a4 * d4;
        float dl = beta * (vj - pks);
        float oo = Cq + qb1 * d1 + qb2 * d2 + qb3 * d3 + qb4 * d4 + qk * dl;
        if (J >= 0 && J < TB && l16 == 0) op[(size_t)J * 2048] = f2b(oo);
        // reduction pipeline rotate (4 shfl levels spread over 3 bodies)
        float tp = Bp + __shfl_xor(Bp, 4); Cp = tp + __shfl_xor(tp, 8);
        float tq = Bq + __shfl_xor(Bq, 4); Cq = tq + __shfl_xor(tq, 8);
        Bp = Ap + __shfl_xor(Ap, 2); Bq = Aq + __shfl_xor(Aq, 2);
        Ap = pk + __shfl_xor(pk, 1); Aq = pq + __shfl_xor(pq, 1);
        d4 = d3; d3 = d2; d2 = d1; d1 = dl;
    };

    int J = -2;
    for (int it = 0; it < 820; ++it) {   // 820*5 = 4100 bodies: J = -2 .. 4097
        body(J, A);
        body(J + 1, B);
        body(J + 2, C);
        body(J + 3, D);
        body(J + 4, E5);
        J += 5;
    }
}

// ---------------------------------------------------------------------------
// gated RMS norm: og = bf16( o*rsqrt(mean o^2+1e-5)*norm_w*sigmoid(gate+bg2) )
// ---------------------------------------------------------------------------
__global__ __launch_bounds__(256) void normgate_kernel(
    const ushort* __restrict__ o, const ushort* __restrict__ gate,
    const float* __restrict__ bg2, const float* __restrict__ norm_w,
    ushort* __restrict__ og) {
    const int lane = threadIdx.x & 63;
    const int wstart = (blockIdx.x * 256 + threadIdx.x) >> 6;
    const int nw = (gridDim.x * 256) >> 6;
    for (int pair = wstart; pair < TB * 16; pair += nw) {
        const int t = pair >> 4, h = pair & 15;
        const size_t basep = (size_t)t * 2048 + h * 128 + lane * 2;
        unsigned int ovu = *(const unsigned int*)(o + basep);
        float o0 = __uint_as_float(ovu << 16);
        float o1 = __uint_as_float(ovu & 0xffff0000u);
        float ss = o0 * o0 + o1 * o1;
#pragma unroll
        for (int m = 32; m >= 1; m >>= 1) ss += __shfl_xor(ss, m);
        float rn = rsqrtf(ss * (1.0f / 128.0f) + 1e-5f);
        const int dg = h * 128 + lane * 2;
        unsigned int gv = *(const unsigned int*)(gate + basep);
        float g0 = __uint_as_float(gv << 16) + bg2[dg];
        float g1 = __uint_as_float(gv & 0xffff0000u) + bg2[dg + 1];
        float w0 = norm_w[lane * 2], w1 = norm_w[lane * 2 + 1];
        float r0 = o0 * rn * w0 / (1.0f + expf(-g0));
        float r1 = o1 * rn * w1 / (1.0f + expf(-g1));
        unsigned int outw = (unsigned int)f2b(r0) | ((unsigned int)f2b(r1) << 16);
        *(unsigned int*)(og + basep) = outw;
    }
}

// ---------------------------------------------------------------------------
extern "C" void kernel_launch(void* const* d_in, const int* in_sizes, int n_in,
                              void* d_out, int out_size, void* d_ws, size_t ws_size,
                              hipStream_t stream) {
    const float* x = (const float*)d_in[0];
    const float* Wq = (const float*)d_in[1];
    const float* Wk = (const float*)d_in[2];
    const float* Wv = (const float*)d_in[3];
    const float* convq = (const float*)d_in[4];
    const float* convk = (const float*)d_in[5];
    const float* convv = (const float*)d_in[6];
    const float* A_log = (const float*)d_in[7];
    const float* dt_bias = (const float*)d_in[8];
    const float* Wsv = (const float*)d_in[9];
    const float* Wb1 = (const float*)d_in[10];
    const float* bb1 = (const float*)d_in[11];
    const float* Wb2 = (const float*)d_in[12];
    const float* bb2 = (const float*)d_in[13];
    const float* Wa1 = (const float*)d_in[14];
    const float* ba1 = (const float*)d_in[15];
    const float* Wa2 = (const float*)d_in[16];
    const float* ba2 = (const float*)d_in[17];
    const float* Wg1 = (const float*)d_in[18];
    const float* Wg2 = (const float*)d_in[19];
    const float* bg2 = (const float*)d_in[20];
    const float* norm_w = (const float*)d_in[21];
    const float* Wo = (const float*)d_in[22];

    // ---- workspace layout (bytes) ----
    const size_t PBATCH   = (size_t)16 * BHSH * 2;      // 87,116,800 per batch
    const size_t OFF_WQKV = 0;                          // 25,165,824
    const size_t OFF_XB   = OFF_WQKV + 25165824;        // 16,777,216
    const size_t OFF_WG1  = OFF_XB + 16777216;          //    524,288
    const size_t OFF_WG2  = OFF_WG1 + 524288;           //    524,288
    const size_t OFF_QKV  = OFF_WG2 + 524288;           // 50,331,648
    const size_t OFF_P    = OFF_QKV + 50331648;         // = 93,323,264
    const size_t NEED_B   = OFF_P + PBATCH + TAILPAD;   // ~180.5 MB
    const size_t NEED_A   = OFF_P + 2 * PBATCH + TAILPAD;  // ~267.6 MB
    if (ws_size < NEED_B) return;  // diagnostic guard
    const bool planA = (ws_size >= NEED_A);

    char* ws = (char*)d_ws;
    ushort* wqkv = (ushort*)(ws + OFF_WQKV);
    ushort* xb   = (ushort*)(ws + OFF_XB);
    ushort* wg1b = (ushort*)(ws + OFF_WG1);
    ushort* wg2b = (ushort*)(ws + OFF_WG2);
    ushort* qkvb = (ushort*)(ws + OFF_QKV);
    ushort* P    = (ushort*)(ws + OFF_P);
    // phase-3 aliases in the dead qkv region:
    ushort* gateb = qkvb;                               // +0        16,777,216
    ushort* xg1b  = (ushort*)(ws + OFF_QKV + 16777216); // +16.78M    1,048,576
    ushort* ogb   = (ushort*)(ws + OFF_QKV + 17825792); // +17.83M   16,777,216
    ushort* wob   = (ushort*)(ws + OFF_QKV + 34603008); // +34.60M    8,388,608
    // scan output: planB -> xb region (per batch, 16.7MB);
    //              planA -> wqkv+xb contiguous span (both batches, 33.5MB; both dead)
    ushort* obp = planA ? (ushort*)(ws + OFF_WQKV) : xb;

    // weight casts
    cast_f32_bf16<<<512, 256, 0, stream>>>(Wq, wqkv, 4194304);
    cast_f32_bf16<<<512, 256, 0, stream>>>(Wk, wqkv + 4194304, 4194304);
    cast_f32_bf16<<<512, 256, 0, stream>>>(Wv, wqkv + 8388608, 4194304);
    cast_f32_bf16<<<64, 256, 0, stream>>>(Wg1, wg1b, 262144);
    cast_f32_bf16<<<64, 256, 0, stream>>>(Wg2, wg2b, 262144);

    if (planA) {
        for (int b = 0; b < 2; ++b) {
            cast_f32_bf16<<<512, 256, 0, stream>>>(x + (size_t)b * TB * 2048, xb, TB * 2048);
            gemm_bf16<ushort><<<dim3(48, TB / 128), 256, 0, stream>>>(xb, wqkv, qkvb, TB, 6144, 2048);
            conv_stats_kernel<<<TB * 16 / 8, 256, 0, stream>>>(qkvb, convq, convk, convv, Wsv,
                Wb1, bb1, Wb2, bb2, Wa1, ba1, Wa2, ba2, A_log, dt_bias,
                P + (size_t)b * 16 * BHSH);
        }
        prepass_kernel<<<32 * 1024, 256, 0, stream>>>(P);
        // ONE scan over both batches (256 blocks) -> obp (wqkv+xb span, now dead)
        scan_kernel<<<256, 256, 0, stream>>>(P, obp, 31, 5);
        // phase 3 (wqkv destroyed; qkv region reused for gate/xg1/og/wob)
        cast_f32_bf16<<<512, 256, 0, stream>>>(Wo, wob, 4194304);
        for (int b = 0; b < 2; ++b) {
            ushort* xstage = ogb;  // 16.7MB staging for x (og written later)
            cast_f32_bf16<<<512, 256, 0, stream>>>(x + (size_t)b * TB * 2048, xstage, TB * 2048);
            gemm_bf16<ushort><<<dim3(1, TB / 128), 256, 0, stream>>>(xstage, wg1b, xg1b, TB, 128, 2048);
            gemm_bf16<ushort><<<dim3(16, TB / 128), 256, 0, stream>>>(xg1b, wg2b, gateb, TB, 2048, 128);
            normgate_kernel<<<2048, 256, 0, stream>>>(obp + (size_t)b * TB * 2048, gateb, bg2, norm_w, ogb);
            gemm_bf16<float><<<dim3(16, TB / 128), 256, 0, stream>>>(ogb, wob,
                (float*)d_out + (size_t)b * TB * 2048, TB, 2048, 2048);
        }
    } else {
        for (int b = 0; b < 2; ++b) {
            const float* xbp = x + (size_t)b * TB * 2048;
            float* outp = (float*)d_out + (size_t)b * TB * 2048;
            cast_f32_bf16<<<512, 256, 0, stream>>>(xbp, xb, TB * 2048);
            gemm_bf16<ushort><<<dim3(48, TB / 128), 256, 0, stream>>>(xb, wqkv, qkvb, TB, 6144, 2048);
            conv_stats_kernel<<<TB * 16 / 8, 256, 0, stream>>>(qkvb, convq, convk, convv, Wsv,
                Wb1, bb1, Wb2, bb2, Wa1, ba1, Wa2, ba2, A_log, dt_bias, P);
            gemm_bf16<ushort><<<dim3(1, TB / 128), 256, 0, stream>>>(xb, wg1b, xg1b, TB, 128, 2048);
            gemm_bf16<ushort><<<dim3(16, TB / 128), 256, 0, stream>>>(xg1b, wg2b, gateb, TB, 2048, 128);
            cast_f32_bf16<<<512, 256, 0, stream>>>(Wo, wob, 4194304);
            prepass_kernel<<<16 * 1024, 256, 0, stream>>>(P);
            scan_kernel<<<128, 256, 0, stream>>>(P, xb, 15, 4);   // xb dead -> ob
            normgate_kernel<<<2048, 256, 0, stream>>>(xb, gateb, bg2, norm_w, ogb);
            gemm_bf16<float><<<dim3(16, TB / 128), 256, 0, stream>>>(ogb, wob, outp, TB, 2048, 2048);
        }
    }
}

// Round 10
// 2377.143 us; speedup vs baseline: 1.1901x; 1.0001x over previous
//
#include <hip/hip_runtime.h>
#include <hip/hip_bf16.h>

// ---------------------------------------------------------------------------
// SurpriseKimiDeltaAttention  (B=2, T=4096, H=2048, NH=16, DK=DV=128, CONV=4)
// Pipeline: cast -> qkv GEMM -> conv/stats -> gate GEMMs -> prepass ->
//           scan (reg-pipelined, D=5 deferral, 5-stage prefetch,
//                 1-shfl-level-per-body pipelined reduction) ->
//           normgate -> out GEMM
// Record (per h,t; 664 shorts = 1328 B), index r = t+8 (recs 0..7 zero pads):
//   bytes: kw@0 qw@256 k@512 E@768 v@1024 sc@1280 (f32[12]: beta,qk,a1..4,qb1..4)
// Scan recurrence (deferral D=5):
//   pk_t = kw_t . S_{t-5} + sum_m a_m(t) d_{t-m};  d_t = beta (v_t - pk_t)
//   o_t  = qw_t . S_{t-5} + sum_m qb_m d_{t-m} + qk d_t
//   S_t  = E_t * S_{t-1} + k_t d_t
// Body X: S-update with (k,E,d) of t=X-1; dot kw_{X+4}.S_{X-1}; the 16-lane
// reduction runs one shfl level per body (result consumed next body ->
// bpermute latency fully hidden); scalar chain + store for t=X.
// Plan A (ws >= ~267.8MB): both batches' P resident -> ONE scan launch (256 blk).
// Plan B (ws >= ~180.6MB): per-batch sequential (128 blk).
// ---------------------------------------------------------------------------

typedef __attribute__((ext_vector_type(8))) short bf16x8;
typedef __attribute__((ext_vector_type(4))) float floatx4;

#define TB 4096
#define RSH 664                      // shorts per record
#define RB 1328                      // bytes per record
#define NREC 4104                    // 8 zero pads + TB
#define BHSH ((size_t)NREC * RSH)    // shorts per (b,h) stream
#define TAILPAD (16 * RB)            // benign-overread pad after last stream

__device__ __forceinline__ float b2f(ushort u) {
    union { unsigned int u; float f; } c; c.u = ((unsigned int)u) << 16; return c.f;
}
__device__ __forceinline__ ushort f2b(float f) {
    union { float f; unsigned int u; } c; c.f = f;
    unsigned int r = (c.u + 0x7fffu + ((c.u >> 16) & 1u)) >> 16;
    return (ushort)r;
}
__device__ __forceinline__ float silu(float x) { return x / (1.0f + expf(-x)); }

// ---------------------------------------------------------------------------
__global__ __launch_bounds__(256) void cast_f32_bf16(const float* __restrict__ in,
                                                     ushort* __restrict__ out, int n) {
    int i = (blockIdx.x * 256 + threadIdx.x) * 4;
    int stride = gridDim.x * 256 * 4;
    for (; i + 3 < n; i += stride) {
        float4 v = *(const float4*)(in + i);
        ushort4 u;
        u.x = f2b(v.x); u.y = f2b(v.y); u.z = f2b(v.z); u.w = f2b(v.w);
        *(ushort4*)(out + i) = u;
    }
}

// ---------------------------------------------------------------------------
// bf16 MFMA GEMM: C[M][N] = A[M][K] @ B[N][K]^T  (row-major, K contiguous)
// ---------------------------------------------------------------------------
template <typename CT>
__global__ __launch_bounds__(256) void gemm_bf16(const ushort* __restrict__ A,
                                                 const ushort* __restrict__ B,
                                                 CT* __restrict__ C, int M, int N, int K) {
    __shared__ ushort As[128 * 40];
    __shared__ ushort Bs[128 * 40];
    const int tid = threadIdx.x;
    const int lane = tid & 63, wid = tid >> 6;
    const int wr = wid >> 1, wc = wid & 1;
    const int bm = blockIdx.y, bn = blockIdx.x;

    const int r0 = tid >> 2;
    const int kc0 = (tid & 3) * 8;
    const size_t aoff0 = (size_t)(bm * 128 + r0) * K + kc0;
    const size_t aoff1 = aoff0 + (size_t)64 * K;
    const size_t boff0 = (size_t)(bn * 128 + r0) * K + kc0;
    const size_t boff1 = boff0 + (size_t)64 * K;
    const int lw0 = r0 * 40 + kc0;
    const int lw1 = (r0 + 64) * 40 + kc0;

    const int arow = wr * 64 + (lane & 15);
    const int brow = wc * 64 + (lane & 15);
    const int kg = (lane >> 4) * 8;

    floatx4 acc[4][4];
#pragma unroll
    for (int m = 0; m < 4; ++m)
#pragma unroll
        for (int n = 0; n < 4; ++n) acc[m][n] = (floatx4){0.f, 0.f, 0.f, 0.f};

    uint4 ra0 = *(const uint4*)(A + aoff0);
    uint4 ra1 = *(const uint4*)(A + aoff1);
    uint4 rb0 = *(const uint4*)(B + boff0);
    uint4 rb1 = *(const uint4*)(B + boff1);

    for (int kt = 32; kt <= K; kt += 32) {
        __syncthreads();
        *(uint4*)(As + lw0) = ra0;
        *(uint4*)(As + lw1) = ra1;
        *(uint4*)(Bs + lw0) = rb0;
        *(uint4*)(Bs + lw1) = rb1;
        __syncthreads();
        if (kt < K) {
            ra0 = *(const uint4*)(A + aoff0 + kt);
            ra1 = *(const uint4*)(A + aoff1 + kt);
            rb0 = *(const uint4*)(B + boff0 + kt);
            rb1 = *(const uint4*)(B + boff1 + kt);
        }
        bf16x8 af[4], bfr[4];
#pragma unroll
        for (int m = 0; m < 4; ++m) af[m] = *(const bf16x8*)(As + (arow + m * 16) * 40 + kg);
#pragma unroll
        for (int n = 0; n < 4; ++n) bfr[n] = *(const bf16x8*)(Bs + (brow + n * 16) * 40 + kg);
#pragma unroll
        for (int m = 0; m < 4; ++m)
#pragma unroll
            for (int n = 0; n < 4; ++n)
                acc[m][n] = __builtin_amdgcn_mfma_f32_16x16x32_bf16(af[m], bfr[n], acc[m][n], 0, 0, 0);
    }

    const int crow0 = bm * 128 + wr * 64 + (lane >> 4) * 4;
    const int ccol0 = bn * 128 + wc * 64 + (lane & 15);
#pragma unroll
    for (int m = 0; m < 4; ++m)
#pragma unroll
        for (int n = 0; n < 4; ++n)
#pragma unroll
            for (int j = 0; j < 4; ++j) {
                int row = crow0 + m * 16 + j;
                int col = ccol0 + n * 16;
                if constexpr (sizeof(CT) == 2)
                    C[(size_t)row * N + col] = (CT)f2b(acc[m][n][j]);
                else
                    C[(size_t)row * N + col] = (CT)acc[m][n][j];
            }
}

// ---------------------------------------------------------------------------
// conv + silu + surprise stats + beta/amp MLPs -> record fields (one batch)
// ---------------------------------------------------------------------------
__global__ __launch_bounds__(256) void conv_stats_kernel(
    const ushort* __restrict__ qkv,
    const float* __restrict__ convq, const float* __restrict__ convk,
    const float* __restrict__ convv, const float* __restrict__ Wsv,
    const float* __restrict__ Wb1, const float* __restrict__ bb1,
    const float* __restrict__ Wb2, const float* __restrict__ bb2,
    const float* __restrict__ Wa1, const float* __restrict__ ba1,
    const float* __restrict__ Wa2, const float* __restrict__ ba2,
    const float* __restrict__ A_log, const float* __restrict__ dt_bias,
    ushort* __restrict__ P) {
    __shared__ ushort wsv_s[128 * 136];
    __shared__ float k_sh[4][128];
    // zero-fill pad records 0..7 for each h
    if (blockIdx.x == 0) {
        for (int z = threadIdx.x; z < 16 * 8 * RSH; z += 256) {
            int hh = z / (8 * RSH);
            int off = z % (8 * RSH);
            P[(size_t)hh * BHSH + off] = 0;
        }
    }
    for (int i = threadIdx.x; i < 128 * 128; i += 256) {
        int row = i >> 7, col = i & 127;
        wsv_s[row * 136 + col] = f2b(Wsv[i]);
    }
    __syncthreads();
    const int wid = threadIdx.x >> 6, lane = threadIdx.x & 63;

    for (int it = 0; it < 2; ++it) {
        const int pair = blockIdx.x * 8 + it * 4 + wid;   // [0, TB*16)
        const int t = pair >> 4, h = pair & 15;
        const int c0 = h * 128 + lane, c1 = c0 + 64;

        float wq[4], wq2[4], wk[4], wk2[4], wv[4], wv2[4];
#pragma unroll
        for (int i2 = 0; i2 < 4; ++i2) {
            wq[i2] = convq[c0 * 4 + i2]; wq2[i2] = convq[c1 * 4 + i2];
            wk[i2] = convk[c0 * 4 + i2]; wk2[i2] = convk[c1 * 4 + i2];
            wv[i2] = convv[c0 * 4 + i2]; wv2[i2] = convv[c1 * 4 + i2];
        }
        float aq0 = 0, aq1 = 0, ak0 = 0, ak1 = 0, av0 = 0, av1 = 0;
#pragma unroll
        for (int i2 = 0; i2 < 4; ++i2) {
            int tt = t - 3 + i2;
            if (tt >= 0) {
                const ushort* rowp = qkv + (size_t)tt * 6144 + h * 128;
                aq0 = fmaf(b2f(rowp[lane]), wq[i2], aq0);
                aq1 = fmaf(b2f(rowp[lane + 64]), wq2[i2], aq1);
                ak0 = fmaf(b2f(rowp[2048 + lane]), wk[i2], ak0);
                ak1 = fmaf(b2f(rowp[2048 + lane + 64]), wk2[i2], ak1);
                av0 = fmaf(b2f(rowp[4096 + lane]), wv[i2], av0);
                av1 = fmaf(b2f(rowp[4096 + lane + 64]), wv2[i2], av1);
            }
        }
        float q0 = silu(aq0), q1 = silu(aq1);
        float k0 = silu(ak0), k1 = silu(ak1);
        float v0 = silu(av0), v1 = silu(av1);

        __syncthreads();
        k_sh[wid][lane] = k0;
        k_sh[wid][lane + 64] = k1;
        __syncthreads();

        float vh0 = 0.f, vh1 = 0.f;
        const ushort* wr0 = wsv_s + lane * 136;
        const ushort* wr1 = wsv_s + (lane + 64) * 136;
#pragma unroll 4
        for (int j = 0; j < 128; j += 8) {
            float4 ka = *(const float4*)&k_sh[wid][j];
            float4 kb = *(const float4*)&k_sh[wid][j + 4];
            uint4 wa = *(const uint4*)(wr0 + j);
            uint4 wb = *(const uint4*)(wr1 + j);
            vh0 = fmaf(__uint_as_float(wa.x << 16), ka.x, vh0);
            vh0 = fmaf(__uint_as_float(wa.x & 0xffff0000u), ka.y, vh0);
            vh0 = fmaf(__uint_as_float(wa.y << 16), ka.z, vh0);
            vh0 = fmaf(__uint_as_float(wa.y & 0xffff0000u), ka.w, vh0);
            vh0 = fmaf(__uint_as_float(wa.z << 16), kb.x, vh0);
            vh0 = fmaf(__uint_as_float(wa.z & 0xffff0000u), kb.y, vh0);
            vh0 = fmaf(__uint_as_float(wa.w << 16), kb.z, vh0);
            vh0 = fmaf(__uint_as_float(wa.w & 0xffff0000u), kb.w, vh0);
            vh1 = fmaf(__uint_as_float(wb.x << 16), ka.x, vh1);
            vh1 = fmaf(__uint_as_float(wb.x & 0xffff0000u), ka.y, vh1);
            vh1 = fmaf(__uint_as_float(wb.y << 16), ka.z, vh1);
            vh1 = fmaf(__uint_as_float(wb.y & 0xffff0000u), ka.w, vh1);
            vh1 = fmaf(__uint_as_float(wb.z << 16), kb.x, vh1);
            vh1 = fmaf(__uint_as_float(wb.z & 0xffff0000u), kb.y, vh1);
            vh1 = fmaf(__uint_as_float(wb.w << 16), kb.z, vh1);
            vh1 = fmaf(__uint_as_float(wb.w & 0xffff0000u), kb.w, vh1);
        }

        float e0 = vh0 - v0, e1 = vh1 - v1;
        float se2 = e0 * e0 + e1 * e1;
        float sl1 = fabsf(e0) + fabsf(e1);
        float shv = vh0 * v0 + vh1 * v1;
        float shh = vh0 * vh0 + vh1 * vh1;
        float svv = v0 * v0 + v1 * v1;
        float sk2 = k0 * k0 + k1 * k1;
        float sq2 = q0 * q0 + q1 * q1;
#pragma unroll
        for (int m = 32; m >= 1; m >>= 1) {
            se2 += __shfl_xor(se2, m);
            sl1 += __shfl_xor(sl1, m);
            shv += __shfl_xor(shv, m);
            shh += __shfl_xor(shh, m);
            svv += __shfl_xor(svv, m);
            sk2 += __shfl_xor(sk2, m);
            sq2 += __shfl_xor(sq2, m);
        }
        float s_l2 = sqrtf(se2 + 1e-6f);
        float s_l1 = sl1;
        float s_cos = 1.0f - shv / (sqrtf(shh + 1e-6f) * sqrtf(svv + 1e-6f) + 1e-6f);

        const int j2 = lane & 31;
        const float* W1 = (lane < 32) ? Wb1 : Wa1;
        const float* b1 = (lane < 32) ? bb1 : ba1;
        const float* W2 = (lane < 32) ? Wb2 : Wa2;
        float pre = W1[j2 * 3] * s_l2 + W1[j2 * 3 + 1] * s_l1 + W1[j2 * 3 + 2] * s_cos + b1[j2];
        float val = W2[j2] * silu(pre);
#pragma unroll
        for (int m = 16; m >= 1; m >>= 1) val += __shfl_xor(val, m);
        float pre_b = __shfl(val, 0) + bb2[0];
        float pre_a = __shfl(val, 32) + ba2[0];
        float betav = 1.0f / (1.0f + expf(-pre_b));
        float amp = pre_a;

        float knorm = sqrtf(sk2);
        float rinv = amp / fmaxf(knorm, 1e-12f);
        float ah = expf(A_log[h]);
        float gr0 = fmaf(k0, rinv, dt_bias[c0]);
        float gr1 = fmaf(k1, rinv, dt_bias[c1]);
        float sp0 = (gr0 > 20.f) ? gr0 : log1pf(expf(gr0));
        float sp1 = (gr1 > 20.f) ? gr1 : log1pf(expf(gr1));

        ushort* rec = P + (size_t)h * BHSH + (size_t)(t + 8) * RSH;
        float kinv = rsqrtf(sk2 + 1e-6f);
        float qinv = rsqrtf(sq2 + 1e-6f) * 0.08838834764831845f;  // * DK^-0.5
        rec[128 + lane]      = f2b(q0 * qinv);     // q~ (prepass overwrites with qw)
        rec[128 + lane + 64] = f2b(q1 * qinv);
        rec[256 + lane]      = f2b(k0 * kinv);     // raw normalized k
        rec[256 + lane + 64] = f2b(k1 * kinv);
        rec[384 + lane]      = f2b(expf(-ah * sp0));  // E = exp(g)
        rec[384 + lane + 64] = f2b(expf(-ah * sp1));
        rec[512 + lane]      = f2b(v0);
        rec[512 + lane + 64] = f2b(v1);
        if (lane == 0) *(float*)(rec + 640) = betav;
    }
}

// ---------------------------------------------------------------------------
// prepass: kw = k*W5, qw = q~*W5 (W5 = prod_{i=0..4} E_{t-i}), scalars
// qk, a1..a4, qb1..qb4.  One wave per record; in-place.
// ---------------------------------------------------------------------------
__global__ __launch_bounds__(256) void prepass_kernel(ushort* __restrict__ P) {
    const int g = blockIdx.x * 4 + (threadIdx.x >> 6);
    const int bh = g >> 12, t = g & 4095;
    const int lane = threadIdx.x & 63;
    ushort* rec = P + (size_t)bh * BHSH + (size_t)(t + 8) * RSH;

    float kt0 = b2f(rec[256 + lane]), kt1 = b2f(rec[256 + lane + 64]);
    float qt0 = b2f(rec[128 + lane]), qt1 = b2f(rec[128 + lane + 64]);
    float a[4], qb[4];
    float wa = b2f(rec[384 + lane]), wb = b2f(rec[384 + lane + 64]);  // E_t
    float qk = qt0 * kt0 + qt1 * kt1;
#pragma unroll
    for (int m = 1; m <= 4; ++m) {
        const ushort* rp = rec - (size_t)m * RSH;
        float kp0 = b2f(rp[256 + lane]), kp1 = b2f(rp[256 + lane + 64]);
        a[m - 1]  = kt0 * wa * kp0 + kt1 * wb * kp1;
        qb[m - 1] = qt0 * wa * kp0 + qt1 * wb * kp1;
        float ep0 = b2f(rp[384 + lane]), ep1 = b2f(rp[384 + lane + 64]);
        wa *= ep0; wb *= ep1;   // after loop: wa = W5 per dim
    }
#pragma unroll
    for (int m = 32; m >= 1; m >>= 1) {
        qk += __shfl_xor(qk, m);
        a[0] += __shfl_xor(a[0], m); a[1] += __shfl_xor(a[1], m);
        a[2] += __shfl_xor(a[2], m); a[3] += __shfl_xor(a[3], m);
        qb[0] += __shfl_xor(qb[0], m); qb[1] += __shfl_xor(qb[1], m);
        qb[2] += __shfl_xor(qb[2], m); qb[3] += __shfl_xor(qb[3], m);
    }
    rec[lane]            = f2b(kt0 * wa);
    rec[lane + 64]       = f2b(kt1 * wb);
    rec[128 + lane]      = f2b(qt0 * wa);
    rec[128 + lane + 64] = f2b(qt1 * wb);
    if (lane == 0) {
        float* sc = (float*)(rec + 640);
        sc[1] = qk;
        sc[2] = a[0]; sc[3] = a[1]; sc[4] = a[2]; sc[5] = a[3];
        sc[6] = qb[0]; sc[7] = qb[1]; sc[8] = qb[2]; sc[9] = qb[3];
    }
}

// ---------------------------------------------------------------------------
// scan: 5-stage register prefetch (distance 5), 16 lanes/col, 8 dims/thread,
// pipelined 4-level shfl reduction (one level per body, result consumed next
// body -> ds_bpermute latency fully hidden).  vmcnt-domain stage loads.
// __launch_bounds__(256,1): 1 wave/SIMD -> up to 512 VGPR.
// ---------------------------------------------------------------------------
struct Stage {
    uint4 kek, kee, kqw, kqq;
    uint vv;
    float4 s0, s1;
    float2 s2;
};

__device__ __forceinline__ void dec8(uint4 u, float* f) {
    f[0] = __uint_as_float(u.x << 16); f[1] = __uint_as_float(u.x & 0xffff0000u);
    f[2] = __uint_as_float(u.y << 16); f[3] = __uint_as_float(u.y & 0xffff0000u);
    f[4] = __uint_as_float(u.z << 16); f[5] = __uint_as_float(u.z & 0xffff0000u);
    f[6] = __uint_as_float(u.w << 16); f[7] = __uint_as_float(u.w & 0xffff0000u);
}

__global__ __launch_bounds__(256, 1) void scan_kernel(const ushort* __restrict__ P,
                                                      ushort* __restrict__ ob,
                                                      int smask, int sshift) {
    const int tid = threadIdx.x;
    const int l16 = tid & 15, cg = tid >> 4;
    const int s = blockIdx.x & smask;
    const int c = blockIdx.x >> sshift;
    const int b = s >> 4;
    const int h = s & 15;
    const int col = c * 16 + cg;
    // opaque per-lane zero: forces vector (vmcnt-domain) loads even for
    // wave-uniform addresses (prevents SMEM s_load / lgkm collision)
    unsigned opq;
    asm volatile("v_mov_b32 %0, 0" : "=v"(opq));
    const char* gb = (const char*)(P + (size_t)s * BHSH) + opq;
    ushort* op = ob + (size_t)b * TB * 2048 + h * 128 + col;
    const int lo = l16 * 16;
    const int co = col * 2;

    auto ldinit = [&](Stage& st, int rke, int rkq, int rvs) {
        const char* pa = gb + (size_t)rke * RB;
        const char* pb = gb + (size_t)rkq * RB;
        const char* pc = gb + (size_t)rvs * RB;
        st.kek = *(const uint4*)(pa + 512 + lo);
        st.kee = *(const uint4*)(pa + 768 + lo);
        st.kqw = *(const uint4*)(pb + 0 + lo);
        st.kqq = *(const uint4*)(pb + 256 + lo);
        st.vv  = *(const ushort*)(pc + 1024 + co);
        st.s0  = *(const float4*)(pc + 1280);
        st.s1  = *(const float4*)(pc + 1296);
        st.s2  = *(const float2*)(pc + 1312);
    };

    // stage for body X holds: (k,E) rec X+7 (t=X-1), (kw,qw) rec X+12 (t=X+4),
    // (v,sc) rec X+8 (t=X).  First bodies X = -4..0:
    Stage A, B, C, D, E5;
    ldinit(A, 3, 8, 4); ldinit(B, 4, 9, 5); ldinit(C, 5, 10, 6);
    ldinit(D, 6, 11, 7); ldinit(E5, 7, 12, 8);

    // rolling refill pointers: body X refills the stage consumed at X+5:
    // rke rec X+12, rkq rec X+17, rvs rec X+13.  First body X=-4:
    const char* pke = gb + (size_t)8 * RB;
    const char* pkq = gb + (size_t)13 * RB;
    const char* pvs = gb + (size_t)9 * RB;

    float S[8];
#pragma unroll
    for (int i = 0; i < 8; ++i) S[i] = 0.f;
    float d1 = 0.f, d2 = 0.f, d3 = 0.f, d4 = 0.f;
    // pipelined reduction registers: sNx = partial sum at level N (issued
    // shfl pending in rNx), consumed next body.
    float s0p = 0.f, s1p = 0.f, s2p = 0.f, s3p = 0.f;
    float r0p = 0.f, r1p = 0.f, r2p = 0.f, r3p = 0.f;
    float s0q = 0.f, s1q = 0.f, s2q = 0.f, s3q = 0.f;
    float r0q = 0.f, r1q = 0.f, r2q = 0.f, r3q = 0.f;

    auto body = [&](int X, Stage& st) {
        float k8[8], e8[8], w8[8], q8[8];
        dec8(st.kek, k8); dec8(st.kee, e8);
        dec8(st.kqw, w8); dec8(st.kqq, q8);
        float vj = b2f((ushort)st.vv);
        float beta = st.s0.x, qk = st.s0.y;
        float a1 = st.s0.z, a2 = st.s0.w, a3 = st.s1.x, a4 = st.s1.y;
        float qb1 = st.s1.z, qb2 = st.s1.w, qb3 = st.s2.x, qb4 = st.s2.y;
        // refill (consumed 5 bodies later); rolling pointers
        st.kek = *(const uint4*)(pke + 512 + lo);
        st.kee = *(const uint4*)(pke + 768 + lo);
        st.kqw = *(const uint4*)(pkq + 0 + lo);
        st.kqq = *(const uint4*)(pkq + 256 + lo);
        st.vv  = *(const ushort*)(pvs + 1024 + co);
        st.s0  = *(const float4*)(pvs + 1280);
        st.s1  = *(const float4*)(pvs + 1296);
        st.s2  = *(const float2*)(pvs + 1312);
        pke += RB; pkq += RB; pvs += RB;
        // compiler memory barrier: refill loads cannot sink below
        asm volatile("" ::: "memory");
        // S update: apply delta_{X-1} with k,E of t = X-1  -> S becomes S_{X-1}
#pragma unroll
        for (int i = 0; i < 8; ++i) S[i] = fmaf(k8[i], d1, e8[i] * S[i]);
        // dots for t = X+4: kw_{X+4} . S_{X-1}
        float pk = 0.f, pq = 0.f;
#pragma unroll
        for (int i = 0; i < 8; ++i) { pk = fmaf(w8[i], S[i], pk); pq = fmaf(q8[i], S[i], pq); }
        // consume shfl results issued last body (latency fully hidden)
        float fullp = s3p + r3p, fullq = s3q + r3q;
        float n3p = s2p + r2p, n3q = s2q + r2q;
        float n2p = s1p + r1p, n2q = s1q + r1q;
        float n1p = s0p + r0p, n1q = s0q + r0q;
        // scalar chain: t = X
        float pks = fullp + a1 * d1 + a2 * d2 + a3 * d3 + a4 * d4;
        float dl = beta * (vj - pks);
        float oo = fullq + qb1 * d1 + qb2 * d2 + qb3 * d3 + qb4 * d4 + qk * dl;
        if (X >= 0 && l16 == 0) op[(size_t)X * 2048] = f2b(oo);
        // issue one shfl level per value (consumed next body)
        r3p = __shfl_xor(n3p, 8); s3p = n3p;
        r2p = __shfl_xor(n2p, 4); s2p = n2p;
        r1p = __shfl_xor(n1p, 2); s1p = n1p;
        r0p = __shfl_xor(pk, 1);  s0p = pk;
        r3q = __shfl_xor(n3q, 8); s3q = n3q;
        r2q = __shfl_xor(n2q, 4); s2q = n2q;
        r1q = __shfl_xor(n1q, 2); s1q = n1q;
        r0q = __shfl_xor(pq, 1);  s0q = pq;
        d4 = d3; d3 = d2; d2 = d1; d1 = dl;
    };

    int X = -4;
    for (int it = 0; it < 820; ++it) {   // 820*5 = 4100 bodies: X = -4 .. 4095
        body(X, A);
        body(X + 1, B);
        body(X + 2, C);
        body(X + 3, D);
        body(X + 4, E5);
        X += 5;
    }
}

// ---------------------------------------------------------------------------
// gated RMS norm: og = bf16( o*rsqrt(mean o^2+1e-5)*norm_w*sigmoid(gate+bg2) )
// ---------------------------------------------------------------------------
__global__ __launch_bounds__(256) void normgate_kernel(
    const ushort* __restrict__ o, const ushort* __restrict__ gate,
    const float* __restrict__ bg2, const float* __restrict__ norm_w,
    ushort* __restrict__ og) {
    const int lane = threadIdx.x & 63;
    const int wstart = (blockIdx.x * 256 + threadIdx.x) >> 6;
    const int nw = (gridDim.x * 256) >> 6;
    for (int pair = wstart; pair < TB * 16; pair += nw) {
        const int t = pair >> 4, h = pair & 15;
        const size_t basep = (size_t)t * 2048 + h * 128 + lane * 2;
        unsigned int ovu = *(const unsigned int*)(o + basep);
        float o0 = __uint_as_float(ovu << 16);
        float o1 = __uint_as_float(ovu & 0xffff0000u);
        float ss = o0 * o0 + o1 * o1;
#pragma unroll
        for (int m = 32; m >= 1; m >>= 1) ss += __shfl_xor(ss, m);
        float rn = rsqrtf(ss * (1.0f / 128.0f) + 1e-5f);
        const int dg = h * 128 + lane * 2;
        unsigned int gv = *(const unsigned int*)(gate + basep);
        float g0 = __uint_as_float(gv << 16) + bg2[dg];
        float g1 = __uint_as_float(gv & 0xffff0000u) + bg2[dg + 1];
        float w0 = norm_w[lane * 2], w1 = norm_w[lane * 2 + 1];
        float r0 = o0 * rn * w0 / (1.0f + expf(-g0));
        float r1 = o1 * rn * w1 / (1.0f + expf(-g1));
        unsigned int outw = (unsigned int)f2b(r0) | ((unsigned int)f2b(r1) << 16);
        *(unsigned int*)(og + basep) = outw;
    }
}

// ---------------------------------------------------------------------------
extern "C" void kernel_launch(void* const* d_in, const int* in_sizes, int n_in,
                              void* d_out, int out_size, void* d_ws, size_t ws_size,
                              hipStream_t stream) {
    const float* x = (const float*)d_in[0];
    const float* Wq = (const float*)d_in[1];
    const float* Wk = (const float*)d_in[2];
    const float* Wv = (const float*)d_in[3];
    const float* convq = (const float*)d_in[4];
    const float* convk = (const float*)d_in[5];
    const float* convv = (const float*)d_in[6];
    const float* A_log = (const float*)d_in[7];
    const float* dt_bias = (const float*)d_in[8];
    const float* Wsv = (const float*)d_in[9];
    const float* Wb1 = (const float*)d_in[10];
    const float* bb1 = (const float*)d_in[11];
    const float* Wb2 = (const float*)d_in[12];
    const float* bb2 = (const float*)d_in[13];
    const float* Wa1 = (const float*)d_in[14];
    const float* ba1 = (const float*)d_in[15];
    const float* Wa2 = (const float*)d_in[16];
    const float* ba2 = (const float*)d_in[17];
    const float* Wg1 = (const float*)d_in[18];
    const float* Wg2 = (const float*)d_in[19];
    const float* bg2 = (const float*)d_in[20];
    const float* norm_w = (const float*)d_in[21];
    const float* Wo = (const float*)d_in[22];

    // ---- workspace layout (bytes) ----
    const size_t PBATCH   = (size_t)16 * BHSH * 2;      // 87,201,792 per batch
    const size_t OFF_WQKV = 0;                          // 25,165,824
    const size_t OFF_XB   = OFF_WQKV + 25165824;        // 16,777,216
    const size_t OFF_WG1  = OFF_XB + 16777216;          //    524,288
    const size_t OFF_WG2  = OFF_WG1 + 524288;           //    524,288
    const size_t OFF_QKV  = OFF_WG2 + 524288;           // 50,331,648
    const size_t OFF_P    = OFF_QKV + 50331648;         // = 93,323,264
    const size_t NEED_B   = OFF_P + PBATCH + TAILPAD;   // ~180.6 MB
    const size_t NEED_A   = OFF_P + 2 * PBATCH + TAILPAD;  // ~267.8 MB
    if (ws_size < NEED_B) return;  // diagnostic guard
    const bool planA = (ws_size >= NEED_A);

    char* ws = (char*)d_ws;
    ushort* wqkv = (ushort*)(ws + OFF_WQKV);
    ushort* xb   = (ushort*)(ws + OFF_XB);
    ushort* wg1b = (ushort*)(ws + OFF_WG1);
    ushort* wg2b = (ushort*)(ws + OFF_WG2);
    ushort* qkvb = (ushort*)(ws + OFF_QKV);
    ushort* P    = (ushort*)(ws + OFF_P);
    // phase-3 aliases in the dead qkv region:
    ushort* gateb = qkvb;                               // +0        16,777,216
    ushort* xg1b  = (ushort*)(ws + OFF_QKV + 16777216); // +16.78M    1,048,576
    ushort* ogb   = (ushort*)(ws + OFF_QKV + 17825792); // +17.83M   16,777,216
    ushort* wob   = (ushort*)(ws + OFF_QKV + 34603008); // +34.60M    8,388,608
    // scan output: planB -> xb region (per batch, 16.7MB);
    //              planA -> wqkv+xb contiguous span (both batches, 33.5MB; both dead)
    ushort* obp = planA ? (ushort*)(ws + OFF_WQKV) : xb;

    // weight casts
    cast_f32_bf16<<<512, 256, 0, stream>>>(Wq, wqkv, 4194304);
    cast_f32_bf16<<<512, 256, 0, stream>>>(Wk, wqkv + 4194304, 4194304);
    cast_f32_bf16<<<512, 256, 0, stream>>>(Wv, wqkv + 8388608, 4194304);
    cast_f32_bf16<<<64, 256, 0, stream>>>(Wg1, wg1b, 262144);
    cast_f32_bf16<<<64, 256, 0, stream>>>(Wg2, wg2b, 262144);

    if (planA) {
        for (int b = 0; b < 2; ++b) {
            cast_f32_bf16<<<512, 256, 0, stream>>>(x + (size_t)b * TB * 2048, xb, TB * 2048);
            gemm_bf16<ushort><<<dim3(48, TB / 128), 256, 0, stream>>>(xb, wqkv, qkvb, TB, 6144, 2048);
            conv_stats_kernel<<<TB * 16 / 8, 256, 0, stream>>>(qkvb, convq, convk, convv, Wsv,
                Wb1, bb1, Wb2, bb2, Wa1, ba1, Wa2, ba2, A_log, dt_bias,
                P + (size_t)b * 16 * BHSH);
        }
        prepass_kernel<<<32 * 1024, 256, 0, stream>>>(P);
        // ONE scan over both batches (256 blocks) -> obp (wqkv+xb span, now dead)
        scan_kernel<<<256, 256, 0, stream>>>(P, obp, 31, 5);
        // phase 3 (wqkv destroyed; qkv region reused for gate/xg1/og/wob)
        cast_f32_bf16<<<512, 256, 0, stream>>>(Wo, wob, 4194304);
        for (int b = 0; b < 2; ++b) {
            ushort* xstage = ogb;  // 16.7MB staging for x (og written later)
            cast_f32_bf16<<<512, 256, 0, stream>>>(x + (size_t)b * TB * 2048, xstage, TB * 2048);
            gemm_bf16<ushort><<<dim3(1, TB / 128), 256, 0, stream>>>(xstage, wg1b, xg1b, TB, 128, 2048);
            gemm_bf16<ushort><<<dim3(16, TB / 128), 256, 0, stream>>>(xg1b, wg2b, gateb, TB, 2048, 128);
            normgate_kernel<<<2048, 256, 0, stream>>>(obp + (size_t)b * TB * 2048, gateb, bg2, norm_w, ogb);
            gemm_bf16<float><<<dim3(16, TB / 128), 256, 0, stream>>>(ogb, wob,
                (float*)d_out + (size_t)b * TB * 2048, TB, 2048, 2048);
        }
    } else {
        for (int b = 0; b < 2; ++b) {
            const float* xbp = x + (size_t)b * TB * 2048;
            float* outp = (float*)d_out + (size_t)b * TB * 2048;
            cast_f32_bf16<<<512, 256, 0, stream>>>(xbp, xb, TB * 2048);
            gemm_bf16<ushort><<<dim3(48, TB / 128), 256, 0, stream>>>(xb, wqkv, qkvb, TB, 6144, 2048);
            conv_stats_kernel<<<TB * 16 / 8, 256, 0, stream>>>(qkvb, convq, convk, convv, Wsv,
                Wb1, bb1, Wb2, bb2, Wa1, ba1, Wa2, ba2, A_log, dt_bias, P);
            gemm_bf16<ushort><<<dim3(1, TB / 128), 256, 0, stream>>>(xb, wg1b, xg1b, TB, 128, 2048);
            gemm_bf16<ushort><<<dim3(16, TB / 128), 256, 0, stream>>>(xg1b, wg2b, gateb, TB, 2048, 128);
            cast_f32_bf16<<<512, 256, 0, stream>>>(Wo, wob, 4194304);
            prepass_kernel<<<16 * 1024, 256, 0, stream>>>(P);
            scan_kernel<<<128, 256, 0, stream>>>(P, xb, 15, 4);   // xb dead -> ob
            normgate_kernel<<<2048, 256, 0, stream>>>(xb, gateb, bg2, norm_w, ogb);
            gemm_bf16<float><<<dim3(16, TB / 128), 256, 0, stream>>>(ogb, wob, outp, TB, 2048, 2048);
        }
    }
}

// Round 11
// 2038.251 us; speedup vs baseline: 1.3879x; 1.1663x over previous
//
#include <hip/hip_runtime.h>
#include <hip/hip_bf16.h>

// ---------------------------------------------------------------------------
// SurpriseKimiDeltaAttention  (B=2, T=4096, H=2048, NH=16, DK=DV=128, CONV=4)
// R11: CHUNKED scan (C=16, UT transform).
//  conv_stats -> records per (h,t): q~|k|E|v|beta   (dims paired (2l,2l+1))
//  phasea (parallel, 1 wave/chunk): in-place converts each 16-record span to:
//    KW[16][128]bf16 @0 | QW @4096 | KV'[16][128]bf16 @8192 | VT[128][16]bf16
//    @12288 | W15[128]bf16 @16384 | UM'[16][16]f32 @16640   (span = 21248 B)
//    where A_ij = beta_i * k_i.(k_j*R_ij), M' = (I+A)^-1 B, UM' = U M',
//    KV' = M'^T KU, all within-chunk decay ratios <= 1 (overflow-safe).
//  phaseb (sequential over 256 chunks, parallel over (stream, 16-col block)):
//    Y = KW.S0, Z = QW.S0 (16-lane reduce); r' = v - Y;
//    o_i = Z_i + UM'[i][:].r';  S = W15*S + sum_m KV'_m r'_m.
// Plan A (ws >= ~267.4MB): both batches resident, ONE phaseb launch (256 blk).
// Plan B (ws >= ~180.4MB): per-batch sequential.
// ---------------------------------------------------------------------------

typedef __attribute__((ext_vector_type(8))) short bf16x8;
typedef __attribute__((ext_vector_type(4))) float floatx4;

#define TB 4096
#define RSH 664                      // shorts per record
#define NREC 4096
#define BHSH ((size_t)NREC * RSH)    // shorts per (b,h) stream
#define CSB ((size_t)16 * RSH * 2)   // chunk span bytes = 21248

__device__ __forceinline__ float b2f(ushort u) {
    union { unsigned int u; float f; } c; c.u = ((unsigned int)u) << 16; return c.f;
}
__device__ __forceinline__ ushort f2b(float f) {
    union { float f; unsigned int u; } c; c.f = f;
    unsigned int r = (c.u + 0x7fffu + ((c.u >> 16) & 1u)) >> 16;
    return (ushort)r;
}
__device__ __forceinline__ float silu(float x) { return x / (1.0f + expf(-x)); }
__device__ __forceinline__ void dec8(uint4 u, float* f) {
    f[0] = __uint_as_float(u.x << 16); f[1] = __uint_as_float(u.x & 0xffff0000u);
    f[2] = __uint_as_float(u.y << 16); f[3] = __uint_as_float(u.y & 0xffff0000u);
    f[4] = __uint_as_float(u.z << 16); f[5] = __uint_as_float(u.z & 0xffff0000u);
    f[6] = __uint_as_float(u.w << 16); f[7] = __uint_as_float(u.w & 0xffff0000u);
}

// ---------------------------------------------------------------------------
__global__ __launch_bounds__(256) void cast_f32_bf16(const float* __restrict__ in,
                                                     ushort* __restrict__ out, int n) {
    int i = (blockIdx.x * 256 + threadIdx.x) * 4;
    int stride = gridDim.x * 256 * 4;
    for (; i + 3 < n; i += stride) {
        float4 v = *(const float4*)(in + i);
        ushort4 u;
        u.x = f2b(v.x); u.y = f2b(v.y); u.z = f2b(v.z); u.w = f2b(v.w);
        *(ushort4*)(out + i) = u;
    }
}

// ---------------------------------------------------------------------------
// bf16 MFMA GEMM: C[M][N] = A[M][K] @ B[N][K]^T  (row-major, K contiguous)
// ---------------------------------------------------------------------------
template <typename CT>
__global__ __launch_bounds__(256) void gemm_bf16(const ushort* __restrict__ A,
                                                 const ushort* __restrict__ B,
                                                 CT* __restrict__ C, int M, int N, int K) {
    __shared__ ushort As[128 * 40];
    __shared__ ushort Bs[128 * 40];
    const int tid = threadIdx.x;
    const int lane = tid & 63, wid = tid >> 6;
    const int wr = wid >> 1, wc = wid & 1;
    const int bm = blockIdx.y, bn = blockIdx.x;

    const int r0 = tid >> 2;
    const int kc0 = (tid & 3) * 8;
    const size_t aoff0 = (size_t)(bm * 128 + r0) * K + kc0;
    const size_t aoff1 = aoff0 + (size_t)64 * K;
    const size_t boff0 = (size_t)(bn * 128 + r0) * K + kc0;
    const size_t boff1 = boff0 + (size_t)64 * K;
    const int lw0 = r0 * 40 + kc0;
    const int lw1 = (r0 + 64) * 40 + kc0;

    const int arow = wr * 64 + (lane & 15);
    const int brow = wc * 64 + (lane & 15);
    const int kg = (lane >> 4) * 8;

    floatx4 acc[4][4];
#pragma unroll
    for (int m = 0; m < 4; ++m)
#pragma unroll
        for (int n = 0; n < 4; ++n) acc[m][n] = (floatx4){0.f, 0.f, 0.f, 0.f};

    uint4 ra0 = *(const uint4*)(A + aoff0);
    uint4 ra1 = *(const uint4*)(A + aoff1);
    uint4 rb0 = *(const uint4*)(B + boff0);
    uint4 rb1 = *(const uint4*)(B + boff1);

    for (int kt = 32; kt <= K; kt += 32) {
        __syncthreads();
        *(uint4*)(As + lw0) = ra0;
        *(uint4*)(As + lw1) = ra1;
        *(uint4*)(Bs + lw0) = rb0;
        *(uint4*)(Bs + lw1) = rb1;
        __syncthreads();
        if (kt < K) {
            ra0 = *(const uint4*)(A + aoff0 + kt);
            ra1 = *(const uint4*)(A + aoff1 + kt);
            rb0 = *(const uint4*)(B + boff0 + kt);
            rb1 = *(const uint4*)(B + boff1 + kt);
        }
        bf16x8 af[4], bfr[4];
#pragma unroll
        for (int m = 0; m < 4; ++m) af[m] = *(const bf16x8*)(As + (arow + m * 16) * 40 + kg);
#pragma unroll
        for (int n = 0; n < 4; ++n) bfr[n] = *(const bf16x8*)(Bs + (brow + n * 16) * 40 + kg);
#pragma unroll
        for (int m = 0; m < 4; ++m)
#pragma unroll
            for (int n = 0; n < 4; ++n)
                acc[m][n] = __builtin_amdgcn_mfma_f32_16x16x32_bf16(af[m], bfr[n], acc[m][n], 0, 0, 0);
    }

    const int crow0 = bm * 128 + wr * 64 + (lane >> 4) * 4;
    const int ccol0 = bn * 128 + wc * 64 + (lane & 15);
#pragma unroll
    for (int m = 0; m < 4; ++m)
#pragma unroll
        for (int n = 0; n < 4; ++n)
#pragma unroll
            for (int j = 0; j < 4; ++j) {
                int row = crow0 + m * 16 + j;
                int col = ccol0 + n * 16;
                if constexpr (sizeof(CT) == 2)
                    C[(size_t)row * N + col] = (CT)f2b(acc[m][n][j]);
                else
                    C[(size_t)row * N + col] = (CT)acc[m][n][j];
            }
}

// ---------------------------------------------------------------------------
// conv + silu + surprise stats + beta/amp MLPs -> records (one batch)
// lane owns dims (2*lane, 2*lane+1)  [contiguous pair for phasea uint loads]
// record shorts: q~@128, k@256, E@384, v@512, beta f32 @640
// ---------------------------------------------------------------------------
__global__ __launch_bounds__(256) void conv_stats_kernel(
    const ushort* __restrict__ qkv,
    const float* __restrict__ convq, const float* __restrict__ convk,
    const float* __restrict__ convv, const float* __restrict__ Wsv,
    const float* __restrict__ Wb1, const float* __restrict__ bb1,
    const float* __restrict__ Wb2, const float* __restrict__ bb2,
    const float* __restrict__ Wa1, const float* __restrict__ ba1,
    const float* __restrict__ Wa2, const float* __restrict__ ba2,
    const float* __restrict__ A_log, const float* __restrict__ dt_bias,
    ushort* __restrict__ P) {
    __shared__ ushort wsv_s[128 * 136];
    __shared__ float k_sh[4][128];
    for (int i = threadIdx.x; i < 128 * 128; i += 256) {
        int row = i >> 7, col = i & 127;
        wsv_s[row * 136 + col] = f2b(Wsv[i]);
    }
    __syncthreads();
    const int wid = threadIdx.x >> 6, lane = threadIdx.x & 63;

    for (int it = 0; it < 2; ++it) {
        const int pair = blockIdx.x * 8 + it * 4 + wid;   // [0, TB*16)
        const int t = pair >> 4, h = pair & 15;
        const int c0 = h * 128 + 2 * lane, c1 = c0 + 1;

        float wq[4], wq2[4], wk[4], wk2[4], wv[4], wv2[4];
#pragma unroll
        for (int i2 = 0; i2 < 4; ++i2) {
            wq[i2] = convq[c0 * 4 + i2]; wq2[i2] = convq[c1 * 4 + i2];
            wk[i2] = convk[c0 * 4 + i2]; wk2[i2] = convk[c1 * 4 + i2];
            wv[i2] = convv[c0 * 4 + i2]; wv2[i2] = convv[c1 * 4 + i2];
        }
        float aq0 = 0, aq1 = 0, ak0 = 0, ak1 = 0, av0 = 0, av1 = 0;
#pragma unroll
        for (int i2 = 0; i2 < 4; ++i2) {
            int tt = t - 3 + i2;
            if (tt >= 0) {
                const ushort* rowp = qkv + (size_t)tt * 6144 + h * 128;
                uint xq = *(const uint*)(rowp + 2 * lane);
                uint xk = *(const uint*)(rowp + 2048 + 2 * lane);
                uint xv = *(const uint*)(rowp + 4096 + 2 * lane);
                aq0 = fmaf(__uint_as_float(xq << 16), wq[i2], aq0);
                aq1 = fmaf(__uint_as_float(xq & 0xffff0000u), wq2[i2], aq1);
                ak0 = fmaf(__uint_as_float(xk << 16), wk[i2], ak0);
                ak1 = fmaf(__uint_as_float(xk & 0xffff0000u), wk2[i2], ak1);
                av0 = fmaf(__uint_as_float(xv << 16), wv[i2], av0);
                av1 = fmaf(__uint_as_float(xv & 0xffff0000u), wv2[i2], av1);
            }
        }
        float q0 = silu(aq0), q1 = silu(aq1);
        float k0 = silu(ak0), k1 = silu(ak1);
        float v0 = silu(av0), v1 = silu(av1);

        __syncthreads();
        k_sh[wid][2 * lane] = k0;
        k_sh[wid][2 * lane + 1] = k1;
        __syncthreads();

        float vh0 = 0.f, vh1 = 0.f;
        const ushort* wr0 = wsv_s + (2 * lane) * 136;
        const ushort* wr1 = wsv_s + (2 * lane + 1) * 136;
#pragma unroll 4
        for (int j = 0; j < 128; j += 8) {
            float4 ka = *(const float4*)&k_sh[wid][j];
            float4 kb = *(const float4*)&k_sh[wid][j + 4];
            uint4 wa = *(const uint4*)(wr0 + j);
            uint4 wb = *(const uint4*)(wr1 + j);
            vh0 = fmaf(__uint_as_float(wa.x << 16), ka.x, vh0);
            vh0 = fmaf(__uint_as_float(wa.x & 0xffff0000u), ka.y, vh0);
            vh0 = fmaf(__uint_as_float(wa.y << 16), ka.z, vh0);
            vh0 = fmaf(__uint_as_float(wa.y & 0xffff0000u), ka.w, vh0);
            vh0 = fmaf(__uint_as_float(wa.z << 16), kb.x, vh0);
            vh0 = fmaf(__uint_as_float(wa.z & 0xffff0000u), kb.y, vh0);
            vh0 = fmaf(__uint_as_float(wa.w << 16), kb.z, vh0);
            vh0 = fmaf(__uint_as_float(wa.w & 0xffff0000u), kb.w, vh0);
            vh1 = fmaf(__uint_as_float(wb.x << 16), ka.x, vh1);
            vh1 = fmaf(__uint_as_float(wb.x & 0xffff0000u), ka.y, vh1);
            vh1 = fmaf(__uint_as_float(wb.y << 16), ka.z, vh1);
            vh1 = fmaf(__uint_as_float(wb.y & 0xffff0000u), ka.w, vh1);
            vh1 = fmaf(__uint_as_float(wb.z << 16), kb.x, vh1);
            vh1 = fmaf(__uint_as_float(wb.z & 0xffff0000u), kb.y, vh1);
            vh1 = fmaf(__uint_as_float(wb.w << 16), kb.z, vh1);
            vh1 = fmaf(__uint_as_float(wb.w & 0xffff0000u), kb.w, vh1);
        }

        float e0 = vh0 - v0, e1 = vh1 - v1;
        float se2 = e0 * e0 + e1 * e1;
        float sl1 = fabsf(e0) + fabsf(e1);
        float shv = vh0 * v0 + vh1 * v1;
        float shh = vh0 * vh0 + vh1 * vh1;
        float svv = v0 * v0 + v1 * v1;
        float sk2 = k0 * k0 + k1 * k1;
        float sq2 = q0 * q0 + q1 * q1;
#pragma unroll
        for (int m = 32; m >= 1; m >>= 1) {
            se2 += __shfl_xor(se2, m);
            sl1 += __shfl_xor(sl1, m);
            shv += __shfl_xor(shv, m);
            shh += __shfl_xor(shh, m);
            svv += __shfl_xor(svv, m);
            sk2 += __shfl_xor(sk2, m);
            sq2 += __shfl_xor(sq2, m);
        }
        float s_l2 = sqrtf(se2 + 1e-6f);
        float s_l1 = sl1;
        float s_cos = 1.0f - shv / (sqrtf(shh + 1e-6f) * sqrtf(svv + 1e-6f) + 1e-6f);

        const int j2 = lane & 31;
        const float* W1 = (lane < 32) ? Wb1 : Wa1;
        const float* b1 = (lane < 32) ? bb1 : ba1;
        const float* W2 = (lane < 32) ? Wb2 : Wa2;
        float pre = W1[j2 * 3] * s_l2 + W1[j2 * 3 + 1] * s_l1 + W1[j2 * 3 + 2] * s_cos + b1[j2];
        float val = W2[j2] * silu(pre);
#pragma unroll
        for (int m = 16; m >= 1; m >>= 1) val += __shfl_xor(val, m);
        float pre_b = __shfl(val, 0) + bb2[0];
        float pre_a = __shfl(val, 32) + ba2[0];
        float betav = 1.0f / (1.0f + expf(-pre_b));
        float amp = pre_a;

        float knorm = sqrtf(sk2);
        float rinv = amp / fmaxf(knorm, 1e-12f);
        float ah = expf(A_log[h]);
        float gr0 = fmaf(k0, rinv, dt_bias[c0]);
        float gr1 = fmaf(k1, rinv, dt_bias[c1]);
        float sp0 = (gr0 > 20.f) ? gr0 : log1pf(expf(gr0));
        float sp1 = (gr1 > 20.f) ? gr1 : log1pf(expf(gr1));

        ushort* rec = P + (size_t)h * BHSH + (size_t)t * RSH;
        float kinv = rsqrtf(sk2 + 1e-6f);
        float qinv = rsqrtf(sq2 + 1e-6f) * 0.08838834764831845f;  // * DK^-0.5
        *(uint*)(rec + 128 + 2 * lane) = (uint)f2b(q0 * qinv) | ((uint)f2b(q1 * qinv) << 16);
        *(uint*)(rec + 256 + 2 * lane) = (uint)f2b(k0 * kinv) | ((uint)f2b(k1 * kinv) << 16);
        *(uint*)(rec + 384 + 2 * lane) = (uint)f2b(expf(-ah * sp0)) | ((uint)f2b(expf(-ah * sp1)) << 16);
        *(uint*)(rec + 512 + 2 * lane) = (uint)f2b(v0) | ((uint)f2b(v1) << 16);
        if (lane == 0) *(float*)(rec + 640) = betav;
    }
}

// ---------------------------------------------------------------------------
// phase A: one wave per (stream, chunk).  In-place: reads q~,k,E,v,beta from
// the 16 records, writes the chunk block over the span.
// ---------------------------------------------------------------------------
__global__ __launch_bounds__(256, 1) void phasea_kernel(ushort* __restrict__ P) {
    __shared__ float lA[4][16][16];
    __shared__ float lU[4][16][16];
    __shared__ float lM[4][16][16];
    const int wid = threadIdx.x >> 6, lane = threadIdx.x & 63;
    const int g = blockIdx.x * 4 + wid;
    const int s = g >> 8, n = g & 255;
    ushort* cb = P + (size_t)s * BHSH + (size_t)n * (16 * RSH);
    char* sb = (char*)cb;
    float (*A_)[16] = lA[wid];
    float (*U_)[16] = lU[wid];
    float (*M_)[16] = lM[wid];

    // ---- load ALL inputs to registers before any store (in-place safety) ----
    float kf[32], Ef[32], qf[32], bf[16];
    uint vq[16];
#pragma unroll
    for (int i = 0; i < 16; ++i) {
        const ushort* r = cb + i * RSH;
        uint ku = *(const uint*)(r + 256 + 2 * lane);
        uint eu = *(const uint*)(r + 384 + 2 * lane);
        uint qu = *(const uint*)(r + 128 + 2 * lane);
        vq[i] = *(const uint*)(r + 512 + 2 * lane);
        bf[i] = *(const float*)(r + 640);
        kf[2 * i]     = __uint_as_float(ku << 16);
        kf[2 * i + 1] = __uint_as_float(ku & 0xffff0000u);
        Ef[2 * i]     = __uint_as_float(eu << 16);
        Ef[2 * i + 1] = __uint_as_float(eu & 0xffff0000u);
        qf[2 * i]     = __uint_as_float(qu << 16);
        qf[2 * i + 1] = __uint_as_float(qu & 0xffff0000u);
    }

    // ---- main triangular pass: T,U rows; kw,qw writes; R(->KU) ----
    float R[32];
    float Pc0 = 1.f, Pc1 = 1.f;
#pragma unroll
    for (int i = 0; i < 16; ++i) {
#pragma unroll
        for (int j = 0; j < 16; ++j) if (j < i) {
            R[2 * j] *= Ef[2 * i];
            R[2 * j + 1] *= Ef[2 * i + 1];
        }
        float Tr[16], Ur[16];
#pragma unroll
        for (int j = 0; j < 16; ++j) { Tr[j] = 0.f; Ur[j] = 0.f; }
#pragma unroll
        for (int j = 0; j < 16; ++j) if (j < i) {
            Tr[j] = kf[2 * i] * R[2 * j] + kf[2 * i + 1] * R[2 * j + 1];
            Ur[j] = qf[2 * i] * R[2 * j] + qf[2 * i + 1] * R[2 * j + 1];
        }
        Ur[i] = qf[2 * i] * kf[2 * i] + qf[2 * i + 1] * kf[2 * i + 1];
#pragma unroll
        for (int m = 1; m <= 32; m <<= 1) {
#pragma unroll
            for (int j = 0; j < 16; ++j) if (j <= i) {
                if (j < i) Tr[j] += __shfl_xor(Tr[j], m);
                Ur[j] += __shfl_xor(Ur[j], m);
            }
        }
        if (lane == 0) {
#pragma unroll
            for (int j = 0; j < 16; ++j) if (j < i) A_[i][j] = bf[i] * Tr[j];
#pragma unroll
            for (int j = 0; j < 16; ++j) if (j <= i) U_[i][j] = Ur[j];
        }
        R[2 * i] = kf[2 * i];
        R[2 * i + 1] = kf[2 * i + 1];
        Pc0 *= Ef[2 * i];
        Pc1 *= Ef[2 * i + 1];
        *(uint*)(sb + (size_t)i * 256 + 4 * lane) =
            (uint)f2b(kf[2 * i] * Pc0) | ((uint)f2b(kf[2 * i + 1] * Pc1) << 16);
        *(uint*)(sb + 4096 + (size_t)i * 256 + 4 * lane) =
            (uint)f2b(qf[2 * i] * Pc0) | ((uint)f2b(qf[2 * i + 1] * Pc1) << 16);
    }
    // W15
    *(uint*)(sb + 16384 + 4 * lane) = (uint)f2b(Pc0) | ((uint)f2b(Pc1) << 16);
    // vT  (rows 2*lane and 2*lane+1)
    {
        uint lw[8], hw[8];
#pragma unroll
        for (int w = 0; w < 8; ++w) {
            lw[w] = (vq[2 * w] & 0xffffu) | (vq[2 * w + 1] << 16);
            hw[w] = (vq[2 * w] >> 16) | (vq[2 * w + 1] & 0xffff0000u);
        }
        char* vt0 = sb + 12288 + (size_t)(2 * lane) * 32;
        *(uint4*)(vt0)      = (uint4){lw[0], lw[1], lw[2], lw[3]};
        *(uint4*)(vt0 + 16) = (uint4){lw[4], lw[5], lw[6], lw[7]};
        *(uint4*)(vt0 + 32) = (uint4){hw[0], hw[1], hw[2], hw[3]};
        *(uint4*)(vt0 + 48) = (uint4){hw[4], hw[5], hw[6], hw[7]};
    }
    // ---- M' = (I+A)^{-1} B, column m = lane&15 ----
    const int mcol = lane & 15;
    float M[16];
#pragma unroll
    for (int i = 0; i < 16; ++i) {
        float acc = (i == mcol) ? bf[i] : 0.f;
#pragma unroll
        for (int j = 0; j < 16; ++j) if (j < i) acc -= A_[i][j] * M[j];
        M[i] = acc;
    }
    if (lane < 16) {
#pragma unroll
        for (int j = 0; j < 16; ++j) M_[j][lane] = M[j];
    }
    // ---- UM' = U M'  (lane m writes column m of row-major UM) ----
    if (lane < 16) {
#pragma unroll
        for (int i = 0; i < 16; ++i) {
            float acc = 0.f;
#pragma unroll
            for (int j = 0; j < 16; ++j) if (j <= i) acc += U_[i][j] * M[j];
            *(float*)(sb + 16640 + (size_t)i * 64 + 4 * lane) = acc;
        }
    }
    // ---- KV'[m][d] = sum_j M'[j][m] * KU_j[d]  (KU_j = R[j] after loop) ----
#pragma unroll
    for (int m = 0; m < 16; ++m) {
        float a0 = 0.f, a1 = 0.f;
#pragma unroll
        for (int j = 0; j < 16; ++j) if (j >= m) {
            float mv = M_[j][m];
            a0 = fmaf(mv, R[2 * j], a0);
            a1 = fmaf(mv, R[2 * j + 1], a1);
        }
        *(uint*)(sb + 8192 + (size_t)m * 256 + 4 * lane) =
            (uint)f2b(a0) | ((uint)f2b(a1) << 16);
    }
}

// ---------------------------------------------------------------------------
// phase B: sequential over 256 chunks; block = (stream, 16-col slice).
// thread (l16 = tid&15 -> dims l16*8..+8, cg = tid>>4 -> col).
// Double-buffered LDS staging of KW/QW/KV (f32), one barrier per chunk.
// ---------------------------------------------------------------------------
__global__ __launch_bounds__(256, 1) void phaseb_kernel(const ushort* __restrict__ P,
                                                        ushort* __restrict__ ob,
                                                        int smask, int sshift) {
    __shared__ float kwf[2][2048];
    __shared__ float qwf[2][2048];
    __shared__ float kvf[2][2048];
    const int tid = threadIdx.x;
    const int l16 = tid & 15, cg = tid >> 4;
    const int s = blockIdx.x & smask, c = blockIdx.x >> sshift;
    const int b = s >> 4, h = s & 15;
    const int col = c * 16 + cg;
    const char* gb = (const char*)(P + (size_t)s * BHSH);
    ushort* opb = ob + (size_t)b * (TB * 2048) + h * 128 + col;
    const int fo = tid * 8;

    uint4 sA = *(const uint4*)(gb + (size_t)fo * 2);
    uint4 sB = *(const uint4*)(gb + 4096 + (size_t)fo * 2);
    uint4 sC = *(const uint4*)(gb + 8192 + (size_t)fo * 2);
    {
        float t[8];
        dec8(sA, t);
        *(float4*)&kwf[0][fo] = (float4){t[0], t[1], t[2], t[3]};
        *(float4*)&kwf[0][fo + 4] = (float4){t[4], t[5], t[6], t[7]};
        dec8(sB, t);
        *(float4*)&qwf[0][fo] = (float4){t[0], t[1], t[2], t[3]};
        *(float4*)&qwf[0][fo + 4] = (float4){t[4], t[5], t[6], t[7]};
        dec8(sC, t);
        *(float4*)&kvf[0][fo] = (float4){t[0], t[1], t[2], t[3]};
        *(float4*)&kvf[0][fo + 4] = (float4){t[4], t[5], t[6], t[7]};
    }
    sA = *(const uint4*)(gb + CSB + (size_t)fo * 2);
    sB = *(const uint4*)(gb + CSB + 4096 + (size_t)fo * 2);
    sC = *(const uint4*)(gb + CSB + 8192 + (size_t)fo * 2);
    __syncthreads();

    float S[8];
#pragma unroll
    for (int i = 0; i < 8; ++i) S[i] = 0.f;
    int p = 0;

    for (int n = 0; n < 256; ++n) {
        const char* cbn = gb + (size_t)n * CSB;
        uint4 vt0 = *(const uint4*)(cbn + 12288 + (size_t)col * 32);
        uint4 vt1 = *(const uint4*)(cbn + 12288 + (size_t)col * 32 + 16);
        uint4 wu  = *(const uint4*)(cbn + 16384 + (size_t)l16 * 16);
        float um[16];
        *(float4*)&um[0]  = *(const float4*)(cbn + 16640 + (size_t)l16 * 64);
        *(float4*)&um[4]  = *(const float4*)(cbn + 16640 + (size_t)l16 * 64 + 16);
        *(float4*)&um[8]  = *(const float4*)(cbn + 16640 + (size_t)l16 * 64 + 32);
        *(float4*)&um[12] = *(const float4*)(cbn + 16640 + (size_t)l16 * 64 + 48);
        // stage chunk n+1 into buffer p^1
        if (n < 255) {
            float t[8];
            dec8(sA, t);
            *(float4*)&kwf[p ^ 1][fo] = (float4){t[0], t[1], t[2], t[3]};
            *(float4*)&kwf[p ^ 1][fo + 4] = (float4){t[4], t[5], t[6], t[7]};
            dec8(sB, t);
            *(float4*)&qwf[p ^ 1][fo] = (float4){t[0], t[1], t[2], t[3]};
            *(float4*)&qwf[p ^ 1][fo + 4] = (float4){t[4], t[5], t[6], t[7]};
            dec8(sC, t);
            *(float4*)&kvf[p ^ 1][fo] = (float4){t[0], t[1], t[2], t[3]};
            *(float4*)&kvf[p ^ 1][fo + 4] = (float4){t[4], t[5], t[6], t[7]};
        }
        // prefetch chunk n+2 staging
        if (n < 254) {
            const char* pf = gb + (size_t)(n + 2) * CSB;
            sA = *(const uint4*)(pf + (size_t)fo * 2);
            sB = *(const uint4*)(pf + 4096 + (size_t)fo * 2);
            sC = *(const uint4*)(pf + 8192 + (size_t)fo * 2);
        }
        // Y = KW.S0, Z = QW.S0
        float Y[16], Z[16];
#pragma unroll
        for (int i = 0; i < 16; ++i) {
            float4 ka = *(const float4*)&kwf[p][i * 128 + l16 * 8];
            float4 kb = *(const float4*)&kwf[p][i * 128 + l16 * 8 + 4];
            float4 qa = *(const float4*)&qwf[p][i * 128 + l16 * 8];
            float4 qb = *(const float4*)&qwf[p][i * 128 + l16 * 8 + 4];
            Y[i] = ka.x * S[0] + ka.y * S[1] + ka.z * S[2] + ka.w * S[3]
                 + kb.x * S[4] + kb.y * S[5] + kb.z * S[6] + kb.w * S[7];
            Z[i] = qa.x * S[0] + qa.y * S[1] + qa.z * S[2] + qa.w * S[3]
                 + qb.x * S[4] + qb.y * S[5] + qb.z * S[6] + qb.w * S[7];
        }
#pragma unroll
        for (int m = 1; m <= 8; m <<= 1) {
#pragma unroll
            for (int i = 0; i < 16; ++i) {
                Y[i] += __shfl_xor(Y[i], m);
                Z[i] += __shfl_xor(Z[i], m);
            }
        }
        // r' = v - Y
        float rr[16];
        {
            float vf[16];
            dec8(vt0, vf);
            dec8(vt1, vf + 8);
#pragma unroll
            for (int j = 0; j < 16; ++j) rr[j] = vf[j] - Y[j];
        }
        // o for i = l16
        float Zs = Z[0];
#pragma unroll
        for (int j = 1; j < 16; ++j) Zs = (l16 == j) ? Z[j] : Zs;
        float oo = Zs;
#pragma unroll
        for (int j = 0; j < 16; ++j) oo = fmaf(um[j], rr[j], oo);
        opb[(size_t)(n * 16 + l16) * 2048] = f2b(oo);
        // S = W15*S + sum_m KV'_m * r'_m
        {
            float wf[8];
            dec8(wu, wf);
#pragma unroll
            for (int d = 0; d < 8; ++d) S[d] *= wf[d];
        }
#pragma unroll
        for (int m2 = 0; m2 < 16; ++m2) {
            float4 va = *(const float4*)&kvf[p][m2 * 128 + l16 * 8];
            float4 vb = *(const float4*)&kvf[p][m2 * 128 + l16 * 8 + 4];
            S[0] = fmaf(va.x, rr[m2], S[0]);
            S[1] = fmaf(va.y, rr[m2], S[1]);
            S[2] = fmaf(va.z, rr[m2], S[2]);
            S[3] = fmaf(va.w, rr[m2], S[3]);
            S[4] = fmaf(vb.x, rr[m2], S[4]);
            S[5] = fmaf(vb.y, rr[m2], S[5]);
            S[6] = fmaf(vb.z, rr[m2], S[6]);
            S[7] = fmaf(vb.w, rr[m2], S[7]);
        }
        __syncthreads();
        p ^= 1;
    }
}

// ---------------------------------------------------------------------------
// gated RMS norm: og = bf16( o*rsqrt(mean o^2+1e-5)*norm_w*sigmoid(gate+bg2) )
// ---------------------------------------------------------------------------
__global__ __launch_bounds__(256) void normgate_kernel(
    const ushort* __restrict__ o, const ushort* __restrict__ gate,
    const float* __restrict__ bg2, const float* __restrict__ norm_w,
    ushort* __restrict__ og) {
    const int lane = threadIdx.x & 63;
    const int wstart = (blockIdx.x * 256 + threadIdx.x) >> 6;
    const int nw = (gridDim.x * 256) >> 6;
    for (int pair = wstart; pair < TB * 16; pair += nw) {
        const int t = pair >> 4, h = pair & 15;
        const size_t basep = (size_t)t * 2048 + h * 128 + lane * 2;
        unsigned int ovu = *(const unsigned int*)(o + basep);
        float o0 = __uint_as_float(ovu << 16);
        float o1 = __uint_as_float(ovu & 0xffff0000u);
        float ss = o0 * o0 + o1 * o1;
#pragma unroll
        for (int m = 32; m >= 1; m >>= 1) ss += __shfl_xor(ss, m);
        float rn = rsqrtf(ss * (1.0f / 128.0f) + 1e-5f);
        const int dg = h * 128 + lane * 2;
        unsigned int gv = *(const unsigned int*)(gate + basep);
        float g0 = __uint_as_float(gv << 16) + bg2[dg];
        float g1 = __uint_as_float(gv & 0xffff0000u) + bg2[dg + 1];
        float w0 = norm_w[lane * 2], w1 = norm_w[lane * 2 + 1];
        float r0 = o0 * rn * w0 / (1.0f + expf(-g0));
        float r1 = o1 * rn * w1 / (1.0f + expf(-g1));
        unsigned int outw = (unsigned int)f2b(r0) | ((unsigned int)f2b(r1) << 16);
        *(unsigned int*)(og + basep) = outw;
    }
}

// ---------------------------------------------------------------------------
extern "C" void kernel_launch(void* const* d_in, const int* in_sizes, int n_in,
                              void* d_out, int out_size, void* d_ws, size_t ws_size,
                              hipStream_t stream) {
    const float* x = (const float*)d_in[0];
    const float* Wq = (const float*)d_in[1];
    const float* Wk = (const float*)d_in[2];
    const float* Wv = (const float*)d_in[3];
    const float* convq = (const float*)d_in[4];
    const float* convk = (const float*)d_in[5];
    const float* convv = (const float*)d_in[6];
    const float* A_log = (const float*)d_in[7];
    const float* dt_bias = (const float*)d_in[8];
    const float* Wsv = (const float*)d_in[9];
    const float* Wb1 = (const float*)d_in[10];
    const float* bb1 = (const float*)d_in[11];
    const float* Wb2 = (const float*)d_in[12];
    const float* bb2 = (const float*)d_in[13];
    const float* Wa1 = (const float*)d_in[14];
    const float* ba1 = (const float*)d_in[15];
    const float* Wa2 = (const float*)d_in[16];
    const float* ba2 = (const float*)d_in[17];
    const float* Wg1 = (const float*)d_in[18];
    const float* Wg2 = (const float*)d_in[19];
    const float* bg2 = (const float*)d_in[20];
    const float* norm_w = (const float*)d_in[21];
    const float* Wo = (const float*)d_in[22];

    // ---- workspace layout (bytes) ----
    const size_t PBATCH   = (size_t)16 * BHSH * 2;      // 87,031,808 per batch
    const size_t OFF_WQKV = 0;                          // 25,165,824
    const size_t OFF_XB   = OFF_WQKV + 25165824;        // 16,777,216
    const size_t OFF_WG1  = OFF_XB + 16777216;          //    524,288
    const size_t OFF_WG2  = OFF_WG1 + 524288;           //    524,288
    const size_t OFF_QKV  = OFF_WG2 + 524288;           // 50,331,648
    const size_t OFF_P    = OFF_QKV + 50331648;         // = 93,323,264
    const size_t NEED_B   = OFF_P + PBATCH;             // ~180.4 MB
    const size_t NEED_A   = OFF_P + 2 * PBATCH;         // ~267.4 MB
    if (ws_size < NEED_B) return;  // diagnostic guard
    const bool planA = (ws_size >= NEED_A);

    char* ws = (char*)d_ws;
    ushort* wqkv = (ushort*)(ws + OFF_WQKV);
    ushort* xb   = (ushort*)(ws + OFF_XB);
    ushort* wg1b = (ushort*)(ws + OFF_WG1);
    ushort* wg2b = (ushort*)(ws + OFF_WG2);
    ushort* qkvb = (ushort*)(ws + OFF_QKV);
    ushort* P    = (ushort*)(ws + OFF_P);
    // phase-3 aliases in the dead qkv region:
    ushort* gateb = qkvb;                               // +0        16,777,216
    ushort* xg1b  = (ushort*)(ws + OFF_QKV + 16777216); // +16.78M    1,048,576
    ushort* ogb   = (ushort*)(ws + OFF_QKV + 17825792); // +17.83M   16,777,216
    ushort* wob   = (ushort*)(ws + OFF_QKV + 34603008); // +34.60M    8,388,608
    ushort* obp = planA ? (ushort*)(ws + OFF_WQKV) : xb;

    // weight casts
    cast_f32_bf16<<<512, 256, 0, stream>>>(Wq, wqkv, 4194304);
    cast_f32_bf16<<<512, 256, 0, stream>>>(Wk, wqkv + 4194304, 4194304);
    cast_f32_bf16<<<512, 256, 0, stream>>>(Wv, wqkv + 8388608, 4194304);
    cast_f32_bf16<<<64, 256, 0, stream>>>(Wg1, wg1b, 262144);
    cast_f32_bf16<<<64, 256, 0, stream>>>(Wg2, wg2b, 262144);

    if (planA) {
        for (int b = 0; b < 2; ++b) {
            cast_f32_bf16<<<512, 256, 0, stream>>>(x + (size_t)b * TB * 2048, xb, TB * 2048);
            gemm_bf16<ushort><<<dim3(48, TB / 128), 256, 0, stream>>>(xb, wqkv, qkvb, TB, 6144, 2048);
            conv_stats_kernel<<<TB * 16 / 8, 256, 0, stream>>>(qkvb, convq, convk, convv, Wsv,
                Wb1, bb1, Wb2, bb2, Wa1, ba1, Wa2, ba2, A_log, dt_bias,
                P + (size_t)b * 16 * BHSH);
        }
        phasea_kernel<<<2048, 256, 0, stream>>>(P);
        phaseb_kernel<<<256, 256, 0, stream>>>(P, obp, 31, 5);
        cast_f32_bf16<<<512, 256, 0, stream>>>(Wo, wob, 4194304);
        for (int b = 0; b < 2; ++b) {
            ushort* xstage = ogb;
            cast_f32_bf16<<<512, 256, 0, stream>>>(x + (size_t)b * TB * 2048, xstage, TB * 2048);
            gemm_bf16<ushort><<<dim3(1, TB / 128), 256, 0, stream>>>(xstage, wg1b, xg1b, TB, 128, 2048);
            gemm_bf16<ushort><<<dim3(16, TB / 128), 256, 0, stream>>>(xg1b, wg2b, gateb, TB, 2048, 128);
            normgate_kernel<<<2048, 256, 0, stream>>>(obp + (size_t)b * TB * 2048, gateb, bg2, norm_w, ogb);
            gemm_bf16<float><<<dim3(16, TB / 128), 256, 0, stream>>>(ogb, wob,
                (float*)d_out + (size_t)b * TB * 2048, TB, 2048, 2048);
        }
    } else {
        for (int b = 0; b < 2; ++b) {
            const float* xbp = x + (size_t)b * TB * 2048;
            float* outp = (float*)d_out + (size_t)b * TB * 2048;
            cast_f32_bf16<<<512, 256, 0, stream>>>(xbp, xb, TB * 2048);
            gemm_bf16<ushort><<<dim3(48, TB / 128), 256, 0, stream>>>(xb, wqkv, qkvb, TB, 6144, 2048);
            conv_stats_kernel<<<TB * 16 / 8, 256, 0, stream>>>(qkvb, convq, convk, convv, Wsv,
                Wb1, bb1, Wb2, bb2, Wa1, ba1, Wa2, ba2, A_log, dt_bias, P);
            gemm_bf16<ushort><<<dim3(1, TB / 128), 256, 0, stream>>>(xb, wg1b, xg1b, TB, 128, 2048);
            gemm_bf16<ushort><<<dim3(16, TB / 128), 256, 0, stream>>>(xg1b, wg2b, gateb, TB, 2048, 128);
            cast_f32_bf16<<<512, 256, 0, stream>>>(Wo, wob, 4194304);
            phasea_kernel<<<1024, 256, 0, stream>>>(P);
            phaseb_kernel<<<128, 256, 0, stream>>>(P, xb, 15, 4);   // xb dead -> ob
            normgate_kernel<<<2048, 256, 0, stream>>>(xb, gateb, bg2, norm_w, ogb);
            gemm_bf16<float><<<dim3(16, TB / 128), 256, 0, stream>>>(ogb, wob, outp, TB, 2048, 2048);
        }
    }
}

// Round 12
// 1784.643 us; speedup vs baseline: 1.5852x; 1.1421x over previous
//
#include <hip/hip_runtime.h>
#include <hip/hip_bf16.h>

// ---------------------------------------------------------------------------
// SurpriseKimiDeltaAttention  (B=2, T=4096, H=2048, NH=16, DK=DV=128, CONV=4)
// R12 = R11 chunked scan + phaseb LDS XOR-swizzle (kill 4-way bank conflicts)
//       + owner-reduce/gather reduction (46 ds-ops vs 128).
// ---------------------------------------------------------------------------

typedef __attribute__((ext_vector_type(8))) short bf16x8;
typedef __attribute__((ext_vector_type(4))) float floatx4;

#define TB 4096
#define RSH 664                      // shorts per record
#define NREC 4096
#define BHSH ((size_t)NREC * RSH)    // shorts per (b,h) stream
#define CSB ((size_t)16 * RSH * 2)   // chunk span bytes = 21248

__device__ __forceinline__ float b2f(ushort u) {
    union { unsigned int u; float f; } c; c.u = ((unsigned int)u) << 16; return c.f;
}
__device__ __forceinline__ ushort f2b(float f) {
    union { float f; unsigned int u; } c; c.f = f;
    unsigned int r = (c.u + 0x7fffu + ((c.u >> 16) & 1u)) >> 16;
    return (ushort)r;
}
__device__ __forceinline__ float silu(float x) { return x / (1.0f + expf(-x)); }
__device__ __forceinline__ void dec8(uint4 u, float* f) {
    f[0] = __uint_as_float(u.x << 16); f[1] = __uint_as_float(u.x & 0xffff0000u);
    f[2] = __uint_as_float(u.y << 16); f[3] = __uint_as_float(u.y & 0xffff0000u);
    f[4] = __uint_as_float(u.z << 16); f[5] = __uint_as_float(u.z & 0xffff0000u);
    f[6] = __uint_as_float(u.w << 16); f[7] = __uint_as_float(u.w & 0xffff0000u);
}

// ---------------------------------------------------------------------------
__global__ __launch_bounds__(256) void cast_f32_bf16(const float* __restrict__ in,
                                                     ushort* __restrict__ out, int n) {
    int i = (blockIdx.x * 256 + threadIdx.x) * 4;
    int stride = gridDim.x * 256 * 4;
    for (; i + 3 < n; i += stride) {
        float4 v = *(const float4*)(in + i);
        ushort4 u;
        u.x = f2b(v.x); u.y = f2b(v.y); u.z = f2b(v.z); u.w = f2b(v.w);
        *(ushort4*)(out + i) = u;
    }
}

// ---------------------------------------------------------------------------
// bf16 MFMA GEMM: C[M][N] = A[M][K] @ B[N][K]^T  (row-major, K contiguous)
// ---------------------------------------------------------------------------
template <typename CT>
__global__ __launch_bounds__(256) void gemm_bf16(const ushort* __restrict__ A,
                                                 const ushort* __restrict__ B,
                                                 CT* __restrict__ C, int M, int N, int K) {
    __shared__ ushort As[128 * 40];
    __shared__ ushort Bs[128 * 40];
    const int tid = threadIdx.x;
    const int lane = tid & 63, wid = tid >> 6;
    const int wr = wid >> 1, wc = wid & 1;
    const int bm = blockIdx.y, bn = blockIdx.x;

    const int r0 = tid >> 2;
    const int kc0 = (tid & 3) * 8;
    const size_t aoff0 = (size_t)(bm * 128 + r0) * K + kc0;
    const size_t aoff1 = aoff0 + (size_t)64 * K;
    const size_t boff0 = (size_t)(bn * 128 + r0) * K + kc0;
    const size_t boff1 = boff0 + (size_t)64 * K;
    const int lw0 = r0 * 40 + kc0;
    const int lw1 = (r0 + 64) * 40 + kc0;

    const int arow = wr * 64 + (lane & 15);
    const int brow = wc * 64 + (lane & 15);
    const int kg = (lane >> 4) * 8;

    floatx4 acc[4][4];
#pragma unroll
    for (int m = 0; m < 4; ++m)
#pragma unroll
        for (int n = 0; n < 4; ++n) acc[m][n] = (floatx4){0.f, 0.f, 0.f, 0.f};

    uint4 ra0 = *(const uint4*)(A + aoff0);
    uint4 ra1 = *(const uint4*)(A + aoff1);
    uint4 rb0 = *(const uint4*)(B + boff0);
    uint4 rb1 = *(const uint4*)(B + boff1);

    for (int kt = 32; kt <= K; kt += 32) {
        __syncthreads();
        *(uint4*)(As + lw0) = ra0;
        *(uint4*)(As + lw1) = ra1;
        *(uint4*)(Bs + lw0) = rb0;
        *(uint4*)(Bs + lw1) = rb1;
        __syncthreads();
        if (kt < K) {
            ra0 = *(const uint4*)(A + aoff0 + kt);
            ra1 = *(const uint4*)(A + aoff1 + kt);
            rb0 = *(const uint4*)(B + boff0 + kt);
            rb1 = *(const uint4*)(B + boff1 + kt);
        }
        bf16x8 af[4], bfr[4];
#pragma unroll
        for (int m = 0; m < 4; ++m) af[m] = *(const bf16x8*)(As + (arow + m * 16) * 40 + kg);
#pragma unroll
        for (int n = 0; n < 4; ++n) bfr[n] = *(const bf16x8*)(Bs + (brow + n * 16) * 40 + kg);
#pragma unroll
        for (int m = 0; m < 4; ++m)
#pragma unroll
            for (int n = 0; n < 4; ++n)
                acc[m][n] = __builtin_amdgcn_mfma_f32_16x16x32_bf16(af[m], bfr[n], acc[m][n], 0, 0, 0);
    }

    const int crow0 = bm * 128 + wr * 64 + (lane >> 4) * 4;
    const int ccol0 = bn * 128 + wc * 64 + (lane & 15);
#pragma unroll
    for (int m = 0; m < 4; ++m)
#pragma unroll
        for (int n = 0; n < 4; ++n)
#pragma unroll
            for (int j = 0; j < 4; ++j) {
                int row = crow0 + m * 16 + j;
                int col = ccol0 + n * 16;
                if constexpr (sizeof(CT) == 2)
                    C[(size_t)row * N + col] = (CT)f2b(acc[m][n][j]);
                else
                    C[(size_t)row * N + col] = (CT)acc[m][n][j];
            }
}

// ---------------------------------------------------------------------------
// conv + silu + surprise stats + beta/amp MLPs -> records (one batch)
// lane owns dims (2*lane, 2*lane+1); record: q~@128 k@256 E@384 v@512 beta@640
// ---------------------------------------------------------------------------
__global__ __launch_bounds__(256) void conv_stats_kernel(
    const ushort* __restrict__ qkv,
    const float* __restrict__ convq, const float* __restrict__ convk,
    const float* __restrict__ convv, const float* __restrict__ Wsv,
    const float* __restrict__ Wb1, const float* __restrict__ bb1,
    const float* __restrict__ Wb2, const float* __restrict__ bb2,
    const float* __restrict__ Wa1, const float* __restrict__ ba1,
    const float* __restrict__ Wa2, const float* __restrict__ ba2,
    const float* __restrict__ A_log, const float* __restrict__ dt_bias,
    ushort* __restrict__ P) {
    __shared__ ushort wsv_s[128 * 136];
    __shared__ float k_sh[4][128];
    for (int i = threadIdx.x; i < 128 * 128; i += 256) {
        int row = i >> 7, col = i & 127;
        wsv_s[row * 136 + col] = f2b(Wsv[i]);
    }
    __syncthreads();
    const int wid = threadIdx.x >> 6, lane = threadIdx.x & 63;

    for (int it = 0; it < 2; ++it) {
        const int pair = blockIdx.x * 8 + it * 4 + wid;   // [0, TB*16)
        const int t = pair >> 4, h = pair & 15;
        const int c0 = h * 128 + 2 * lane, c1 = c0 + 1;

        float wq[4], wq2[4], wk[4], wk2[4], wv[4], wv2[4];
#pragma unroll
        for (int i2 = 0; i2 < 4; ++i2) {
            wq[i2] = convq[c0 * 4 + i2]; wq2[i2] = convq[c1 * 4 + i2];
            wk[i2] = convk[c0 * 4 + i2]; wk2[i2] = convk[c1 * 4 + i2];
            wv[i2] = convv[c0 * 4 + i2]; wv2[i2] = convv[c1 * 4 + i2];
        }
        float aq0 = 0, aq1 = 0, ak0 = 0, ak1 = 0, av0 = 0, av1 = 0;
#pragma unroll
        for (int i2 = 0; i2 < 4; ++i2) {
            int tt = t - 3 + i2;
            if (tt >= 0) {
                const ushort* rowp = qkv + (size_t)tt * 6144 + h * 128;
                uint xq = *(const uint*)(rowp + 2 * lane);
                uint xk = *(const uint*)(rowp + 2048 + 2 * lane);
                uint xv = *(const uint*)(rowp + 4096 + 2 * lane);
                aq0 = fmaf(__uint_as_float(xq << 16), wq[i2], aq0);
                aq1 = fmaf(__uint_as_float(xq & 0xffff0000u), wq2[i2], aq1);
                ak0 = fmaf(__uint_as_float(xk << 16), wk[i2], ak0);
                ak1 = fmaf(__uint_as_float(xk & 0xffff0000u), wk2[i2], ak1);
                av0 = fmaf(__uint_as_float(xv << 16), wv[i2], av0);
                av1 = fmaf(__uint_as_float(xv & 0xffff0000u), wv2[i2], av1);
            }
        }
        float q0 = silu(aq0), q1 = silu(aq1);
        float k0 = silu(ak0), k1 = silu(ak1);
        float v0 = silu(av0), v1 = silu(av1);

        __syncthreads();
        k_sh[wid][2 * lane] = k0;
        k_sh[wid][2 * lane + 1] = k1;
        __syncthreads();

        float vh0 = 0.f, vh1 = 0.f;
        const ushort* wr0 = wsv_s + (2 * lane) * 136;
        const ushort* wr1 = wsv_s + (2 * lane + 1) * 136;
#pragma unroll 4
        for (int j = 0; j < 128; j += 8) {
            float4 ka = *(const float4*)&k_sh[wid][j];
            float4 kb = *(const float4*)&k_sh[wid][j + 4];
            uint4 wa = *(const uint4*)(wr0 + j);
            uint4 wb = *(const uint4*)(wr1 + j);
            vh0 = fmaf(__uint_as_float(wa.x << 16), ka.x, vh0);
            vh0 = fmaf(__uint_as_float(wa.x & 0xffff0000u), ka.y, vh0);
            vh0 = fmaf(__uint_as_float(wa.y << 16), ka.z, vh0);
            vh0 = fmaf(__uint_as_float(wa.y & 0xffff0000u), ka.w, vh0);
            vh0 = fmaf(__uint_as_float(wa.z << 16), kb.x, vh0);
            vh0 = fmaf(__uint_as_float(wa.z & 0xffff0000u), kb.y, vh0);
            vh0 = fmaf(__uint_as_float(wa.w << 16), kb.z, vh0);
            vh0 = fmaf(__uint_as_float(wa.w & 0xffff0000u), kb.w, vh0);
            vh1 = fmaf(__uint_as_float(wb.x << 16), ka.x, vh1);
            vh1 = fmaf(__uint_as_float(wb.x & 0xffff0000u), ka.y, vh1);
            vh1 = fmaf(__uint_as_float(wb.y << 16), ka.z, vh1);
            vh1 = fmaf(__uint_as_float(wb.y & 0xffff0000u), ka.w, vh1);
            vh1 = fmaf(__uint_as_float(wb.z << 16), kb.x, vh1);
            vh1 = fmaf(__uint_as_float(wb.z & 0xffff0000u), kb.y, vh1);
            vh1 = fmaf(__uint_as_float(wb.w << 16), kb.z, vh1);
            vh1 = fmaf(__uint_as_float(wb.w & 0xffff0000u), kb.w, vh1);
        }

        float e0 = vh0 - v0, e1 = vh1 - v1;
        float se2 = e0 * e0 + e1 * e1;
        float sl1 = fabsf(e0) + fabsf(e1);
        float shv = vh0 * v0 + vh1 * v1;
        float shh = vh0 * vh0 + vh1 * vh1;
        float svv = v0 * v0 + v1 * v1;
        float sk2 = k0 * k0 + k1 * k1;
        float sq2 = q0 * q0 + q1 * q1;
#pragma unroll
        for (int m = 32; m >= 1; m >>= 1) {
            se2 += __shfl_xor(se2, m);
            sl1 += __shfl_xor(sl1, m);
            shv += __shfl_xor(shv, m);
            shh += __shfl_xor(shh, m);
            svv += __shfl_xor(svv, m);
            sk2 += __shfl_xor(sk2, m);
            sq2 += __shfl_xor(sq2, m);
        }
        float s_l2 = sqrtf(se2 + 1e-6f);
        float s_l1 = sl1;
        float s_cos = 1.0f - shv / (sqrtf(shh + 1e-6f) * sqrtf(svv + 1e-6f) + 1e-6f);

        const int j2 = lane & 31;
        const float* W1 = (lane < 32) ? Wb1 : Wa1;
        const float* b1 = (lane < 32) ? bb1 : ba1;
        const float* W2 = (lane < 32) ? Wb2 : Wa2;
        float pre = W1[j2 * 3] * s_l2 + W1[j2 * 3 + 1] * s_l1 + W1[j2 * 3 + 2] * s_cos + b1[j2];
        float val = W2[j2] * silu(pre);
#pragma unroll
        for (int m = 16; m >= 1; m >>= 1) val += __shfl_xor(val, m);
        float pre_b = __shfl(val, 0) + bb2[0];
        float pre_a = __shfl(val, 32) + ba2[0];
        float betav = 1.0f / (1.0f + expf(-pre_b));
        float amp = pre_a;

        float knorm = sqrtf(sk2);
        float rinv = amp / fmaxf(knorm, 1e-12f);
        float ah = expf(A_log[h]);
        float gr0 = fmaf(k0, rinv, dt_bias[c0]);
        float gr1 = fmaf(k1, rinv, dt_bias[c1]);
        float sp0 = (gr0 > 20.f) ? gr0 : log1pf(expf(gr0));
        float sp1 = (gr1 > 20.f) ? gr1 : log1pf(expf(gr1));

        ushort* rec = P + (size_t)h * BHSH + (size_t)t * RSH;
        float kinv = rsqrtf(sk2 + 1e-6f);
        float qinv = rsqrtf(sq2 + 1e-6f) * 0.08838834764831845f;  // * DK^-0.5
        *(uint*)(rec + 128 + 2 * lane) = (uint)f2b(q0 * qinv) | ((uint)f2b(q1 * qinv) << 16);
        *(uint*)(rec + 256 + 2 * lane) = (uint)f2b(k0 * kinv) | ((uint)f2b(k1 * kinv) << 16);
        *(uint*)(rec + 384 + 2 * lane) = (uint)f2b(expf(-ah * sp0)) | ((uint)f2b(expf(-ah * sp1)) << 16);
        *(uint*)(rec + 512 + 2 * lane) = (uint)f2b(v0) | ((uint)f2b(v1) << 16);
        if (lane == 0) *(float*)(rec + 640) = betav;
    }
}

// ---------------------------------------------------------------------------
// phase A: one wave per (stream, chunk).  In-place chunk-block construction.
// ---------------------------------------------------------------------------
__global__ __launch_bounds__(256, 1) void phasea_kernel(ushort* __restrict__ P) {
    __shared__ float lA[4][16][16];
    __shared__ float lU[4][16][16];
    __shared__ float lM[4][16][16];
    const int wid = threadIdx.x >> 6, lane = threadIdx.x & 63;
    const int g = blockIdx.x * 4 + wid;
    const int s = g >> 8, n = g & 255;
    ushort* cb = P + (size_t)s * BHSH + (size_t)n * (16 * RSH);
    char* sb = (char*)cb;
    float (*A_)[16] = lA[wid];
    float (*U_)[16] = lU[wid];
    float (*M_)[16] = lM[wid];

    float kf[32], Ef[32], qf[32], bf[16];
    uint vq[16];
#pragma unroll
    for (int i = 0; i < 16; ++i) {
        const ushort* r = cb + i * RSH;
        uint ku = *(const uint*)(r + 256 + 2 * lane);
        uint eu = *(const uint*)(r + 384 + 2 * lane);
        uint qu = *(const uint*)(r + 128 + 2 * lane);
        vq[i] = *(const uint*)(r + 512 + 2 * lane);
        bf[i] = *(const float*)(r + 640);
        kf[2 * i]     = __uint_as_float(ku << 16);
        kf[2 * i + 1] = __uint_as_float(ku & 0xffff0000u);
        Ef[2 * i]     = __uint_as_float(eu << 16);
        Ef[2 * i + 1] = __uint_as_float(eu & 0xffff0000u);
        qf[2 * i]     = __uint_as_float(qu << 16);
        qf[2 * i + 1] = __uint_as_float(qu & 0xffff0000u);
    }

    float R[32];
    float Pc0 = 1.f, Pc1 = 1.f;
#pragma unroll
    for (int i = 0; i < 16; ++i) {
#pragma unroll
        for (int j = 0; j < 16; ++j) if (j < i) {
            R[2 * j] *= Ef[2 * i];
            R[2 * j + 1] *= Ef[2 * i + 1];
        }
        float Tr[16], Ur[16];
#pragma unroll
        for (int j = 0; j < 16; ++j) { Tr[j] = 0.f; Ur[j] = 0.f; }
#pragma unroll
        for (int j = 0; j < 16; ++j) if (j < i) {
            Tr[j] = kf[2 * i] * R[2 * j] + kf[2 * i + 1] * R[2 * j + 1];
            Ur[j] = qf[2 * i] * R[2 * j] + qf[2 * i + 1] * R[2 * j + 1];
        }
        Ur[i] = qf[2 * i] * kf[2 * i] + qf[2 * i + 1] * kf[2 * i + 1];
#pragma unroll
        for (int m = 1; m <= 32; m <<= 1) {
#pragma unroll
            for (int j = 0; j < 16; ++j) if (j <= i) {
                if (j < i) Tr[j] += __shfl_xor(Tr[j], m);
                Ur[j] += __shfl_xor(Ur[j], m);
            }
        }
        if (lane == 0) {
#pragma unroll
            for (int j = 0; j < 16; ++j) if (j < i) A_[i][j] = bf[i] * Tr[j];
#pragma unroll
            for (int j = 0; j < 16; ++j) if (j <= i) U_[i][j] = Ur[j];
        }
        R[2 * i] = kf[2 * i];
        R[2 * i + 1] = kf[2 * i + 1];
        Pc0 *= Ef[2 * i];
        Pc1 *= Ef[2 * i + 1];
        *(uint*)(sb + (size_t)i * 256 + 4 * lane) =
            (uint)f2b(kf[2 * i] * Pc0) | ((uint)f2b(kf[2 * i + 1] * Pc1) << 16);
        *(uint*)(sb + 4096 + (size_t)i * 256 + 4 * lane) =
            (uint)f2b(qf[2 * i] * Pc0) | ((uint)f2b(qf[2 * i + 1] * Pc1) << 16);
    }
    *(uint*)(sb + 16384 + 4 * lane) = (uint)f2b(Pc0) | ((uint)f2b(Pc1) << 16);
    {
        uint lw[8], hw[8];
#pragma unroll
        for (int w = 0; w < 8; ++w) {
            lw[w] = (vq[2 * w] & 0xffffu) | (vq[2 * w + 1] << 16);
            hw[w] = (vq[2 * w] >> 16) | (vq[2 * w + 1] & 0xffff0000u);
        }
        char* vt0 = sb + 12288 + (size_t)(2 * lane) * 32;
        *(uint4*)(vt0)      = (uint4){lw[0], lw[1], lw[2], lw[3]};
        *(uint4*)(vt0 + 16) = (uint4){lw[4], lw[5], lw[6], lw[7]};
        *(uint4*)(vt0 + 32) = (uint4){hw[0], hw[1], hw[2], hw[3]};
        *(uint4*)(vt0 + 48) = (uint4){hw[4], hw[5], hw[6], hw[7]};
    }
    const int mcol = lane & 15;
    float M[16];
#pragma unroll
    for (int i = 0; i < 16; ++i) {
        float acc = (i == mcol) ? bf[i] : 0.f;
#pragma unroll
        for (int j = 0; j < 16; ++j) if (j < i) acc -= A_[i][j] * M[j];
        M[i] = acc;
    }
    if (lane < 16) {
#pragma unroll
        for (int j = 0; j < 16; ++j) M_[j][lane] = M[j];
    }
    if (lane < 16) {
#pragma unroll
        for (int i = 0; i < 16; ++i) {
            float acc = 0.f;
#pragma unroll
            for (int j = 0; j < 16; ++j) if (j <= i) acc += U_[i][j] * M[j];
            *(float*)(sb + 16640 + (size_t)i * 64 + 4 * lane) = acc;
        }
    }
#pragma unroll
    for (int m = 0; m < 16; ++m) {
        float a0 = 0.f, a1 = 0.f;
#pragma unroll
        for (int j = 0; j < 16; ++j) if (j >= m) {
            float mv = M_[j][m];
            a0 = fmaf(mv, R[2 * j], a0);
            a1 = fmaf(mv, R[2 * j + 1], a1);
        }
        *(uint*)(sb + 8192 + (size_t)m * 256 + 4 * lane) =
            (uint)f2b(a0) | ((uint)f2b(a1) << 16);
    }
}

// ---------------------------------------------------------------------------
// owner-reduce: lane l16 (within 16-lane group) ends with full sum of Y[l16].
// 15 shfls (value-halving butterfly).
// ---------------------------------------------------------------------------
__device__ __forceinline__ float ownred16(const float* Y, int l16) {
    float a8[8], a4[4], a2[2];
    const bool b0 = (l16 & 1) != 0;
#pragma unroll
    for (int k = 0; k < 8; ++k) {
        float t  = b0 ? Y[2 * k] : Y[2 * k + 1];
        float kp = b0 ? Y[2 * k + 1] : Y[2 * k];
        a8[k] = kp + __shfl_xor(t, 1);
    }
    const bool b1 = (l16 & 2) != 0;
#pragma unroll
    for (int k = 0; k < 4; ++k) {
        float t  = b1 ? a8[2 * k] : a8[2 * k + 1];
        float kp = b1 ? a8[2 * k + 1] : a8[2 * k];
        a4[k] = kp + __shfl_xor(t, 2);
    }
    const bool b2 = (l16 & 4) != 0;
#pragma unroll
    for (int k = 0; k < 2; ++k) {
        float t  = b2 ? a4[2 * k] : a4[2 * k + 1];
        float kp = b2 ? a4[2 * k + 1] : a4[2 * k];
        a2[k] = kp + __shfl_xor(t, 4);
    }
    const bool b3 = (l16 & 8) != 0;
    float t  = b3 ? a2[0] : a2[1];
    float kp = b3 ? a2[1] : a2[0];
    return kp + __shfl_xor(t, 8);
}

// ---------------------------------------------------------------------------
// phase B: sequential over 256 chunks; block = (stream, 16-col slice).
// LDS XOR-swizzled (conflict-free); owner-reduce + 16-shfl rr gather.
// ---------------------------------------------------------------------------
__global__ __launch_bounds__(256, 1) void phaseb_kernel(const ushort* __restrict__ P,
                                                        ushort* __restrict__ ob,
                                                        int smask, int sshift) {
    __shared__ float kwf[2][2048];
    __shared__ float qwf[2][2048];
    __shared__ float kvf[2][2048];
    const int tid = threadIdx.x;
    const int l16 = tid & 15, cg = tid >> 4;
    const int s = blockIdx.x & smask, c = blockIdx.x >> sshift;
    const int b = s >> 4, h = s & 15;
    const int col = c * 16 + cg;
    const char* gb = (const char*)(P + (size_t)s * BHSH);
    ushort* opb = ob + (size_t)b * (TB * 2048) + h * 128 + col;
    const int fo = tid * 8;
    // LDS float-index swizzle: phys = logical ^ (((logical>>5)&1)<<2)
    const int cw = ((tid >> 2) & 1) << 2;      // constant for writes (logical fo..fo+7)
    const int wo1 = fo ^ cw;
    const int wo2 = (fo + 4) ^ cw;
    const int cr = ((l16 >> 2) & 1) << 2;      // constant for reads (logical l16*8..)
    const int ro1 = (l16 * 8) ^ cr;
    const int ro2 = (l16 * 8 + 4) ^ cr;
    const int gbase = tid & 48;                // 16-group base lane (within wave)

    auto stage = [&](int pb, uint4 sA, uint4 sB, uint4 sC) {
        float t[8];
        dec8(sA, t);
        *(float4*)&kwf[pb][wo1] = (float4){t[0], t[1], t[2], t[3]};
        *(float4*)&kwf[pb][wo2] = (float4){t[4], t[5], t[6], t[7]};
        dec8(sB, t);
        *(float4*)&qwf[pb][wo1] = (float4){t[0], t[1], t[2], t[3]};
        *(float4*)&qwf[pb][wo2] = (float4){t[4], t[5], t[6], t[7]};
        dec8(sC, t);
        *(float4*)&kvf[pb][wo1] = (float4){t[0], t[1], t[2], t[3]};
        *(float4*)&kvf[pb][wo2] = (float4){t[4], t[5], t[6], t[7]};
    };

    uint4 sA = *(const uint4*)(gb + (size_t)fo * 2);
    uint4 sB = *(const uint4*)(gb + 4096 + (size_t)fo * 2);
    uint4 sC = *(const uint4*)(gb + 8192 + (size_t)fo * 2);
    stage(0, sA, sB, sC);
    sA = *(const uint4*)(gb + CSB + (size_t)fo * 2);
    sB = *(const uint4*)(gb + CSB + 4096 + (size_t)fo * 2);
    sC = *(const uint4*)(gb + CSB + 8192 + (size_t)fo * 2);
    __syncthreads();

    float S[8];
#pragma unroll
    for (int i = 0; i < 8; ++i) S[i] = 0.f;
    int p = 0;

    for (int n = 0; n < 256; ++n) {
        const char* cbn = gb + (size_t)n * CSB;
        // per-chunk global loads (latency hidden under Y/Z dots)
        float vf_own = b2f(*(const ushort*)(cbn + 12288 + (size_t)col * 32 + l16 * 2));
        uint4 wu = *(const uint4*)(cbn + 16384 + (size_t)l16 * 16);
        float um[16];
        *(float4*)&um[0]  = *(const float4*)(cbn + 16640 + (size_t)l16 * 64);
        *(float4*)&um[4]  = *(const float4*)(cbn + 16640 + (size_t)l16 * 64 + 16);
        *(float4*)&um[8]  = *(const float4*)(cbn + 16640 + (size_t)l16 * 64 + 32);
        *(float4*)&um[12] = *(const float4*)(cbn + 16640 + (size_t)l16 * 64 + 48);
        // stage chunk n+1 into buffer p^1
        if (n < 255) stage(p ^ 1, sA, sB, sC);
        // prefetch chunk n+2
        if (n < 254) {
            const char* pf = gb + (size_t)(n + 2) * CSB;
            sA = *(const uint4*)(pf + (size_t)fo * 2);
            sB = *(const uint4*)(pf + 4096 + (size_t)fo * 2);
            sC = *(const uint4*)(pf + 8192 + (size_t)fo * 2);
        }
        // Y = KW.S0, Z = QW.S0  (partial over this lane's 8 dims)
        float Y[16], Z[16];
#pragma unroll
        for (int i = 0; i < 16; ++i) {
            float4 ka = *(const float4*)&kwf[p][i * 128 + ro1];
            float4 kb = *(const float4*)&kwf[p][i * 128 + ro2];
            float4 qa = *(const float4*)&qwf[p][i * 128 + ro1];
            float4 qb = *(const float4*)&qwf[p][i * 128 + ro2];
            Y[i] = ka.x * S[0] + ka.y * S[1] + ka.z * S[2] + ka.w * S[3]
                 + kb.x * S[4] + kb.y * S[5] + kb.z * S[6] + kb.w * S[7];
            Z[i] = qa.x * S[0] + qa.y * S[1] + qa.z * S[2] + qa.w * S[3]
                 + qb.x * S[4] + qb.y * S[5] + qb.z * S[6] + qb.w * S[7];
        }
        // owner-reduce (lane l16 gets full Y[l16], Z[l16])
        float Yo = ownred16(Y, l16);
        float Zo = ownred16(Z, l16);
        float rro = vf_own - Yo;
        // gather rr[0..15] to all lanes of the group
        float rrg[16];
#pragma unroll
        for (int j = 0; j < 16; ++j) rrg[j] = __shfl(rro, gbase + j);
        // S-update first (inter-chunk critical chain): S = W15*S + sum_m KV'_m rr_m
        {
            float wf[8];
            dec8(wu, wf);
#pragma unroll
            for (int d = 0; d < 8; ++d) S[d] *= wf[d];
        }
#pragma unroll
        for (int m2 = 0; m2 < 16; ++m2) {
            float4 va = *(const float4*)&kvf[p][m2 * 128 + ro1];
            float4 vb = *(const float4*)&kvf[p][m2 * 128 + ro2];
            S[0] = fmaf(va.x, rrg[m2], S[0]);
            S[1] = fmaf(va.y, rrg[m2], S[1]);
            S[2] = fmaf(va.z, rrg[m2], S[2]);
            S[3] = fmaf(va.w, rrg[m2], S[3]);
            S[4] = fmaf(vb.x, rrg[m2], S[4]);
            S[5] = fmaf(vb.y, rrg[m2], S[5]);
            S[6] = fmaf(vb.z, rrg[m2], S[6]);
            S[7] = fmaf(vb.w, rrg[m2], S[7]);
        }
        // o for row i = l16 (off critical chain)
        float oo = Zo;
#pragma unroll
        for (int j = 0; j < 16; ++j) oo = fmaf(um[j], rrg[j], oo);
        opb[(size_t)(n * 16 + l16) * 2048] = f2b(oo);
        __syncthreads();
        p ^= 1;
    }
}

// ---------------------------------------------------------------------------
// gated RMS norm: og = bf16( o*rsqrt(mean o^2+1e-5)*norm_w*sigmoid(gate+bg2) )
// ---------------------------------------------------------------------------
__global__ __launch_bounds__(256) void normgate_kernel(
    const ushort* __restrict__ o, const ushort* __restrict__ gate,
    const float* __restrict__ bg2, const float* __restrict__ norm_w,
    ushort* __restrict__ og) {
    const int lane = threadIdx.x & 63;
    const int wstart = (blockIdx.x * 256 + threadIdx.x) >> 6;
    const int nw = (gridDim.x * 256) >> 6;
    for (int pair = wstart; pair < TB * 16; pair += nw) {
        const int t = pair >> 4, h = pair & 15;
        const size_t basep = (size_t)t * 2048 + h * 128 + lane * 2;
        unsigned int ovu = *(const unsigned int*)(o + basep);
        float o0 = __uint_as_float(ovu << 16);
        float o1 = __uint_as_float(ovu & 0xffff0000u);
        float ss = o0 * o0 + o1 * o1;
#pragma unroll
        for (int m = 32; m >= 1; m >>= 1) ss += __shfl_xor(ss, m);
        float rn = rsqrtf(ss * (1.0f / 128.0f) + 1e-5f);
        const int dg = h * 128 + lane * 2;
        unsigned int gv = *(const unsigned int*)(gate + basep);
        float g0 = __uint_as_float(gv << 16) + bg2[dg];
        float g1 = __uint_as_float(gv & 0xffff0000u) + bg2[dg + 1];
        float w0 = norm_w[lane * 2], w1 = norm_w[lane * 2 + 1];
        float r0 = o0 * rn * w0 / (1.0f + expf(-g0));
        float r1 = o1 * rn * w1 / (1.0f + expf(-g1));
        unsigned int outw = (unsigned int)f2b(r0) | ((unsigned int)f2b(r1) << 16);
        *(unsigned int*)(og + basep) = outw;
    }
}

// ---------------------------------------------------------------------------
extern "C" void kernel_launch(void* const* d_in, const int* in_sizes, int n_in,
                              void* d_out, int out_size, void* d_ws, size_t ws_size,
                              hipStream_t stream) {
    const float* x = (const float*)d_in[0];
    const float* Wq = (const float*)d_in[1];
    const float* Wk = (const float*)d_in[2];
    const float* Wv = (const float*)d_in[3];
    const float* convq = (const float*)d_in[4];
    const float* convk = (const float*)d_in[5];
    const float* convv = (const float*)d_in[6];
    const float* A_log = (const float*)d_in[7];
    const float* dt_bias = (const float*)d_in[8];
    const float* Wsv = (const float*)d_in[9];
    const float* Wb1 = (const float*)d_in[10];
    const float* bb1 = (const float*)d_in[11];
    const float* Wb2 = (const float*)d_in[12];
    const float* bb2 = (const float*)d_in[13];
    const float* Wa1 = (const float*)d_in[14];
    const float* ba1 = (const float*)d_in[15];
    const float* Wa2 = (const float*)d_in[16];
    const float* ba2 = (const float*)d_in[17];
    const float* Wg1 = (const float*)d_in[18];
    const float* Wg2 = (const float*)d_in[19];
    const float* bg2 = (const float*)d_in[20];
    const float* norm_w = (const float*)d_in[21];
    const float* Wo = (const float*)d_in[22];

    // ---- workspace layout (bytes) ----
    const size_t PBATCH   = (size_t)16 * BHSH * 2;      // 87,031,808 per batch
    const size_t OFF_WQKV = 0;                          // 25,165,824
    const size_t OFF_XB   = OFF_WQKV + 25165824;        // 16,777,216
    const size_t OFF_WG1  = OFF_XB + 16777216;          //    524,288
    const size_t OFF_WG2  = OFF_WG1 + 524288;           //    524,288
    const size_t OFF_QKV  = OFF_WG2 + 524288;           // 50,331,648
    const size_t OFF_P    = OFF_QKV + 50331648;         // = 93,323,264
    const size_t NEED_B   = OFF_P + PBATCH;             // ~180.4 MB
    const size_t NEED_A   = OFF_P + 2 * PBATCH;         // ~267.4 MB
    if (ws_size < NEED_B) return;  // diagnostic guard
    const bool planA = (ws_size >= NEED_A);

    char* ws = (char*)d_ws;
    ushort* wqkv = (ushort*)(ws + OFF_WQKV);
    ushort* xb   = (ushort*)(ws + OFF_XB);
    ushort* wg1b = (ushort*)(ws + OFF_WG1);
    ushort* wg2b = (ushort*)(ws + OFF_WG2);
    ushort* qkvb = (ushort*)(ws + OFF_QKV);
    ushort* P    = (ushort*)(ws + OFF_P);
    ushort* gateb = qkvb;                               // +0        16,777,216
    ushort* xg1b  = (ushort*)(ws + OFF_QKV + 16777216); // +16.78M    1,048,576
    ushort* ogb   = (ushort*)(ws + OFF_QKV + 17825792); // +17.83M   16,777,216
    ushort* wob   = (ushort*)(ws + OFF_QKV + 34603008); // +34.60M    8,388,608
    ushort* obp = planA ? (ushort*)(ws + OFF_WQKV) : xb;

    // weight casts
    cast_f32_bf16<<<512, 256, 0, stream>>>(Wq, wqkv, 4194304);
    cast_f32_bf16<<<512, 256, 0, stream>>>(Wk, wqkv + 4194304, 4194304);
    cast_f32_bf16<<<512, 256, 0, stream>>>(Wv, wqkv + 8388608, 4194304);
    cast_f32_bf16<<<64, 256, 0, stream>>>(Wg1, wg1b, 262144);
    cast_f32_bf16<<<64, 256, 0, stream>>>(Wg2, wg2b, 262144);

    if (planA) {
        for (int b = 0; b < 2; ++b) {
            cast_f32_bf16<<<512, 256, 0, stream>>>(x + (size_t)b * TB * 2048, xb, TB * 2048);
            gemm_bf16<ushort><<<dim3(48, TB / 128), 256, 0, stream>>>(xb, wqkv, qkvb, TB, 6144, 2048);
            conv_stats_kernel<<<TB * 16 / 8, 256, 0, stream>>>(qkvb, convq, convk, convv, Wsv,
                Wb1, bb1, Wb2, bb2, Wa1, ba1, Wa2, ba2, A_log, dt_bias,
                P + (size_t)b * 16 * BHSH);
        }
        phasea_kernel<<<2048, 256, 0, stream>>>(P);
        phaseb_kernel<<<256, 256, 0, stream>>>(P, obp, 31, 5);
        cast_f32_bf16<<<512, 256, 0, stream>>>(Wo, wob, 4194304);
        for (int b = 0; b < 2; ++b) {
            ushort* xstage = ogb;
            cast_f32_bf16<<<512, 256, 0, stream>>>(x + (size_t)b * TB * 2048, xstage, TB * 2048);
            gemm_bf16<ushort><<<dim3(1, TB / 128), 256, 0, stream>>>(xstage, wg1b, xg1b, TB, 128, 2048);
            gemm_bf16<ushort><<<dim3(16, TB / 128), 256, 0, stream>>>(xg1b, wg2b, gateb, TB, 2048, 128);
            normgate_kernel<<<2048, 256, 0, stream>>>(obp + (size_t)b * TB * 2048, gateb, bg2, norm_w, ogb);
            gemm_bf16<float><<<dim3(16, TB / 128), 256, 0, stream>>>(ogb, wob,
                (float*)d_out + (size_t)b * TB * 2048, TB, 2048, 2048);
        }
    } else {
        for (int b = 0; b < 2; ++b) {
            const float* xbp = x + (size_t)b * TB * 2048;
            float* outp = (float*)d_out + (size_t)b * TB * 2048;
            cast_f32_bf16<<<512, 256, 0, stream>>>(xbp, xb, TB * 2048);
            gemm_bf16<ushort><<<dim3(48, TB / 128), 256, 0, stream>>>(xb, wqkv, qkvb, TB, 6144, 2048);
            conv_stats_kernel<<<TB * 16 / 8, 256, 0, stream>>>(qkvb, convq, convk, convv, Wsv,
                Wb1, bb1, Wb2, bb2, Wa1, ba1, Wa2, ba2, A_log, dt_bias, P);
            gemm_bf16<ushort><<<dim3(1, TB / 128), 256, 0, stream>>>(xb, wg1b, xg1b, TB, 128, 2048);
            gemm_bf16<ushort><<<dim3(16, TB / 128), 256, 0, stream>>>(xg1b, wg2b, gateb, TB, 2048, 128);
            cast_f32_bf16<<<512, 256, 0, stream>>>(Wo, wob, 4194304);
            phasea_kernel<<<1024, 256, 0, stream>>>(P);
            phaseb_kernel<<<128, 256, 0, stream>>>(P, xb, 15, 4);   // xb dead -> ob
            normgate_kernel<<<2048, 256, 0, stream>>>(xb, gateb, bg2, norm_w, ogb);
            gemm_bf16<float><<<dim3(16, TB / 128), 256, 0, stream>>>(ogb, wob, outp, TB, 2048, 2048);
        }
    }
}

// Round 13
// 1714.903 us; speedup vs baseline: 1.6496x; 1.0407x over previous
//
#include <hip/hip_runtime.h>
#include <hip/hip_bf16.h>

// ---------------------------------------------------------------------------
// SurpriseKimiDeltaAttention  (B=2, T=4096, H=2048, NH=16, DK=DV=128, CONV=4)
// R13 = R12 chunked scan; phaseb lane->dim map changed to two contiguous
// 4-float blocks (dims l16*4..+3 and 64+l16*4..+3) so all LDS b128 accesses
// are consecutive across lanes -> bank-conflict-free (no swizzle needed).
// ---------------------------------------------------------------------------

typedef __attribute__((ext_vector_type(8))) short bf16x8;
typedef __attribute__((ext_vector_type(4))) float floatx4;

#define TB 4096
#define RSH 664                      // shorts per record
#define NREC 4096
#define BHSH ((size_t)NREC * RSH)    // shorts per (b,h) stream
#define CSB ((size_t)16 * RSH * 2)   // chunk span bytes = 21248

__device__ __forceinline__ float b2f(ushort u) {
    union { unsigned int u; float f; } c; c.u = ((unsigned int)u) << 16; return c.f;
}
__device__ __forceinline__ ushort f2b(float f) {
    union { float f; unsigned int u; } c; c.f = f;
    unsigned int r = (c.u + 0x7fffu + ((c.u >> 16) & 1u)) >> 16;
    return (ushort)r;
}
__device__ __forceinline__ float silu(float x) { return x / (1.0f + expf(-x)); }
__device__ __forceinline__ void dec8(uint4 u, float* f) {
    f[0] = __uint_as_float(u.x << 16); f[1] = __uint_as_float(u.x & 0xffff0000u);
    f[2] = __uint_as_float(u.y << 16); f[3] = __uint_as_float(u.y & 0xffff0000u);
    f[4] = __uint_as_float(u.z << 16); f[5] = __uint_as_float(u.z & 0xffff0000u);
    f[6] = __uint_as_float(u.w << 16); f[7] = __uint_as_float(u.w & 0xffff0000u);
}
__device__ __forceinline__ void dec4(uint2 u, float* f) {
    f[0] = __uint_as_float(u.x << 16); f[1] = __uint_as_float(u.x & 0xffff0000u);
    f[2] = __uint_as_float(u.y << 16); f[3] = __uint_as_float(u.y & 0xffff0000u);
}

// ---------------------------------------------------------------------------
__global__ __launch_bounds__(256) void cast_f32_bf16(const float* __restrict__ in,
                                                     ushort* __restrict__ out, int n) {
    int i = (blockIdx.x * 256 + threadIdx.x) * 4;
    int stride = gridDim.x * 256 * 4;
    for (; i + 3 < n; i += stride) {
        float4 v = *(const float4*)(in + i);
        ushort4 u;
        u.x = f2b(v.x); u.y = f2b(v.y); u.z = f2b(v.z); u.w = f2b(v.w);
        *(ushort4*)(out + i) = u;
    }
}

// ---------------------------------------------------------------------------
// bf16 MFMA GEMM: C[M][N] = A[M][K] @ B[N][K]^T  (row-major, K contiguous)
// ---------------------------------------------------------------------------
template <typename CT>
__global__ __launch_bounds__(256) void gemm_bf16(const ushort* __restrict__ A,
                                                 const ushort* __restrict__ B,
                                                 CT* __restrict__ C, int M, int N, int K) {
    __shared__ ushort As[128 * 40];
    __shared__ ushort Bs[128 * 40];
    const int tid = threadIdx.x;
    const int lane = tid & 63, wid = tid >> 6;
    const int wr = wid >> 1, wc = wid & 1;
    const int bm = blockIdx.y, bn = blockIdx.x;

    const int r0 = tid >> 2;
    const int kc0 = (tid & 3) * 8;
    const size_t aoff0 = (size_t)(bm * 128 + r0) * K + kc0;
    const size_t aoff1 = aoff0 + (size_t)64 * K;
    const size_t boff0 = (size_t)(bn * 128 + r0) * K + kc0;
    const size_t boff1 = boff0 + (size_t)64 * K;
    const int lw0 = r0 * 40 + kc0;
    const int lw1 = (r0 + 64) * 40 + kc0;

    const int arow = wr * 64 + (lane & 15);
    const int brow = wc * 64 + (lane & 15);
    const int kg = (lane >> 4) * 8;

    floatx4 acc[4][4];
#pragma unroll
    for (int m = 0; m < 4; ++m)
#pragma unroll
        for (int n = 0; n < 4; ++n) acc[m][n] = (floatx4){0.f, 0.f, 0.f, 0.f};

    uint4 ra0 = *(const uint4*)(A + aoff0);
    uint4 ra1 = *(const uint4*)(A + aoff1);
    uint4 rb0 = *(const uint4*)(B + boff0);
    uint4 rb1 = *(const uint4*)(B + boff1);

    for (int kt = 32; kt <= K; kt += 32) {
        __syncthreads();
        *(uint4*)(As + lw0) = ra0;
        *(uint4*)(As + lw1) = ra1;
        *(uint4*)(Bs + lw0) = rb0;
        *(uint4*)(Bs + lw1) = rb1;
        __syncthreads();
        if (kt < K) {
            ra0 = *(const uint4*)(A + aoff0 + kt);
            ra1 = *(const uint4*)(A + aoff1 + kt);
            rb0 = *(const uint4*)(B + boff0 + kt);
            rb1 = *(const uint4*)(B + boff1 + kt);
        }
        bf16x8 af[4], bfr[4];
#pragma unroll
        for (int m = 0; m < 4; ++m) af[m] = *(const bf16x8*)(As + (arow + m * 16) * 40 + kg);
#pragma unroll
        for (int n = 0; n < 4; ++n) bfr[n] = *(const bf16x8*)(Bs + (brow + n * 16) * 40 + kg);
#pragma unroll
        for (int m = 0; m < 4; ++m)
#pragma unroll
            for (int n = 0; n < 4; ++n)
                acc[m][n] = __builtin_amdgcn_mfma_f32_16x16x32_bf16(af[m], bfr[n], acc[m][n], 0, 0, 0);
    }

    const int crow0 = bm * 128 + wr * 64 + (lane >> 4) * 4;
    const int ccol0 = bn * 128 + wc * 64 + (lane & 15);
#pragma unroll
    for (int m = 0; m < 4; ++m)
#pragma unroll
        for (int n = 0; n < 4; ++n)
#pragma unroll
            for (int j = 0; j < 4; ++j) {
                int row = crow0 + m * 16 + j;
                int col = ccol0 + n * 16;
                if constexpr (sizeof(CT) == 2)
                    C[(size_t)row * N + col] = (CT)f2b(acc[m][n][j]);
                else
                    C[(size_t)row * N + col] = (CT)acc[m][n][j];
            }
}

// ---------------------------------------------------------------------------
// conv + silu + surprise stats + beta/amp MLPs -> records (one batch)
// lane owns dims (2*lane, 2*lane+1); record: q~@128 k@256 E@384 v@512 beta@640
// ---------------------------------------------------------------------------
__global__ __launch_bounds__(256) void conv_stats_kernel(
    const ushort* __restrict__ qkv,
    const float* __restrict__ convq, const float* __restrict__ convk,
    const float* __restrict__ convv, const float* __restrict__ Wsv,
    const float* __restrict__ Wb1, const float* __restrict__ bb1,
    const float* __restrict__ Wb2, const float* __restrict__ bb2,
    const float* __restrict__ Wa1, const float* __restrict__ ba1,
    const float* __restrict__ Wa2, const float* __restrict__ ba2,
    const float* __restrict__ A_log, const float* __restrict__ dt_bias,
    ushort* __restrict__ P) {
    __shared__ ushort wsv_s[128 * 136];
    __shared__ float k_sh[4][128];
    for (int i = threadIdx.x; i < 128 * 128; i += 256) {
        int row = i >> 7, col = i & 127;
        wsv_s[row * 136 + col] = f2b(Wsv[i]);
    }
    __syncthreads();
    const int wid = threadIdx.x >> 6, lane = threadIdx.x & 63;

    for (int it = 0; it < 2; ++it) {
        const int pair = blockIdx.x * 8 + it * 4 + wid;   // [0, TB*16)
        const int t = pair >> 4, h = pair & 15;
        const int c0 = h * 128 + 2 * lane, c1 = c0 + 1;

        float wq[4], wq2[4], wk[4], wk2[4], wv[4], wv2[4];
#pragma unroll
        for (int i2 = 0; i2 < 4; ++i2) {
            wq[i2] = convq[c0 * 4 + i2]; wq2[i2] = convq[c1 * 4 + i2];
            wk[i2] = convk[c0 * 4 + i2]; wk2[i2] = convk[c1 * 4 + i2];
            wv[i2] = convv[c0 * 4 + i2]; wv2[i2] = convv[c1 * 4 + i2];
        }
        float aq0 = 0, aq1 = 0, ak0 = 0, ak1 = 0, av0 = 0, av1 = 0;
#pragma unroll
        for (int i2 = 0; i2 < 4; ++i2) {
            int tt = t - 3 + i2;
            if (tt >= 0) {
                const ushort* rowp = qkv + (size_t)tt * 6144 + h * 128;
                uint xq = *(const uint*)(rowp + 2 * lane);
                uint xk = *(const uint*)(rowp + 2048 + 2 * lane);
                uint xv = *(const uint*)(rowp + 4096 + 2 * lane);
                aq0 = fmaf(__uint_as_float(xq << 16), wq[i2], aq0);
                aq1 = fmaf(__uint_as_float(xq & 0xffff0000u), wq2[i2], aq1);
                ak0 = fmaf(__uint_as_float(xk << 16), wk[i2], ak0);
                ak1 = fmaf(__uint_as_float(xk & 0xffff0000u), wk2[i2], ak1);
                av0 = fmaf(__uint_as_float(xv << 16), wv[i2], av0);
                av1 = fmaf(__uint_as_float(xv & 0xffff0000u), wv2[i2], av1);
            }
        }
        float q0 = silu(aq0), q1 = silu(aq1);
        float k0 = silu(ak0), k1 = silu(ak1);
        float v0 = silu(av0), v1 = silu(av1);

        __syncthreads();
        k_sh[wid][2 * lane] = k0;
        k_sh[wid][2 * lane + 1] = k1;
        __syncthreads();

        float vh0 = 0.f, vh1 = 0.f;
        const ushort* wr0 = wsv_s + (2 * lane) * 136;
        const ushort* wr1 = wsv_s + (2 * lane + 1) * 136;
#pragma unroll 4
        for (int j = 0; j < 128; j += 8) {
            float4 ka = *(const float4*)&k_sh[wid][j];
            float4 kb = *(const float4*)&k_sh[wid][j + 4];
            uint4 wa = *(const uint4*)(wr0 + j);
            uint4 wb = *(const uint4*)(wr1 + j);
            vh0 = fmaf(__uint_as_float(wa.x << 16), ka.x, vh0);
            vh0 = fmaf(__uint_as_float(wa.x & 0xffff0000u), ka.y, vh0);
            vh0 = fmaf(__uint_as_float(wa.y << 16), ka.z, vh0);
            vh0 = fmaf(__uint_as_float(wa.y & 0xffff0000u), ka.w, vh0);
            vh0 = fmaf(__uint_as_float(wa.z << 16), kb.x, vh0);
            vh0 = fmaf(__uint_as_float(wa.z & 0xffff0000u), kb.y, vh0);
            vh0 = fmaf(__uint_as_float(wa.w << 16), kb.z, vh0);
            vh0 = fmaf(__uint_as_float(wa.w & 0xffff0000u), kb.w, vh0);
            vh1 = fmaf(__uint_as_float(wb.x << 16), ka.x, vh1);
            vh1 = fmaf(__uint_as_float(wb.x & 0xffff0000u), ka.y, vh1);
            vh1 = fmaf(__uint_as_float(wb.y << 16), ka.z, vh1);
            vh1 = fmaf(__uint_as_float(wb.y & 0xffff0000u), ka.w, vh1);
            vh1 = fmaf(__uint_as_float(wb.z << 16), kb.x, vh1);
            vh1 = fmaf(__uint_as_float(wb.z & 0xffff0000u), kb.y, vh1);
            vh1 = fmaf(__uint_as_float(wb.w << 16), kb.z, vh1);
            vh1 = fmaf(__uint_as_float(wb.w & 0xffff0000u), kb.w, vh1);
        }

        float e0 = vh0 - v0, e1 = vh1 - v1;
        float se2 = e0 * e0 + e1 * e1;
        float sl1 = fabsf(e0) + fabsf(e1);
        float shv = vh0 * v0 + vh1 * v1;
        float shh = vh0 * vh0 + vh1 * vh1;
        float svv = v0 * v0 + v1 * v1;
        float sk2 = k0 * k0 + k1 * k1;
        float sq2 = q0 * q0 + q1 * q1;
#pragma unroll
        for (int m = 32; m >= 1; m >>= 1) {
            se2 += __shfl_xor(se2, m);
            sl1 += __shfl_xor(sl1, m);
            shv += __shfl_xor(shv, m);
            shh += __shfl_xor(shh, m);
            svv += __shfl_xor(svv, m);
            sk2 += __shfl_xor(sk2, m);
            sq2 += __shfl_xor(sq2, m);
        }
        float s_l2 = sqrtf(se2 + 1e-6f);
        float s_l1 = sl1;
        float s_cos = 1.0f - shv / (sqrtf(shh + 1e-6f) * sqrtf(svv + 1e-6f) + 1e-6f);

        const int j2 = lane & 31;
        const float* W1 = (lane < 32) ? Wb1 : Wa1;
        const float* b1 = (lane < 32) ? bb1 : ba1;
        const float* W2 = (lane < 32) ? Wb2 : Wa2;
        float pre = W1[j2 * 3] * s_l2 + W1[j2 * 3 + 1] * s_l1 + W1[j2 * 3 + 2] * s_cos + b1[j2];
        float val = W2[j2] * silu(pre);
#pragma unroll
        for (int m = 16; m >= 1; m >>= 1) val += __shfl_xor(val, m);
        float pre_b = __shfl(val, 0) + bb2[0];
        float pre_a = __shfl(val, 32) + ba2[0];
        float betav = 1.0f / (1.0f + expf(-pre_b));
        float amp = pre_a;

        float knorm = sqrtf(sk2);
        float rinv = amp / fmaxf(knorm, 1e-12f);
        float ah = expf(A_log[h]);
        float gr0 = fmaf(k0, rinv, dt_bias[c0]);
        float gr1 = fmaf(k1, rinv, dt_bias[c1]);
        float sp0 = (gr0 > 20.f) ? gr0 : log1pf(expf(gr0));
        float sp1 = (gr1 > 20.f) ? gr1 : log1pf(expf(gr1));

        ushort* rec = P + (size_t)h * BHSH + (size_t)t * RSH;
        float kinv = rsqrtf(sk2 + 1e-6f);
        float qinv = rsqrtf(sq2 + 1e-6f) * 0.08838834764831845f;  // * DK^-0.5
        *(uint*)(rec + 128 + 2 * lane) = (uint)f2b(q0 * qinv) | ((uint)f2b(q1 * qinv) << 16);
        *(uint*)(rec + 256 + 2 * lane) = (uint)f2b(k0 * kinv) | ((uint)f2b(k1 * kinv) << 16);
        *(uint*)(rec + 384 + 2 * lane) = (uint)f2b(expf(-ah * sp0)) | ((uint)f2b(expf(-ah * sp1)) << 16);
        *(uint*)(rec + 512 + 2 * lane) = (uint)f2b(v0) | ((uint)f2b(v1) << 16);
        if (lane == 0) *(float*)(rec + 640) = betav;
    }
}

// ---------------------------------------------------------------------------
// phase A: one wave per (stream, chunk).  In-place chunk-block construction.
// ---------------------------------------------------------------------------
__global__ __launch_bounds__(256, 1) void phasea_kernel(ushort* __restrict__ P) {
    __shared__ float lA[4][16][16];
    __shared__ float lU[4][16][16];
    __shared__ float lM[4][16][16];
    const int wid = threadIdx.x >> 6, lane = threadIdx.x & 63;
    const int g = blockIdx.x * 4 + wid;
    const int s = g >> 8, n = g & 255;
    ushort* cb = P + (size_t)s * BHSH + (size_t)n * (16 * RSH);
    char* sb = (char*)cb;
    float (*A_)[16] = lA[wid];
    float (*U_)[16] = lU[wid];
    float (*M_)[16] = lM[wid];

    float kf[32], Ef[32], qf[32], bf[16];
    uint vq[16];
#pragma unroll
    for (int i = 0; i < 16; ++i) {
        const ushort* r = cb + i * RSH;
        uint ku = *(const uint*)(r + 256 + 2 * lane);
        uint eu = *(const uint*)(r + 384 + 2 * lane);
        uint qu = *(const uint*)(r + 128 + 2 * lane);
        vq[i] = *(const uint*)(r + 512 + 2 * lane);
        bf[i] = *(const float*)(r + 640);
        kf[2 * i]     = __uint_as_float(ku << 16);
        kf[2 * i + 1] = __uint_as_float(ku & 0xffff0000u);
        Ef[2 * i]     = __uint_as_float(eu << 16);
        Ef[2 * i + 1] = __uint_as_float(eu & 0xffff0000u);
        qf[2 * i]     = __uint_as_float(qu << 16);
        qf[2 * i + 1] = __uint_as_float(qu & 0xffff0000u);
    }

    float R[32];
    float Pc0 = 1.f, Pc1 = 1.f;
#pragma unroll
    for (int i = 0; i < 16; ++i) {
#pragma unroll
        for (int j = 0; j < 16; ++j) if (j < i) {
            R[2 * j] *= Ef[2 * i];
            R[2 * j + 1] *= Ef[2 * i + 1];
        }
        float Tr[16], Ur[16];
#pragma unroll
        for (int j = 0; j < 16; ++j) { Tr[j] = 0.f; Ur[j] = 0.f; }
#pragma unroll
        for (int j = 0; j < 16; ++j) if (j < i) {
            Tr[j] = kf[2 * i] * R[2 * j] + kf[2 * i + 1] * R[2 * j + 1];
            Ur[j] = qf[2 * i] * R[2 * j] + qf[2 * i + 1] * R[2 * j + 1];
        }
        Ur[i] = qf[2 * i] * kf[2 * i] + qf[2 * i + 1] * kf[2 * i + 1];
#pragma unroll
        for (int m = 1; m <= 32; m <<= 1) {
#pragma unroll
            for (int j = 0; j < 16; ++j) if (j <= i) {
                if (j < i) Tr[j] += __shfl_xor(Tr[j], m);
                Ur[j] += __shfl_xor(Ur[j], m);
            }
        }
        if (lane == 0) {
#pragma unroll
            for (int j = 0; j < 16; ++j) if (j < i) A_[i][j] = bf[i] * Tr[j];
#pragma unroll
            for (int j = 0; j < 16; ++j) if (j <= i) U_[i][j] = Ur[j];
        }
        R[2 * i] = kf[2 * i];
        R[2 * i + 1] = kf[2 * i + 1];
        Pc0 *= Ef[2 * i];
        Pc1 *= Ef[2 * i + 1];
        *(uint*)(sb + (size_t)i * 256 + 4 * lane) =
            (uint)f2b(kf[2 * i] * Pc0) | ((uint)f2b(kf[2 * i + 1] * Pc1) << 16);
        *(uint*)(sb + 4096 + (size_t)i * 256 + 4 * lane) =
            (uint)f2b(qf[2 * i] * Pc0) | ((uint)f2b(qf[2 * i + 1] * Pc1) << 16);
    }
    *(uint*)(sb + 16384 + 4 * lane) = (uint)f2b(Pc0) | ((uint)f2b(Pc1) << 16);
    {
        uint lw[8], hw[8];
#pragma unroll
        for (int w = 0; w < 8; ++w) {
            lw[w] = (vq[2 * w] & 0xffffu) | (vq[2 * w + 1] << 16);
            hw[w] = (vq[2 * w] >> 16) | (vq[2 * w + 1] & 0xffff0000u);
        }
        char* vt0 = sb + 12288 + (size_t)(2 * lane) * 32;
        *(uint4*)(vt0)      = (uint4){lw[0], lw[1], lw[2], lw[3]};
        *(uint4*)(vt0 + 16) = (uint4){lw[4], lw[5], lw[6], lw[7]};
        *(uint4*)(vt0 + 32) = (uint4){hw[0], hw[1], hw[2], hw[3]};
        *(uint4*)(vt0 + 48) = (uint4){hw[4], hw[5], hw[6], hw[7]};
    }
    const int mcol = lane & 15;
    float M[16];
#pragma unroll
    for (int i = 0; i < 16; ++i) {
        float acc = (i == mcol) ? bf[i] : 0.f;
#pragma unroll
        for (int j = 0; j < 16; ++j) if (j < i) acc -= A_[i][j] * M[j];
        M[i] = acc;
    }
    if (lane < 16) {
#pragma unroll
        for (int j = 0; j < 16; ++j) M_[j][lane] = M[j];
    }
    if (lane < 16) {
#pragma unroll
        for (int i = 0; i < 16; ++i) {
            float acc = 0.f;
#pragma unroll
            for (int j = 0; j < 16; ++j) if (j <= i) acc += U_[i][j] * M[j];
            *(float*)(sb + 16640 + (size_t)i * 64 + 4 * lane) = acc;
        }
    }
#pragma unroll
    for (int m = 0; m < 16; ++m) {
        float a0 = 0.f, a1 = 0.f;
#pragma unroll
        for (int j = 0; j < 16; ++j) if (j >= m) {
            float mv = M_[j][m];
            a0 = fmaf(mv, R[2 * j], a0);
            a1 = fmaf(mv, R[2 * j + 1], a1);
        }
        *(uint*)(sb + 8192 + (size_t)m * 256 + 4 * lane) =
            (uint)f2b(a0) | ((uint)f2b(a1) << 16);
    }
}

// ---------------------------------------------------------------------------
// owner-reduce: lane l16 (within 16-lane group) ends with full sum of Y[l16].
// ---------------------------------------------------------------------------
__device__ __forceinline__ float ownred16(const float* Y, int l16) {
    float a8[8], a4[4], a2[2];
    const bool b0 = (l16 & 1) != 0;
#pragma unroll
    for (int k = 0; k < 8; ++k) {
        float t  = b0 ? Y[2 * k] : Y[2 * k + 1];
        float kp = b0 ? Y[2 * k + 1] : Y[2 * k];
        a8[k] = kp + __shfl_xor(t, 1);
    }
    const bool b1 = (l16 & 2) != 0;
#pragma unroll
    for (int k = 0; k < 4; ++k) {
        float t  = b1 ? a8[2 * k] : a8[2 * k + 1];
        float kp = b1 ? a8[2 * k + 1] : a8[2 * k];
        a4[k] = kp + __shfl_xor(t, 2);
    }
    const bool b2 = (l16 & 4) != 0;
#pragma unroll
    for (int k = 0; k < 2; ++k) {
        float t  = b2 ? a4[2 * k] : a4[2 * k + 1];
        float kp = b2 ? a4[2 * k + 1] : a4[2 * k];
        a2[k] = kp + __shfl_xor(t, 4);
    }
    const bool b3 = (l16 & 8) != 0;
    float t  = b3 ? a2[0] : a2[1];
    float kp = b3 ? a2[1] : a2[0];
    return kp + __shfl_xor(t, 8);
}

// ---------------------------------------------------------------------------
// phase B: sequential over 256 chunks; block = (stream, 16-col slice).
// Lane l16 owns dims {l16*4..+3} and {64+l16*4..+3}: all LDS b128 accesses
// consecutive across lanes -> conflict-free plain row-major layout.
// ---------------------------------------------------------------------------
__global__ __launch_bounds__(256, 1) void phaseb_kernel(const ushort* __restrict__ P,
                                                        ushort* __restrict__ ob,
                                                        int smask, int sshift) {
    __shared__ float kwf[2][2048];
    __shared__ float qwf[2][2048];
    __shared__ float kvf[2][2048];
    const int tid = threadIdx.x;
    const int l16 = tid & 15, cg = tid >> 4;
    const int s = blockIdx.x & smask, c = blockIdx.x >> sshift;
    const int b = s >> 4, h = s & 15;
    const int col = c * 16 + cg;
    const char* gb = (const char*)(P + (size_t)s * BHSH);
    ushort* opb = ob + (size_t)b * (TB * 2048) + h * 128 + col;
    const int fo = tid * 8;
    const int ro1 = l16 * 4;            // dims l16*4..+3
    const int ro2 = 64 + l16 * 4;       // dims 64+l16*4..+3
    const int gbase = tid & 48;         // 16-group base lane (within wave)

    auto stage = [&](int pb, uint4 sA, uint4 sB, uint4 sC) {
        float t[8];
        dec8(sA, t);
        *(float4*)&kwf[pb][fo] = (float4){t[0], t[1], t[2], t[3]};
        *(float4*)&kwf[pb][fo + 4] = (float4){t[4], t[5], t[6], t[7]};
        dec8(sB, t);
        *(float4*)&qwf[pb][fo] = (float4){t[0], t[1], t[2], t[3]};
        *(float4*)&qwf[pb][fo + 4] = (float4){t[4], t[5], t[6], t[7]};
        dec8(sC, t);
        *(float4*)&kvf[pb][fo] = (float4){t[0], t[1], t[2], t[3]};
        *(float4*)&kvf[pb][fo + 4] = (float4){t[4], t[5], t[6], t[7]};
    };

    uint4 sA = *(const uint4*)(gb + (size_t)fo * 2);
    uint4 sB = *(const uint4*)(gb + 4096 + (size_t)fo * 2);
    uint4 sC = *(const uint4*)(gb + 8192 + (size_t)fo * 2);
    stage(0, sA, sB, sC);
    sA = *(const uint4*)(gb + CSB + (size_t)fo * 2);
    sB = *(const uint4*)(gb + CSB + 4096 + (size_t)fo * 2);
    sC = *(const uint4*)(gb + CSB + 8192 + (size_t)fo * 2);
    __syncthreads();

    float S[8];
#pragma unroll
    for (int i = 0; i < 8; ++i) S[i] = 0.f;
    int p = 0;

    for (int n = 0; n < 256; ++n) {
        const char* cbn = gb + (size_t)n * CSB;
        // per-chunk global loads (latency hidden under Y/Z dots)
        float vf_own = b2f(*(const ushort*)(cbn + 12288 + (size_t)col * 32 + l16 * 2));
        uint2 wuL = *(const uint2*)(cbn + 16384 + (size_t)l16 * 8);          // dims l16*4..+3
        uint2 wuH = *(const uint2*)(cbn + 16384 + 128 + (size_t)l16 * 8);    // dims 64+l16*4..+3
        float um[16];
        *(float4*)&um[0]  = *(const float4*)(cbn + 16640 + (size_t)l16 * 64);
        *(float4*)&um[4]  = *(const float4*)(cbn + 16640 + (size_t)l16 * 64 + 16);
        *(float4*)&um[8]  = *(const float4*)(cbn + 16640 + (size_t)l16 * 64 + 32);
        *(float4*)&um[12] = *(const float4*)(cbn + 16640 + (size_t)l16 * 64 + 48);
        // stage chunk n+1 into buffer p^1
        if (n < 255) stage(p ^ 1, sA, sB, sC);
        // prefetch chunk n+2
        if (n < 254) {
            const char* pf = gb + (size_t)(n + 2) * CSB;
            sA = *(const uint4*)(pf + (size_t)fo * 2);
            sB = *(const uint4*)(pf + 4096 + (size_t)fo * 2);
            sC = *(const uint4*)(pf + 8192 + (size_t)fo * 2);
        }
        // Y = KW.S0, Z = QW.S0  (partial over this lane's 8 dims)
        float Y[16], Z[16];
#pragma unroll
        for (int i = 0; i < 16; ++i) {
            float4 ka = *(const float4*)&kwf[p][i * 128 + ro1];
            float4 kb = *(const float4*)&kwf[p][i * 128 + ro2];
            float4 qa = *(const float4*)&qwf[p][i * 128 + ro1];
            float4 qb = *(const float4*)&qwf[p][i * 128 + ro2];
            Y[i] = ka.x * S[0] + ka.y * S[1] + ka.z * S[2] + ka.w * S[3]
                 + kb.x * S[4] + kb.y * S[5] + kb.z * S[6] + kb.w * S[7];
            Z[i] = qa.x * S[0] + qa.y * S[1] + qa.z * S[2] + qa.w * S[3]
                 + qb.x * S[4] + qb.y * S[5] + qb.z * S[6] + qb.w * S[7];
        }
        // owner-reduce (lane l16 gets full Y[l16], Z[l16])
        float Yo = ownred16(Y, l16);
        float Zo = ownred16(Z, l16);
        float rro = vf_own - Yo;
        // gather rr[0..15] to all lanes of the group
        float rrg[16];
#pragma unroll
        for (int j = 0; j < 16; ++j) rrg[j] = __shfl(rro, gbase + j);
        // S-update first (inter-chunk critical chain): S = W15*S + sum_m KV'_m rr_m
        {
            float wf[8];
            dec4(wuL, wf);
            dec4(wuH, wf + 4);
#pragma unroll
            for (int d = 0; d < 8; ++d) S[d] *= wf[d];
        }
#pragma unroll
        for (int m2 = 0; m2 < 16; ++m2) {
            float4 va = *(const float4*)&kvf[p][m2 * 128 + ro1];
            float4 vb = *(const float4*)&kvf[p][m2 * 128 + ro2];
            S[0] = fmaf(va.x, rrg[m2], S[0]);
            S[1] = fmaf(va.y, rrg[m2], S[1]);
            S[2] = fmaf(va.z, rrg[m2], S[2]);
            S[3] = fmaf(va.w, rrg[m2], S[3]);
            S[4] = fmaf(vb.x, rrg[m2], S[4]);
            S[5] = fmaf(vb.y, rrg[m2], S[5]);
            S[6] = fmaf(vb.z, rrg[m2], S[6]);
            S[7] = fmaf(vb.w, rrg[m2], S[7]);
        }
        // o for row i = l16 (off critical chain)
        float oo = Zo;
#pragma unroll
        for (int j = 0; j < 16; ++j) oo = fmaf(um[j], rrg[j], oo);
        opb[(size_t)(n * 16 + l16) * 2048] = f2b(oo);
        __syncthreads();
        p ^= 1;
    }
}

// ---------------------------------------------------------------------------
// gated RMS norm: og = bf16( o*rsqrt(mean o^2+1e-5)*norm_w*sigmoid(gate+bg2) )
// ---------------------------------------------------------------------------
__global__ __launch_bounds__(256) void normgate_kernel(
    const ushort* __restrict__ o, const ushort* __restrict__ gate,
    const float* __restrict__ bg2, const float* __restrict__ norm_w,
    ushort* __restrict__ og) {
    const int lane = threadIdx.x & 63;
    const int wstart = (blockIdx.x * 256 + threadIdx.x) >> 6;
    const int nw = (gridDim.x * 256) >> 6;
    for (int pair = wstart; pair < TB * 16; pair += nw) {
        const int t = pair >> 4, h = pair & 15;
        const size_t basep = (size_t)t * 2048 + h * 128 + lane * 2;
        unsigned int ovu = *(const unsigned int*)(o + basep);
        float o0 = __uint_as_float(ovu << 16);
        float o1 = __uint_as_float(ovu & 0xffff0000u);
        float ss = o0 * o0 + o1 * o1;
#pragma unroll
        for (int m = 32; m >= 1; m >>= 1) ss += __shfl_xor(ss, m);
        float rn = rsqrtf(ss * (1.0f / 128.0f) + 1e-5f);
        const int dg = h * 128 + lane * 2;
        unsigned int gv = *(const unsigned int*)(gate + basep);
        float g0 = __uint_as_float(gv << 16) + bg2[dg];
        float g1 = __uint_as_float(gv & 0xffff0000u) + bg2[dg + 1];
        float w0 = norm_w[lane * 2], w1 = norm_w[lane * 2 + 1];
        float r0 = o0 * rn * w0 / (1.0f + expf(-g0));
        float r1 = o1 * rn * w1 / (1.0f + expf(-g1));
        unsigned int outw = (unsigned int)f2b(r0) | ((unsigned int)f2b(r1) << 16);
        *(unsigned int*)(og + basep) = outw;
    }
}

// ---------------------------------------------------------------------------
extern "C" void kernel_launch(void* const* d_in, const int* in_sizes, int n_in,
                              void* d_out, int out_size, void* d_ws, size_t ws_size,
                              hipStream_t stream) {
    const float* x = (const float*)d_in[0];
    const float* Wq = (const float*)d_in[1];
    const float* Wk = (const float*)d_in[2];
    const float* Wv = (const float*)d_in[3];
    const float* convq = (const float*)d_in[4];
    const float* convk = (const float*)d_in[5];
    const float* convv = (const float*)d_in[6];
    const float* A_log = (const float*)d_in[7];
    const float* dt_bias = (const float*)d_in[8];
    const float* Wsv = (const float*)d_in[9];
    const float* Wb1 = (const float*)d_in[10];
    const float* bb1 = (const float*)d_in[11];
    const float* Wb2 = (const float*)d_in[12];
    const float* bb2 = (const float*)d_in[13];
    const float* Wa1 = (const float*)d_in[14];
    const float* ba1 = (const float*)d_in[15];
    const float* Wa2 = (const float*)d_in[16];
    const float* ba2 = (const float*)d_in[17];
    const float* Wg1 = (const float*)d_in[18];
    const float* Wg2 = (const float*)d_in[19];
    const float* bg2 = (const float*)d_in[20];
    const float* norm_w = (const float*)d_in[21];
    const float* Wo = (const float*)d_in[22];

    // ---- workspace layout (bytes) ----
    const size_t PBATCH   = (size_t)16 * BHSH * 2;      // 87,031,808 per batch
    const size_t OFF_WQKV = 0;                          // 25,165,824
    const size_t OFF_XB   = OFF_WQKV + 25165824;        // 16,777,216
    const size_t OFF_WG1  = OFF_XB + 16777216;          //    524,288
    const size_t OFF_WG2  = OFF_WG1 + 524288;           //    524,288
    const size_t OFF_QKV  = OFF_WG2 + 524288;           // 50,331,648
    const size_t OFF_P    = OFF_QKV + 50331648;         // = 93,323,264
    const size_t NEED_B   = OFF_P + PBATCH;             // ~180.4 MB
    const size_t NEED_A   = OFF_P + 2 * PBATCH;         // ~267.4 MB
    if (ws_size < NEED_B) return;  // diagnostic guard
    const bool planA = (ws_size >= NEED_A);

    char* ws = (char*)d_ws;
    ushort* wqkv = (ushort*)(ws + OFF_WQKV);
    ushort* xb   = (ushort*)(ws + OFF_XB);
    ushort* wg1b = (ushort*)(ws + OFF_WG1);
    ushort* wg2b = (ushort*)(ws + OFF_WG2);
    ushort* qkvb = (ushort*)(ws + OFF_QKV);
    ushort* P    = (ushort*)(ws + OFF_P);
    ushort* gateb = qkvb;                               // +0        16,777,216
    ushort* xg1b  = (ushort*)(ws + OFF_QKV + 16777216); // +16.78M    1,048,576
    ushort* ogb   = (ushort*)(ws + OFF_QKV + 17825792); // +17.83M   16,777,216
    ushort* wob   = (ushort*)(ws + OFF_QKV + 34603008); // +34.60M    8,388,608
    ushort* obp = planA ? (ushort*)(ws + OFF_WQKV) : xb;

    // weight casts
    cast_f32_bf16<<<512, 256, 0, stream>>>(Wq, wqkv, 4194304);
    cast_f32_bf16<<<512, 256, 0, stream>>>(Wk, wqkv + 4194304, 4194304);
    cast_f32_bf16<<<512, 256, 0, stream>>>(Wv, wqkv + 8388608, 4194304);
    cast_f32_bf16<<<64, 256, 0, stream>>>(Wg1, wg1b, 262144);
    cast_f32_bf16<<<64, 256, 0, stream>>>(Wg2, wg2b, 262144);

    if (planA) {
        for (int b = 0; b < 2; ++b) {
            cast_f32_bf16<<<512, 256, 0, stream>>>(x + (size_t)b * TB * 2048, xb, TB * 2048);
            gemm_bf16<ushort><<<dim3(48, TB / 128), 256, 0, stream>>>(xb, wqkv, qkvb, TB, 6144, 2048);
            conv_stats_kernel<<<TB * 16 / 8, 256, 0, stream>>>(qkvb, convq, convk, convv, Wsv,
                Wb1, bb1, Wb2, bb2, Wa1, ba1, Wa2, ba2, A_log, dt_bias,
                P + (size_t)b * 16 * BHSH);
        }
        phasea_kernel<<<2048, 256, 0, stream>>>(P);
        phaseb_kernel<<<256, 256, 0, stream>>>(P, obp, 31, 5);
        cast_f32_bf16<<<512, 256, 0, stream>>>(Wo, wob, 4194304);
        for (int b = 0; b < 2; ++b) {
            ushort* xstage = ogb;
            cast_f32_bf16<<<512, 256, 0, stream>>>(x + (size_t)b * TB * 2048, xstage, TB * 2048);
            gemm_bf16<ushort><<<dim3(1, TB / 128), 256, 0, stream>>>(xstage, wg1b, xg1b, TB, 128, 2048);
            gemm_bf16<ushort><<<dim3(16, TB / 128), 256, 0, stream>>>(xg1b, wg2b, gateb, TB, 2048, 128);
            normgate_kernel<<<2048, 256, 0, stream>>>(obp + (size_t)b * TB * 2048, gateb, bg2, norm_w, ogb);
            gemm_bf16<float><<<dim3(16, TB / 128), 256, 0, stream>>>(ogb, wob,
                (float*)d_out + (size_t)b * TB * 2048, TB, 2048, 2048);
        }
    } else {
        for (int b = 0; b < 2; ++b) {
            const float* xbp = x + (size_t)b * TB * 2048;
            float* outp = (float*)d_out + (size_t)b * TB * 2048;
            cast_f32_bf16<<<512, 256, 0, stream>>>(xbp, xb, TB * 2048);
            gemm_bf16<ushort><<<dim3(48, TB / 128), 256, 0, stream>>>(xb, wqkv, qkvb, TB, 6144, 2048);
            conv_stats_kernel<<<TB * 16 / 8, 256, 0, stream>>>(qkvb, convq, convk, convv, Wsv,
                Wb1, bb1, Wb2, bb2, Wa1, ba1, Wa2, ba2, A_log, dt_bias, P);
            gemm_bf16<ushort><<<dim3(1, TB / 128), 256, 0, stream>>>(xb, wg1b, xg1b, TB, 128, 2048);
            gemm_bf16<ushort><<<dim3(16, TB / 128), 256, 0, stream>>>(xg1b, wg2b, gateb, TB, 2048, 128);
            cast_f32_bf16<<<512, 256, 0, stream>>>(Wo, wob, 4194304);
            phasea_kernel<<<1024, 256, 0, stream>>>(P);
            phaseb_kernel<<<128, 256, 0, stream>>>(P, xb, 15, 4);   // xb dead -> ob
            normgate_kernel<<<2048, 256, 0, stream>>>(xb, gateb, bg2, norm_w, ogb);
            gemm_bf16<float><<<dim3(16, TB / 128), 256, 0, stream>>>(ogb, wob, outp, TB, 2048, 2048);
        }
    }
}